// Round 5
// baseline (1517.537 us; speedup 1.0000x reference)
//
#include <hip/hip_runtime.h>
#include <math.h>

#define DMODEL 1280
#define NHEADS 16
#define FDIM   5120
#define GPOS   48
#define SEG    512

typedef __attribute__((ext_vector_type(8))) short bf16x8;
typedef __attribute__((ext_vector_type(4))) float f32x4;
typedef unsigned short u16;

__device__ __forceinline__ u16 f2bf(float f) {
  unsigned int u = __float_as_uint(f);
  u = (u + 0x7FFFu + ((u >> 16) & 1u)) >> 16;  // RNE
  return (u16)u;
}
__device__ __forceinline__ float bf2f(u16 u) {
  return __uint_as_float((unsigned int)u << 16);
}
__device__ __forceinline__ float gelu_tanh(float x) {
  float u = 0.7978845608028654f * (x + 0.044715f * x * x * x);
  float t = __expf(2.f * u);
  float th = 1.f - 2.f / (t + 1.f);
  return 0.5f * x * (1.f + th);
}

typedef const __attribute__((address_space(1))) unsigned int* gas_t;
typedef __attribute__((address_space(3))) unsigned int* las_t;
__device__ __forceinline__ void async16(const void* g, void* l) {
  __builtin_amdgcn_global_load_lds((gas_t)g, (las_t)l, 16, 0, 0);
}

// ---------------------------------------------------------------------------
// gemm256: 256x256 tile, BK=64, 8 waves (2Mx4N), 128 KiB dbuf LDS, phased
// schedule with counted vmcnt, R2-verified swizzle and schedule (measured
// best; R3 swizzle variant and R4 deep-prefetch variant both regressed).
// A:[M][K] bf16, B:[N][K] bf16, C = A.B^T.
// EPI 0: bf16 partial planes (split-K). EPI 1: +bias bf16. EPI 3: +bias+gelu.
// ---------------------------------------------------------------------------
#define STG256(mat, PW, ldx, h, kk, pp)                          \
  do {                                                           \
    const u16* g_ = (PW) + (long long)(h) * 128 * (ldx) + (kk);  \
    async16(g_, &L[pp][mat][h][(w * 2 + 0) * 512]);              \
    async16(g_ + 32, &L[pp][mat][h][(w * 2 + 1) * 512]);         \
  } while (0)

#define MM256(ii, ff)                                                          \
  acc[ii][ff] = __builtin_amdgcn_mfma_f32_16x16x32_bf16(aR[(ii) & 3][0],       \
                    bR[ff][0], acc[ii][ff], 0, 0, 0);                          \
  acc[ii][ff] = __builtin_amdgcn_mfma_f32_16x16x32_bf16(aR[(ii) & 3][1],       \
                    bR[ff][1], acc[ii][ff], 0, 0, 0);

#define BAR256() asm volatile("s_barrier" ::: "memory")
#define LGKM0() asm volatile("s_waitcnt lgkmcnt(0)" ::: "memory")

template <int EPI>
__global__ __launch_bounds__(512, 2) void gemm256(
    const u16* __restrict__ A, const u16* __restrict__ B,
    const float* __restrict__ bias, void* __restrict__ Cv,
    int Kd, int lda, int ldb, int ldc, int nsplit, long long pstride) {
  __shared__ __align__(16) u16 L[2][2][2][8192];  // [buf][A/B][half][16KB]
  const int sp = blockIdx.z;
  const int Ks = Kd / nsplit;
  const int NT = Ks >> 6;
  const u16* Ab = A + (long long)sp * Ks;
  const u16* Bb = B + (long long)sp * Ks;
  const int m0 = blockIdx.x * 256, n0 = blockIdx.y * 256;
  const int t = threadIdx.x, ln = t & 63, w = t >> 6;
  const int wr = w >> 2, wc = w & 3;
  const int m16 = ln & 15, q = ln >> 4;
  const int r16 = ln >> 2;
  const int csw = (ln & 3) ^ ((ln >> 5) << 1);
  const int rbase = m16 * 32 + (q ^ ((m16 >> 3) << 1)) * 8;

  const u16* Aw = Ab + (long long)(m0 + w * 16 + r16) * lda + csw * 8;
  const u16* Bw = Bb + (long long)(n0 + w * 16 + r16) * ldb + csw * 8;

  f32x4 acc[8][4];
#pragma unroll
  for (int i = 0; i < 8; i++)
#pragma unroll
    for (int j = 0; j < 4; j++)
#pragma unroll
      for (int r = 0; r < 4; r++) acc[i][j][r] = 0.f;

  STG256(0, Aw, lda, 0, 0, 0);
  STG256(0, Aw, lda, 1, 0, 0);
  STG256(1, Bw, ldb, 0, 0, 0);
  STG256(1, Bw, ldb, 1, 0, 0);
  if (NT > 1) {
    STG256(1, Bw, ldb, 0, 64, 1);
    STG256(1, Bw, ldb, 1, 64, 1);
    asm volatile("s_waitcnt vmcnt(4)" ::: "memory");
  } else {
    asm volatile("s_waitcnt vmcnt(0)" ::: "memory");
  }
  BAR256();

  const int wb = (wc & 1) * 4;
  for (int tt = 0; tt < NT; ++tt) {
    const int p = tt & 1;
    const u16* Abuf = &L[p][0][wr][0];
    const u16* Bbuf = &L[p][1][wc >> 1][0];
    bf16x8 aR[4][2], bR[4][2];

    // phase 1
#pragma unroll
    for (int i = 0; i < 4; ++i) {
      aR[i][0] = *(const bf16x8*)(Abuf + (i * 2 + 0) * 512 + rbase);
      aR[i][1] = *(const bf16x8*)(Abuf + (i * 2 + 1) * 512 + rbase);
    }
#pragma unroll
    for (int fc = 0; fc < 2; ++fc) {
      bR[fc][0] = *(const bf16x8*)(Bbuf + ((wb + fc) * 2 + 0) * 512 + rbase);
      bR[fc][1] = *(const bf16x8*)(Bbuf + ((wb + fc) * 2 + 1) * 512 + rbase);
    }
    if (tt + 1 < NT) STG256(0, Aw, lda, 0, (tt + 1) * 64, (tt + 1) & 1);
    BAR256();
    LGKM0();
    __builtin_amdgcn_s_setprio(1);
#pragma unroll
    for (int i = 0; i < 4; ++i) { MM256(i, 0); MM256(i, 1); }
    __builtin_amdgcn_s_setprio(0);
    BAR256();

    // phase 2
#pragma unroll
    for (int fc = 2; fc < 4; ++fc) {
      bR[fc][0] = *(const bf16x8*)(Bbuf + ((wb + fc) * 2 + 0) * 512 + rbase);
      bR[fc][1] = *(const bf16x8*)(Bbuf + ((wb + fc) * 2 + 1) * 512 + rbase);
    }
    if (tt + 1 < NT) STG256(0, Aw, lda, 1, (tt + 1) * 64, (tt + 1) & 1);
    BAR256();
    LGKM0();
    __builtin_amdgcn_s_setprio(1);
#pragma unroll
    for (int i = 0; i < 4; ++i) { MM256(i, 2); MM256(i, 3); }
    __builtin_amdgcn_s_setprio(0);
    BAR256();

    // phase 3
#pragma unroll
    for (int i = 0; i < 4; ++i) {
      aR[i][0] = *(const bf16x8*)(Abuf + ((4 + i) * 2 + 0) * 512 + rbase);
      aR[i][1] = *(const bf16x8*)(Abuf + ((4 + i) * 2 + 1) * 512 + rbase);
    }
    if (tt + 2 < NT) STG256(1, Bw, ldb, 0, (tt + 2) * 64, p);
    BAR256();
    LGKM0();
    __builtin_amdgcn_s_setprio(1);
#pragma unroll
    for (int i = 0; i < 4; ++i) { MM256(4 + i, 2); MM256(4 + i, 3); }
    __builtin_amdgcn_s_setprio(0);
    BAR256();

    // phase 4
    if (tt + 2 < NT) STG256(1, Bw, ldb, 1, (tt + 2) * 64, p);
    BAR256();
    LGKM0();
    __builtin_amdgcn_s_setprio(1);
#pragma unroll
    for (int i = 0; i < 4; ++i) { MM256(4 + i, 0); MM256(4 + i, 1); }
    __builtin_amdgcn_s_setprio(0);
    if (tt + 1 < NT) {
      if (tt + 2 < NT) asm volatile("s_waitcnt vmcnt(4)" ::: "memory");
      else             asm volatile("s_waitcnt vmcnt(0)" ::: "memory");
    }
    BAR256();
  }

#pragma unroll
  for (int fr = 0; fr < 8; fr++) {
#pragma unroll
    for (int r = 0; r < 4; r++) {
      int row = m0 + wr * 128 + fr * 16 + q * 4 + r;
      if (EPI == 0) {
        u16* Cp = (u16*)Cv + (long long)sp * pstride + (long long)row * ldc;
#pragma unroll
        for (int fc = 0; fc < 4; fc++)
          Cp[n0 + wc * 64 + fc * 16 + m16] = f2bf(acc[fr][fc][r]);
      } else if (EPI == 1) {
        u16* Cb = (u16*)Cv + (long long)row * ldc;
#pragma unroll
        for (int fc = 0; fc < 4; fc++) {
          int col = n0 + wc * 64 + fc * 16 + m16;
          Cb[col] = f2bf(acc[fr][fc][r] + bias[col]);
        }
      } else {  // EPI == 3
        u16* Cb = (u16*)Cv + (long long)row * ldc;
#pragma unroll
        for (int fc = 0; fc < 4; fc++) {
          int col = n0 + wc * 64 + fc * 16 + m16;
          Cb[col] = f2bf(gelu_tanh(acc[fr][fc][r] + bias[col]));
        }
      }
    }
  }
}

// ---------------------------------------------------------------------------
// Fused flash attention (R2-verified form). Grid: (SEG/128, NHEADS*nseg).
// ---------------------------------------------------------------------------
__global__ __launch_bounds__(256) void fattn_k(
    const u16* __restrict__ qr, const u16* __restrict__ kr,
    const u16* __restrict__ vpT, u16* __restrict__ o, int N, float iscale) {
  __shared__ __align__(16) u16 Ks[2][24][512];   // [buf][f*3+kg][16kv x 32hd]
  __shared__ __align__(16) u16 Vs[2][20][512];   // [buf][df*4+kvg][16d x 32kv]
  __shared__ __align__(16) u16 Ps[4][32 * 128];  // per-wave P panel
  const int nseg = N >> 9;
  const int hb = blockIdx.y;
  const int h = hb / nseg, seg = hb - h * nseg;
  const int t = threadIdx.x, ln = t & 63, w = t >> 6;
  const int m16 = ln & 15, qh = ln >> 4;
  const int r4 = ln >> 2, gsw = (ln & 3) ^ ((ln >> 5) << 1);
  const int rbase = m16 * 32 + ((qh ^ ((m16 >> 3) << 1)) << 3);
  const long long hN = (long long)h * N;
  const int segbase = seg * SEG;
  const int q0 = segbase + blockIdx.x * 128 + w * 32;

  bf16x8 qf[2][3];
#pragma unroll
  for (int mi = 0; mi < 2; mi++)
#pragma unroll
    for (int ks = 0; ks < 3; ks++)
      qf[mi][ks] = *(const bf16x8*)&qr[(hN + q0 + mi * 16 + m16) * 96 + ks * 32 + qh * 8];

  f32x4 ao[2][5];
#pragma unroll
  for (int mi = 0; mi < 2; mi++)
#pragma unroll
    for (int df = 0; df < 5; df++)
#pragma unroll
      for (int r = 0; r < 4; r++) ao[mi][df][r] = 0.f;
  float m_[2][4], l_[2][4];
#pragma unroll
  for (int mi = 0; mi < 2; mi++)
#pragma unroll
    for (int r = 0; r < 4; r++) { m_[mi][r] = -1e30f; l_[mi][r] = 0.f; }

  auto stage = [&](int c, int pb) {
#pragma unroll
    for (int i = 0; i < 6; i++) {
      int sK = w * 6 + i, f = sK / 3, kg = sK - f * 3;
      async16(&kr[(hN + segbase + c * 128 + f * 16 + r4) * 96 + kg * 32 + gsw * 8],
              &Ks[pb][sK][0]);
    }
#pragma unroll
    for (int i = 0; i < 5; i++) {
      int sV = w * 5 + i, df = sV >> 2, kvg = sV & 3;
      async16(&vpT[((long long)hb * 128 + df * 16 + r4) * SEG + c * 128 + kvg * 32 + gsw * 8],
              &Vs[pb][sV][0]);
    }
  };

  stage(0, 0);
  u16* Pmy = &Ps[w][0];
  for (int c = 0; c < 4; c++) {
    const int pb = c & 1;
    __syncthreads();  // implicit vmcnt(0)+lgkmcnt(0): buf[pb] staged by all waves
    if (c < 3) stage(c + 1, pb ^ 1);

    // QK^T: s[mi][f] rows q=(mi,qh*4+r), cols kv=f*16+m16
    f32x4 s[2][8];
#pragma unroll
    for (int mi = 0; mi < 2; mi++)
#pragma unroll
      for (int f = 0; f < 8; f++)
#pragma unroll
        for (int r = 0; r < 4; r++) s[mi][f][r] = 0.f;
#pragma unroll
    for (int ks = 0; ks < 3; ks++) {
#pragma unroll
      for (int f = 0; f < 8; f++) {
        bf16x8 kf = *(const bf16x8*)&Ks[pb][f * 3 + ks][rbase];
#pragma unroll
        for (int mi = 0; mi < 2; mi++)
          s[mi][f] = __builtin_amdgcn_mfma_f32_16x16x32_bf16(qf[mi][ks], kf, s[mi][f], 0, 0, 0);
      }
    }

    // online softmax per row
#pragma unroll
    for (int mi = 0; mi < 2; mi++) {
#pragma unroll
      for (int r = 0; r < 4; r++) {
        float mx = s[mi][0][r];
#pragma unroll
        for (int f = 1; f < 8; f++) mx = fmaxf(mx, s[mi][f][r]);
        mx *= iscale;
#pragma unroll
        for (int o2 = 1; o2 <= 8; o2 <<= 1) mx = fmaxf(mx, __shfl_xor(mx, o2));
        float mn = fmaxf(m_[mi][r], mx);
        float corr = __expf(m_[mi][r] - mn);
        m_[mi][r] = mn;
        float rs = 0.f;
#pragma unroll
        for (int f = 0; f < 8; f++) {
          float p = __expf(s[mi][f][r] * iscale - mn);
          s[mi][f][r] = p;
          rs += p;
        }
#pragma unroll
        for (int o2 = 1; o2 <= 8; o2 <<= 1) rs += __shfl_xor(rs, o2);
        l_[mi][r] = l_[mi][r] * corr + rs;
#pragma unroll
        for (int df = 0; df < 5; df++) ao[mi][df][r] *= corr;
      }
    }

    // P -> LDS (per-wave private): addr(q,kv)=q*128 + ((kv>>3)^(q&7))*8 + (kv&7)
#pragma unroll
    for (int mi = 0; mi < 2; mi++) {
#pragma unroll
      for (int r = 0; r < 4; r++) {
        int qq = mi * 16 + qh * 4 + r;
        int base = qq * 128 + (m16 & 7);
        int ql = qq & 7;
#pragma unroll
        for (int f = 0; f < 8; f++) {
          int gr = (f * 2 + (m16 >> 3)) ^ ql;
          Pmy[base + gr * 8] = f2bf(s[mi][f][r]);
        }
      }
    }

    // PV: O[q][d] += P[q][kv] V^T[d][kv]
#pragma unroll
    for (int ks = 0; ks < 4; ks++) {
      bf16x8 pf[2];
#pragma unroll
      for (int mi = 0; mi < 2; mi++)
        pf[mi] = *(const bf16x8*)&Pmy[(mi * 16 + m16) * 128 +
                                      (((ks * 4 + qh) ^ (m16 & 7)) << 3)];
#pragma unroll
      for (int df = 0; df < 5; df++) {
        bf16x8 vf = *(const bf16x8*)&Vs[pb][df * 4 + ks][rbase];
#pragma unroll
        for (int mi = 0; mi < 2; mi++)
          ao[mi][df] = __builtin_amdgcn_mfma_f32_16x16x32_bf16(pf[mi], vf, ao[mi][df], 0, 0, 0);
      }
    }
  }

#pragma unroll
  for (int mi = 0; mi < 2; mi++) {
#pragma unroll
    for (int r = 0; r < 4; r++) {
      float rl = 1.f / l_[mi][r];
      long long rowb = (long long)(q0 + mi * 16 + qh * 4 + r) * DMODEL + h * 80;
#pragma unroll
      for (int df = 0; df < 5; df++)
        o[rowb + df * 16 + m16] = f2bf(ao[mi][df][r] * rl);
    }
  }
}

// ---------------------------------------------------------------------------
// Split-K reduce + epilogue (bf16 partials): out = [gelu](sum + bias) [+ res]
// ---------------------------------------------------------------------------
template <int S, int RES, int GELU, int OUTBF>
__global__ void reduce_k(const u16* __restrict__ Pp, long long mn, int Nn,
                         const float* __restrict__ bias,
                         const float* __restrict__ res, void* __restrict__ out) {
  long long i = ((long long)blockIdx.x * 256 + threadIdx.x) * 4;
  if (i >= mn) return;
  float vx = 0.f, vy = 0.f, vz = 0.f, vw = 0.f;
#pragma unroll
  for (int s = 0; s < S; s++) {
    ushort4 u4 = *(const ushort4*)(Pp + (long long)s * mn + i);
    vx += bf2f(u4.x); vy += bf2f(u4.y); vz += bf2f(u4.z); vw += bf2f(u4.w);
  }
  int col = (int)(i % Nn);
  vx += bias[col]; vy += bias[col + 1]; vz += bias[col + 2]; vw += bias[col + 3];
  if (GELU) {
    vx = gelu_tanh(vx); vy = gelu_tanh(vy);
    vz = gelu_tanh(vz); vw = gelu_tanh(vw);
  }
  if (RES) {
    float4 r4 = *(const float4*)(res + i);
    vx += r4.x; vy += r4.y; vz += r4.z; vw += r4.w;
  }
  if (OUTBF) {
    ushort4 o; o.x = f2bf(vx); o.y = f2bf(vy); o.z = f2bf(vz); o.w = f2bf(vw);
    *(ushort4*)((u16*)out + i) = o;
  } else {
    float4 o; o.x = vx; o.y = vy; o.z = vz; o.w = vw;
    *(float4*)((float*)out + i) = o;
  }
}

// ---------------------------------------------------------------------------
// Fused split-K reduce + residual + LayerNorm: one 320-thread block per row.
// ---------------------------------------------------------------------------
template <int S>
__global__ void redln_k(const u16* __restrict__ Pp, long long mn,
                        const float* __restrict__ bias,
                        float* __restrict__ x,
                        const float* __restrict__ s, const float* __restrict__ b,
                        u16* __restrict__ h) {
  int row = blockIdx.x;
  int d = threadIdx.x * 4;
  long long base = (long long)row * DMODEL + d;
  float vx = 0.f, vy = 0.f, vz = 0.f, vw = 0.f;
#pragma unroll
  for (int si = 0; si < S; si++) {
    ushort4 u4 = *(const ushort4*)(Pp + (long long)si * mn + base);
    vx += bf2f(u4.x); vy += bf2f(u4.y); vz += bf2f(u4.z); vw += bf2f(u4.w);
  }
  vx += bias[d]; vy += bias[d + 1]; vz += bias[d + 2]; vw += bias[d + 3];
  float4 r4 = *(const float4*)(x + base);
  vx += r4.x; vy += r4.y; vz += r4.z; vw += r4.w;
  float4 xv; xv.x = vx; xv.y = vy; xv.z = vz; xv.w = vw;
  *(float4*)(x + base) = xv;
  float sum = vx + vy + vz + vw;
#pragma unroll
  for (int o = 32; o; o >>= 1) sum += __shfl_xor(sum, o);
  __shared__ float red[8];
  int wv = threadIdx.x >> 6, lnn = threadIdx.x & 63;
  if (lnn == 0) red[wv] = sum;
  __syncthreads();
  float mu = 0.f;
  for (int i = 0; i < 5; i++) mu += red[i];
  mu *= (1.f / DMODEL);
  float dx = vx - mu, dy = vy - mu, dz = vz - mu, dw = vw - mu;
  float s2 = dx * dx + dy * dy + dz * dz + dw * dw;
#pragma unroll
  for (int o = 32; o; o >>= 1) s2 += __shfl_xor(s2, o);
  __syncthreads();
  if (lnn == 0) red[wv] = s2;
  __syncthreads();
  float var = 0.f;
  for (int i = 0; i < 5; i++) var += red[i];
  var *= (1.f / DMODEL);
  float rs = rsqrtf(var + 1e-6f);
  ushort4 o4;
  o4.x = f2bf(dx * rs * s[d] + b[d]);
  o4.y = f2bf(dy * rs * s[d + 1] + b[d + 1]);
  o4.z = f2bf(dz * rs * s[d + 2] + b[d + 2]);
  o4.w = f2bf(dw * rs * s[d + 3] + b[d + 3]);
  *(ushort4*)(h + base) = o4;
}

// ---------------------------------------------------------------------------
// Weight convert+transpose: in fp32 [K][N] -> out bf16 [N][K]. 32x32 tiles.
// ---------------------------------------------------------------------------
__global__ void wconv_k(const float* __restrict__ in, u16* __restrict__ out,
                        int K, int N) {
  __shared__ float tl[32][33];
  int n0 = blockIdx.x * 32, k0 = blockIdx.y * 32;
  int t = threadIdx.x;
  int r = t >> 5, c = t & 31;
#pragma unroll
  for (int i = 0; i < 4; i++)
    tl[r + 8 * i][c] = in[(long long)(k0 + r + 8 * i) * N + n0 + c];
  __syncthreads();
  int n = t >> 4, kp = (t & 15) * 2;
#pragma unroll
  for (int i = 0; i < 2; i++) {
    ushort2 o;
    o.x = f2bf(tl[kp][n + 16 * i]);
    o.y = f2bf(tl[kp + 1][n + 16 * i]);
    *(ushort2*)&out[(long long)(n0 + n + 16 * i) * K + k0 + kp] = o;
  }
}

// fp32 -> bf16 flat copy
__global__ void conv_k(const float* __restrict__ in, u16* __restrict__ out,
                       long long n) {
  long long i = ((long long)blockIdx.x * 256 + threadIdx.x) * 4;
  if (i >= n) return;
  float4 v = *(const float4*)(in + i);
  ushort4 o; o.x = f2bf(v.x); o.y = f2bf(v.y); o.z = f2bf(v.z); o.w = f2bf(v.w);
  *(ushort4*)&out[i] = o;
}

// V transpose per batch: in bf16 [b][512][128] -> out bf16 [b][128][512]
union U16x8 { uint4 v; u16 s[8]; };
__global__ void vtr_k(const u16* __restrict__ in, u16* __restrict__ out) {
  __shared__ u16 tl[64][65];
  int b = blockIdx.z;
  int m0 = blockIdx.x * 64;
  int d0 = blockIdx.y * 64;
  const u16* ib = in + (long long)b * SEG * 128;
  u16* ob = out + (long long)b * 128 * SEG;
  int t = threadIdx.x;
  int r = t >> 3, c8 = (t & 7) * 8;
#pragma unroll
  for (int i = 0; i < 2; i++) {
    U16x8 ld;
    ld.v = *(const uint4*)&ib[(long long)(m0 + r + 32 * i) * 128 + d0 + c8];
#pragma unroll
    for (int j = 0; j < 8; j++) tl[r + 32 * i][c8 + j] = ld.s[j];
  }
  __syncthreads();
  int d = t >> 3, m8 = (t & 7) * 8;
#pragma unroll
  for (int i = 0; i < 2; i++) {
    int dd = d + 32 * i;
    U16x8 st;
#pragma unroll
    for (int j = 0; j < 8; j++) st.s[j] = tl[m8 + j][dd];
    *(uint4*)&ob[(long long)(d0 + dd) * SEG + m0 + m8] = st.v;
  }
}

// ---------------------------------------------------------------------------
__global__ void coords_k(const int* __restrict__ g, int nimg,
                         int* __restrict__ rw, int* __restrict__ cl,
                         int* __restrict__ hh, int* __restrict__ ww, int N) {
  int t = blockIdx.x * 256 + threadIdx.x;
  if (t >= N) return;
  int c = 0, local = 0, H = 1, W = 1;
  for (int i = 0; i < nimg; i++) {
    int tpi = g[i * 3] * g[i * 3 + 1] * g[i * 3 + 2];
    if (t >= c && t < c + tpi) { local = t - c; H = g[i * 3 + 1]; W = g[i * 3 + 2]; }
    c += tpi;
  }
  int hw = H * W;
  int sp = local % hw;
  int mw = W >> 1;
  int gr = sp >> 2, intra = sp & 3;
  rw[t] = (gr / mw) * 2 + (intra >> 1);
  cl[t] = (gr % mw) * 2 + (intra & 1);
  hh[t] = H; ww[t] = W;
}

__global__ void peadd_k(float* __restrict__ x, const float* __restrict__ pe,
                        const int* __restrict__ rw, const int* __restrict__ cl,
                        const int* __restrict__ hh, const int* __restrict__ ww) {
  int n = blockIdx.x;
  int d = threadIdx.x * 4;
  int H = hh[n], W = ww[n];
  float rf = (H > 1) ? (float)rw[n] * (float)(GPOS - 1) / (float)(H - 1) : 0.f;
  float cf = (W > 1) ? (float)cl[n] * (float)(GPOS - 1) / (float)(W - 1) : 0.f;
  int r0 = (int)floorf(rf), c0 = (int)floorf(cf);
  int r1 = min(r0 + 1, GPOS - 1), c1 = min(c0 + 1, GPOS - 1);
  float wr = rf - (float)r0, wc = cf - (float)c0;
  float w00 = (1.f - wr) * (1.f - wc), w01 = (1.f - wr) * wc;
  float w10 = wr * (1.f - wc), w11 = wr * wc;
  float4 v00 = *(const float4*)(pe + (long long)(r0 * GPOS + c0) * DMODEL + d);
  float4 v01 = *(const float4*)(pe + (long long)(r0 * GPOS + c1) * DMODEL + d);
  float4 v10 = *(const float4*)(pe + (long long)(r1 * GPOS + c0) * DMODEL + d);
  float4 v11 = *(const float4*)(pe + (long long)(r1 * GPOS + c1) * DMODEL + d);
  float4 xv = *(float4*)(x + (long long)n * DMODEL + d);
  xv.x += w00 * v00.x + w01 * v01.x + w10 * v10.x + w11 * v11.x;
  xv.y += w00 * v00.y + w01 * v01.y + w10 * v10.y + w11 * v11.y;
  xv.z += w00 * v00.z + w01 * v01.z + w10 * v10.z + w11 * v11.z;
  xv.w += w00 * v00.w + w01 * v01.w + w10 * v10.w + w11 * v11.w;
  *(float4*)(x + (long long)n * DMODEL + d) = xv;
}

// LayerNorm fp32 in -> bf16 out (one 320-thread block per row of 1280)
__global__ void ln_k(const float* __restrict__ X, u16* __restrict__ Y,
                     const float* __restrict__ s, const float* __restrict__ b) {
  int row = blockIdx.x;
  int d = threadIdx.x * 4;
  const float* x = X + (long long)row * DMODEL;
  float4 v = *(const float4*)(x + d);
  float sum = v.x + v.y + v.z + v.w;
#pragma unroll
  for (int o = 32; o; o >>= 1) sum += __shfl_xor(sum, o);
  __shared__ float red[8];
  int wv = threadIdx.x >> 6, lnn = threadIdx.x & 63;
  if (lnn == 0) red[wv] = sum;
  __syncthreads();
  float mu = 0.f;
  for (int i = 0; i < 5; i++) mu += red[i];
  mu *= (1.f / DMODEL);
  float dx = v.x - mu, dy = v.y - mu, dz = v.z - mu, dw = v.w - mu;
  float s2 = dx * dx + dy * dy + dz * dz + dw * dw;
#pragma unroll
  for (int o = 32; o; o >>= 1) s2 += __shfl_xor(s2, o);
  __syncthreads();
  if (lnn == 0) red[wv] = s2;
  __syncthreads();
  float var = 0.f;
  for (int i = 0; i < 5; i++) var += red[i];
  var *= (1.f / DMODEL);
  float rs = rsqrtf(var + 1e-6f);
  ushort4 o4;
  o4.x = f2bf(dx * rs * s[d] + b[d]);
  o4.y = f2bf(dy * rs * s[d + 1] + b[d + 1]);
  o4.z = f2bf(dz * rs * s[d + 2] + b[d + 2]);
  o4.w = f2bf(dw * rs * s[d + 3] + b[d + 3]);
  *(ushort4*)(Y + (long long)row * DMODEL + d) = o4;
}

// RoPE from bf16 qkv -> qr/kr bf16 [h][N][96] (zero pad), v -> vp [h][N][128]
__global__ void rope_k(const u16* __restrict__ qkv, const int* __restrict__ rw,
                       const int* __restrict__ cl, u16* __restrict__ qr,
                       u16* __restrict__ kr, u16* __restrict__ vp, int N) {
  int n = blockIdx.x, h = blockIdx.y, t = threadIdx.x;
  const u16* src = qkv + (long long)n * (3 * DMODEL) + h * 80;
  long long ob96 = ((long long)h * N + n) * 96;
  long long ob128 = ((long long)h * N + n) * 128;
  if (t < 40) {
    float pos = (t < 20) ? (float)rw[n] : (float)cl[n];
    float infr = exp2f(-13.287712379549449f * (float)(t % 20) * 0.05f);
    float f = pos * infr;
    float cs = cosf(f), sn = sinf(f);
    float q0 = bf2f(src[t]), q1 = bf2f(src[t + 40]);
    qr[ob96 + t] = f2bf(q0 * cs - q1 * sn);
    qr[ob96 + t + 40] = f2bf(q1 * cs + q0 * sn);
    float k0 = bf2f(src[DMODEL + t]), k1 = bf2f(src[DMODEL + t + 40]);
    kr[ob96 + t] = f2bf(k0 * cs - k1 * sn);
    kr[ob96 + t + 40] = f2bf(k1 * cs + k0 * sn);
    vp[ob128 + t] = src[2 * DMODEL + t];
    vp[ob128 + t + 40] = src[2 * DMODEL + t + 40];
  } else {
    int u = t - 40;
    if (u < 16) { qr[ob96 + 80 + u] = 0; kr[ob96 + 80 + u] = 0; }
    vp[ob128 + 80 + u] = 0;
    vp[ob128 + 104 + u] = 0;
  }
}

// ---------------------------------------------------------------------------
// 256x256-tile path: M%256==0, Nn%256==0, (Kd/nsplit)%64==0.
static void gemm_big(hipStream_t st, int epi, const u16* A, const u16* B,
                     const float* bias, void* C, int M, int Nn, int Kd,
                     int lda, int ldb, int ldc, int nsplit) {
  dim3 g(M / 256, Nn / 256, nsplit), blk(512);
  long long ps = (long long)M * Nn;
  switch (epi) {
    case 0: gemm256<0><<<g, blk, 0, st>>>(A, B, bias, C, Kd, lda, ldb, ldc, nsplit, ps); break;
    case 1: gemm256<1><<<g, blk, 0, st>>>(A, B, bias, C, Kd, lda, ldb, ldc, nsplit, ps); break;
    default: gemm256<3><<<g, blk, 0, st>>>(A, B, bias, C, Kd, lda, ldb, ldc, nsplit, ps); break;
  }
}

extern "C" void kernel_launch(void* const* d_in, const int* in_sizes, int n_in,
                              void* d_out, int out_size, void* d_ws, size_t ws_size,
                              hipStream_t stream) {
  const float* pixels = (const float*)d_in[0];
  const int* grid_thw = (const int*)d_in[1];
  const float* pos_embed = (const float*)d_in[2];
  const float* patch_w = (const float*)d_in[3];
  const float* patch_b = (const float*)d_in[4];
  const float* ln1_s = (const float*)d_in[5];
  const float* ln1_b = (const float*)d_in[6];
  const float* qkv_w = (const float*)d_in[7];
  const float* qkv_b = (const float*)d_in[8];
  const float* proj_w = (const float*)d_in[9];
  const float* proj_b = (const float*)d_in[10];
  const float* ln2_s = (const float*)d_in[11];
  const float* ln2_b = (const float*)d_in[12];
  const float* fc1_w = (const float*)d_in[13];
  const float* fc1_b = (const float*)d_in[14];
  const float* fc2_w = (const float*)d_in[15];
  const float* fc2_b = (const float*)d_in[16];
  const float* mns = (const float*)d_in[17];
  const float* mnb = (const float*)d_in[18];
  const float* mf1w = (const float*)d_in[19];
  const float* mf1b = (const float*)d_in[20];
  const float* mf2w = (const float*)d_in[21];
  const float* mf2b = (const float*)d_in[22];
  float* out = (float*)d_out;

  const int N = in_sizes[0] / 1536;  // 2048
  const int nimg = in_sizes[1] / 3;  // 4
  const int nseg = N / SEG;          // 4
  const int nb = NHEADS * nseg;      // 64

  char* w = (char*)d_ws;
  size_t off = 0;
  auto alloc = [&](size_t bytes) -> void* {
    void* p = w + off;
    off += (bytes + 255) & ~(size_t)255;
    return p;
  };
  int* rw = (int*)alloc((size_t)N * 4);
  int* cl = (int*)alloc((size_t)N * 4);
  int* hh = (int*)alloc((size_t)N * 4);
  int* ww = (int*)alloc((size_t)N * 4);
  float* x = (float*)alloc((size_t)N * DMODEL * 4);
  u16* h = (u16*)alloc((size_t)N * DMODEL * 2);
  u16* pixbf = (u16*)alloc((size_t)N * 1536 * 2);      // mfc2T overlay base
  u16* patchT = (u16*)alloc((size_t)DMODEL * 1536 * 2);
  u16* qkvT = (u16*)alloc((size_t)3 * DMODEL * DMODEL * 2);
  u16* projT = (u16*)alloc((size_t)DMODEL * DMODEL * 2);
  u16* fc1T = (u16*)alloc((size_t)FDIM * DMODEL * 2);
  u16* fc2T = (u16*)alloc((size_t)DMODEL * FDIM * 2);
  u16* qkvb = (u16*)alloc((size_t)N * 3 * DMODEL * 2);  // mfc1T overlay base
  u16* qr = (u16*)alloc((size_t)NHEADS * N * 96 * 2);
  u16* kr = (u16*)alloc((size_t)NHEADS * N * 96 * 2);
  u16* vp = (u16*)alloc((size_t)NHEADS * N * 128 * 2);
  u16* vpT = (u16*)alloc((size_t)NHEADS * N * 128 * 2);
  u16* pad0 = (u16*)alloc((size_t)nb * 2 * SEG * 128 * 2);  // keeps mfc1T overlay in bounds
  u16* o = (u16*)alloc((size_t)N * DMODEL * 2);
  float* bigA = (float*)alloc((size_t)nb * SEG * SEG * 4);  // ffb / mf / big partials
  float* bigB = (float*)alloc((size_t)nb * SEG * SEG * 2);  // small split-K partials
  (void)ws_size; (void)pad0;
  // overlays (lifetimes disjoint with originals)
  u16* mfc1T = qkvb;         // 52.4 MB over qkvb..pad0 region
  u16* mfc2T = pixbf;        // 21.0 MB over pixbf..projT
  u16* ffb = (u16*)bigA;     // fc1 out, 21 MB at bigA base
  u16* mf = (u16*)bigA;      // merger hidden 5.2 MB at bigA base
  u16* part = (u16*)bigB;    // partial planes <= 33.5 MB (patch/proj/qkv/mfc2)
  u16* partA = (u16*)bigA + (size_t)11 * 1024 * 1024;  // +22 MB: 42 MB planes
                             // (fc1 split2, fc2 split8, mfc1 split8); disjoint
                             // from ffb/mf (0..21 MB) and within bigA (67 MB)

  const float iscale = 0.11180339887498949f;  // 80^-0.5
  const long long mnD = (long long)N * DMODEL;

  coords_k<<<dim3((N + 255) / 256), 256, 0, stream>>>(grid_thw, nimg, rw, cl, hh, ww, N);
  conv_k<<<dim3((int)(((long long)N * 1536 / 4 + 255) / 256)), 256, 0, stream>>>(
      pixels, pixbf, (long long)N * 1536);
  wconv_k<<<dim3(DMODEL / 32, 1536 / 32), 256, 0, stream>>>(patch_w, patchT, 1536, DMODEL);
  // patch embed, split-K=4 (160 blocks)
  gemm_big(stream, 0, pixbf, patchT, nullptr, part, N, DMODEL, 1536, 1536, 1536,
           DMODEL, 4);
  reduce_k<4, 0, 0, 0><<<dim3((int)((mnD / 4 + 255) / 256)), 256, 0, stream>>>(
      part, mnD, DMODEL, patch_b, nullptr, x);
  peadd_k<<<dim3(N), 320, 0, stream>>>(x, pos_embed, rw, cl, hh, ww);
  // ln1 of layer 0 (subsequent LNs fused into split-K reduces)
  ln_k<<<dim3(N), 320, 0, stream>>>(x, h, ln1_s, ln1_b);

  for (int l = 0; l < 4; l++) {
    wconv_k<<<dim3(3 * DMODEL / 32, DMODEL / 32), 256, 0, stream>>>(
        qkv_w + (size_t)l * DMODEL * 3 * DMODEL, qkvT, DMODEL, 3 * DMODEL);
    wconv_k<<<dim3(DMODEL / 32, DMODEL / 32), 256, 0, stream>>>(
        proj_w + (size_t)l * DMODEL * DMODEL, projT, DMODEL, DMODEL);
    wconv_k<<<dim3(FDIM / 32, DMODEL / 32), 256, 0, stream>>>(
        fc1_w + (size_t)l * DMODEL * FDIM, fc1T, DMODEL, FDIM);
    wconv_k<<<dim3(DMODEL / 32, FDIM / 32), 256, 0, stream>>>(
        fc2_w + (size_t)l * FDIM * DMODEL, fc2T, FDIM, DMODEL);

    // qkv split-K=2 (240 blocks, NT=10 -> single occupancy round) + reduce
    gemm_big(stream, 0, h, qkvT, nullptr, part, N, 3 * DMODEL, DMODEL,
             DMODEL, DMODEL, 3 * DMODEL, 2);
    reduce_k<2, 0, 0, 1><<<dim3((int)(((long long)N * 3 * DMODEL / 4 + 255) / 256)), 256, 0, stream>>>(
        part, (long long)N * 3 * DMODEL, 3 * DMODEL,
        qkv_b + (size_t)l * 3 * DMODEL, nullptr, qkvb);
    rope_k<<<dim3(N, NHEADS), 64, 0, stream>>>(qkvb, rw, cl, qr, kr, vp, N);
    vtr_k<<<dim3(8, 2, nb), 256, 0, stream>>>(vp, vpT);
    // fused flash attention -> o (256 blocks, 1/CU)
    fattn_k<<<dim3(SEG / 128, nb), 256, 0, stream>>>(qr, kr, vpT, o, N, iscale);
    // proj split-K=4 (160 blocks); fused reduce + bias + residual + ln2 -> h
    gemm_big(stream, 0, o, projT, nullptr, part, N, DMODEL, DMODEL, DMODEL,
             DMODEL, DMODEL, 4);
    redln_k<4><<<dim3(N), 320, 0, stream>>>(part, mnD, proj_b + (size_t)l * DMODEL,
                                            x, ln2_s + (size_t)l * DMODEL,
                                            ln2_b + (size_t)l * DMODEL, h);
    // fc1 split-K=2 (320 blocks, NT=10); reduce + bias + gelu -> ffb
    gemm_big(stream, 0, h, fc1T, nullptr, partA, N, FDIM, DMODEL,
             DMODEL, DMODEL, FDIM, 2);
    reduce_k<2, 0, 1, 1><<<dim3((int)(((long long)N * FDIM / 4 + 255) / 256)), 256, 0, stream>>>(
        partA, (long long)N * FDIM, FDIM, fc1_b + (size_t)l * FDIM, nullptr, ffb);
    // fc2 split-K=8 (320 blocks, NT=10); fused reduce + residual + next LN -> h
    gemm_big(stream, 0, ffb, fc2T, nullptr, partA, N, DMODEL, FDIM, FDIM, FDIM,
             DMODEL, 8);
    const float* nsl = (l < 3) ? ln1_s + (size_t)(l + 1) * DMODEL : mns;
    const float* nbl = (l < 3) ? ln1_b + (size_t)(l + 1) * DMODEL : mnb;
    redln_k<8><<<dim3(N), 320, 0, stream>>>(partA, mnD, fc2_b + (size_t)l * DMODEL,
                                            x, nsl, nbl, h);
  }

  // merger (h already = LN(x; mns,mnb), viewed as [512][5120])
  const int Mm = N / 4;  // 512
  wconv_k<<<dim3(FDIM / 32, FDIM / 32), 256, 0, stream>>>(mf1w, mfc1T, FDIM, FDIM);
  // mfc1 split-K=8 (320 blocks, NT=10); reduce + bias + gelu -> mf
  gemm_big(stream, 0, h, mfc1T, nullptr, partA, Mm, FDIM, FDIM, FDIM, FDIM, FDIM, 8);
  reduce_k<8, 0, 1, 1><<<dim3((int)(((long long)Mm * FDIM / 4 + 255) / 256)), 256, 0, stream>>>(
      partA, (long long)Mm * FDIM, FDIM, mf1b, nullptr, mf);
  wconv_k<<<dim3(2048 / 32, FDIM / 32), 256, 0, stream>>>(mf2w, mfc2T, FDIM, 2048);
  // mfc2 split-K=16 (256 blocks)
  gemm_big(stream, 0, mf, mfc2T, nullptr, part, Mm, 2048, FDIM, FDIM, FDIM, 2048, 16);
  reduce_k<16, 0, 0, 0><<<dim3((int)(((long long)Mm * 2048 / 4 + 255) / 256)), 256, 0, stream>>>(
      part, (long long)Mm * 2048, 2048, mf2b, nullptr, out);
}

// Round 6
// 1440.780 us; speedup vs baseline: 1.0533x; 1.0533x over previous
//
#include <hip/hip_runtime.h>
#include <math.h>

#define DMODEL 1280
#define NHEADS 16
#define FDIM   5120
#define GPOS   48
#define SEG    512

typedef __attribute__((ext_vector_type(8))) short bf16x8;
typedef __attribute__((ext_vector_type(4))) float f32x4;
typedef unsigned short u16;

__device__ __forceinline__ u16 f2bf(float f) {
  unsigned int u = __float_as_uint(f);
  u = (u + 0x7FFFu + ((u >> 16) & 1u)) >> 16;  // RNE
  return (u16)u;
}
__device__ __forceinline__ float bf2f(u16 u) {
  return __uint_as_float((unsigned int)u << 16);
}
__device__ __forceinline__ float gelu_tanh(float x) {
  float u = 0.7978845608028654f * (x + 0.044715f * x * x * x);
  float t = __expf(2.f * u);
  float th = 1.f - 2.f / (t + 1.f);
  return 0.5f * x * (1.f + th);
}

typedef const __attribute__((address_space(1))) unsigned int* gas_t;
typedef __attribute__((address_space(3))) unsigned int* las_t;
__device__ __forceinline__ void async16(const void* g, void* l) {
  __builtin_amdgcn_global_load_lds((gas_t)g, (las_t)l, 16, 0, 0);
}

// Bijective XCD chunk remap (T1, m204 form): blocks b with b%8==k form XCD-k's
// contiguous logical range. Requires only that the result is a bijection.
__device__ __forceinline__ int xcd_remap(int b, int nwg) {
  int q = nwg >> 3, r = nwg & 7, x = b & 7, d = b >> 3;
  return (x < r ? x * (q + 1) : r * (q + 1) + (x - r) * q) + d;
}

// ---------------------------------------------------------------------------
// gemm256: 256x256 tile, BK=64, 8 waves (2Mx4N), 128 KiB dbuf LDS, phased
// schedule with counted vmcnt, R2-verified swizzle and schedule (measured
// best; R3 swizzle / R4 deep-prefetch / R5 split-rebalance all regressed).
// NEW: XCD-aware bijective block swizzle so blocks sharing a B n-panel run
// on the same XCD L2 (GEMMs are refetch-traffic bound, not schedule bound).
// A:[M][K] bf16, B:[N][K] bf16, C = A.B^T.
// EPI 0: bf16 partial planes (split-K). EPI 1: +bias bf16. EPI 3: +bias+gelu.
// ---------------------------------------------------------------------------
#define STG256(mat, PW, ldx, h, kk, pp)                          \
  do {                                                           \
    const u16* g_ = (PW) + (long long)(h) * 128 * (ldx) + (kk);  \
    async16(g_, &L[pp][mat][h][(w * 2 + 0) * 512]);              \
    async16(g_ + 32, &L[pp][mat][h][(w * 2 + 1) * 512]);         \
  } while (0)

#define MM256(ii, ff)                                                          \
  acc[ii][ff] = __builtin_amdgcn_mfma_f32_16x16x32_bf16(aR[(ii) & 3][0],       \
                    bR[ff][0], acc[ii][ff], 0, 0, 0);                          \
  acc[ii][ff] = __builtin_amdgcn_mfma_f32_16x16x32_bf16(aR[(ii) & 3][1],       \
                    bR[ff][1], acc[ii][ff], 0, 0, 0);

#define BAR256() asm volatile("s_barrier" ::: "memory")
#define LGKM0() asm volatile("s_waitcnt lgkmcnt(0)" ::: "memory")

template <int EPI>
__global__ __launch_bounds__(512, 2) void gemm256(
    const u16* __restrict__ A, const u16* __restrict__ B,
    const float* __restrict__ bias, void* __restrict__ Cv,
    int Kd, int lda, int ldb, int ldc, int nsplit, long long pstride) {
  __shared__ __align__(16) u16 L[2][2][2][8192];  // [buf][A/B][half][16KB]
  const int sp = blockIdx.z;
  const int Ks = Kd / nsplit;
  const int NT = Ks >> 6;
  const u16* Ab = A + (long long)sp * Ks;
  const u16* Bb = B + (long long)sp * Ks;
  // T1: remap (x,y) within the split plane; pure bijection.
  const int gx = gridDim.x;
  const int lg = xcd_remap(blockIdx.x + gx * blockIdx.y, gx * gridDim.y);
  const int m0 = (lg % gx) * 256, n0 = (lg / gx) * 256;
  const int t = threadIdx.x, ln = t & 63, w = t >> 6;
  const int wr = w >> 2, wc = w & 3;
  const int m16 = ln & 15, q = ln >> 4;
  const int r16 = ln >> 2;
  const int csw = (ln & 3) ^ ((ln >> 5) << 1);
  const int rbase = m16 * 32 + (q ^ ((m16 >> 3) << 1)) * 8;

  const u16* Aw = Ab + (long long)(m0 + w * 16 + r16) * lda + csw * 8;
  const u16* Bw = Bb + (long long)(n0 + w * 16 + r16) * ldb + csw * 8;

  f32x4 acc[8][4];
#pragma unroll
  for (int i = 0; i < 8; i++)
#pragma unroll
    for (int j = 0; j < 4; j++)
#pragma unroll
      for (int r = 0; r < 4; r++) acc[i][j][r] = 0.f;

  STG256(0, Aw, lda, 0, 0, 0);
  STG256(0, Aw, lda, 1, 0, 0);
  STG256(1, Bw, ldb, 0, 0, 0);
  STG256(1, Bw, ldb, 1, 0, 0);
  if (NT > 1) {
    STG256(1, Bw, ldb, 0, 64, 1);
    STG256(1, Bw, ldb, 1, 64, 1);
    asm volatile("s_waitcnt vmcnt(4)" ::: "memory");
  } else {
    asm volatile("s_waitcnt vmcnt(0)" ::: "memory");
  }
  BAR256();

  const int wb = (wc & 1) * 4;
  for (int tt = 0; tt < NT; ++tt) {
    const int p = tt & 1;
    const u16* Abuf = &L[p][0][wr][0];
    const u16* Bbuf = &L[p][1][wc >> 1][0];
    bf16x8 aR[4][2], bR[4][2];

    // phase 1
#pragma unroll
    for (int i = 0; i < 4; ++i) {
      aR[i][0] = *(const bf16x8*)(Abuf + (i * 2 + 0) * 512 + rbase);
      aR[i][1] = *(const bf16x8*)(Abuf + (i * 2 + 1) * 512 + rbase);
    }
#pragma unroll
    for (int fc = 0; fc < 2; ++fc) {
      bR[fc][0] = *(const bf16x8*)(Bbuf + ((wb + fc) * 2 + 0) * 512 + rbase);
      bR[fc][1] = *(const bf16x8*)(Bbuf + ((wb + fc) * 2 + 1) * 512 + rbase);
    }
    if (tt + 1 < NT) STG256(0, Aw, lda, 0, (tt + 1) * 64, (tt + 1) & 1);
    BAR256();
    LGKM0();
    __builtin_amdgcn_s_setprio(1);
#pragma unroll
    for (int i = 0; i < 4; ++i) { MM256(i, 0); MM256(i, 1); }
    __builtin_amdgcn_s_setprio(0);
    BAR256();

    // phase 2
#pragma unroll
    for (int fc = 2; fc < 4; ++fc) {
      bR[fc][0] = *(const bf16x8*)(Bbuf + ((wb + fc) * 2 + 0) * 512 + rbase);
      bR[fc][1] = *(const bf16x8*)(Bbuf + ((wb + fc) * 2 + 1) * 512 + rbase);
    }
    if (tt + 1 < NT) STG256(0, Aw, lda, 1, (tt + 1) * 64, (tt + 1) & 1);
    BAR256();
    LGKM0();
    __builtin_amdgcn_s_setprio(1);
#pragma unroll
    for (int i = 0; i < 4; ++i) { MM256(i, 2); MM256(i, 3); }
    __builtin_amdgcn_s_setprio(0);
    BAR256();

    // phase 3
#pragma unroll
    for (int i = 0; i < 4; ++i) {
      aR[i][0] = *(const bf16x8*)(Abuf + ((4 + i) * 2 + 0) * 512 + rbase);
      aR[i][1] = *(const bf16x8*)(Abuf + ((4 + i) * 2 + 1) * 512 + rbase);
    }
    if (tt + 2 < NT) STG256(1, Bw, ldb, 0, (tt + 2) * 64, p);
    BAR256();
    LGKM0();
    __builtin_amdgcn_s_setprio(1);
#pragma unroll
    for (int i = 0; i < 4; ++i) { MM256(4 + i, 2); MM256(4 + i, 3); }
    __builtin_amdgcn_s_setprio(0);
    BAR256();

    // phase 4
    if (tt + 2 < NT) STG256(1, Bw, ldb, 1, (tt + 2) * 64, p);
    BAR256();
    LGKM0();
    __builtin_amdgcn_s_setprio(1);
#pragma unroll
    for (int i = 0; i < 4; ++i) { MM256(4 + i, 0); MM256(4 + i, 1); }
    __builtin_amdgcn_s_setprio(0);
    if (tt + 1 < NT) {
      if (tt + 2 < NT) asm volatile("s_waitcnt vmcnt(4)" ::: "memory");
      else             asm volatile("s_waitcnt vmcnt(0)" ::: "memory");
    }
    BAR256();
  }

#pragma unroll
  for (int fr = 0; fr < 8; fr++) {
#pragma unroll
    for (int r = 0; r < 4; r++) {
      int row = m0 + wr * 128 + fr * 16 + q * 4 + r;
      if (EPI == 0) {
        u16* Cp = (u16*)Cv + (long long)sp * pstride + (long long)row * ldc;
#pragma unroll
        for (int fc = 0; fc < 4; fc++)
          Cp[n0 + wc * 64 + fc * 16 + m16] = f2bf(acc[fr][fc][r]);
      } else if (EPI == 1) {
        u16* Cb = (u16*)Cv + (long long)row * ldc;
#pragma unroll
        for (int fc = 0; fc < 4; fc++) {
          int col = n0 + wc * 64 + fc * 16 + m16;
          Cb[col] = f2bf(acc[fr][fc][r] + bias[col]);
        }
      } else {  // EPI == 3
        u16* Cb = (u16*)Cv + (long long)row * ldc;
#pragma unroll
        for (int fc = 0; fc < 4; fc++) {
          int col = n0 + wc * 64 + fc * 16 + m16;
          Cb[col] = f2bf(gelu_tanh(acc[fr][fc][r] + bias[col]));
        }
      }
    }
  }
}

// ---------------------------------------------------------------------------
// Fused flash attention (R2-verified form) + T1 block swizzle: the 4 q-strip
// blocks of each (head,seg) share 230 KB of K/V; chunking keeps an XCD's
// head-segs resident in its own L2 (8 x 230 KB < 4 MB).
// Grid: (SEG/128, NHEADS*nseg).
// ---------------------------------------------------------------------------
__global__ __launch_bounds__(256) void fattn_k(
    const u16* __restrict__ qr, const u16* __restrict__ kr,
    const u16* __restrict__ vpT, u16* __restrict__ o, int N, float iscale) {
  __shared__ __align__(16) u16 Ks[2][24][512];   // [buf][f*3+kg][16kv x 32hd]
  __shared__ __align__(16) u16 Vs[2][20][512];   // [buf][df*4+kvg][16d x 32kv]
  __shared__ __align__(16) u16 Ps[4][32 * 128];  // per-wave P panel
  const int nseg = N >> 9;
  const int gx = gridDim.x;
  const int lg = xcd_remap(blockIdx.x + gx * blockIdx.y, gx * gridDim.y);
  const int strip = lg % gx, hb = lg / gx;
  const int h = hb / nseg, seg = hb - h * nseg;
  const int t = threadIdx.x, ln = t & 63, w = t >> 6;
  const int m16 = ln & 15, qh = ln >> 4;
  const int r4 = ln >> 2, gsw = (ln & 3) ^ ((ln >> 5) << 1);
  const int rbase = m16 * 32 + ((qh ^ ((m16 >> 3) << 1)) << 3);
  const long long hN = (long long)h * N;
  const int segbase = seg * SEG;
  const int q0 = segbase + strip * 128 + w * 32;

  bf16x8 qf[2][3];
#pragma unroll
  for (int mi = 0; mi < 2; mi++)
#pragma unroll
    for (int ks = 0; ks < 3; ks++)
      qf[mi][ks] = *(const bf16x8*)&qr[(hN + q0 + mi * 16 + m16) * 96 + ks * 32 + qh * 8];

  f32x4 ao[2][5];
#pragma unroll
  for (int mi = 0; mi < 2; mi++)
#pragma unroll
    for (int df = 0; df < 5; df++)
#pragma unroll
      for (int r = 0; r < 4; r++) ao[mi][df][r] = 0.f;
  float m_[2][4], l_[2][4];
#pragma unroll
  for (int mi = 0; mi < 2; mi++)
#pragma unroll
    for (int r = 0; r < 4; r++) { m_[mi][r] = -1e30f; l_[mi][r] = 0.f; }

  auto stage = [&](int c, int pb) {
#pragma unroll
    for (int i = 0; i < 6; i++) {
      int sK = w * 6 + i, f = sK / 3, kg = sK - f * 3;
      async16(&kr[(hN + segbase + c * 128 + f * 16 + r4) * 96 + kg * 32 + gsw * 8],
              &Ks[pb][sK][0]);
    }
#pragma unroll
    for (int i = 0; i < 5; i++) {
      int sV = w * 5 + i, df = sV >> 2, kvg = sV & 3;
      async16(&vpT[((long long)hb * 128 + df * 16 + r4) * SEG + c * 128 + kvg * 32 + gsw * 8],
              &Vs[pb][sV][0]);
    }
  };

  stage(0, 0);
  u16* Pmy = &Ps[w][0];
  for (int c = 0; c < 4; c++) {
    const int pb = c & 1;
    __syncthreads();  // implicit vmcnt(0)+lgkmcnt(0): buf[pb] staged by all waves
    if (c < 3) stage(c + 1, pb ^ 1);

    // QK^T: s[mi][f] rows q=(mi,qh*4+r), cols kv=f*16+m16
    f32x4 s[2][8];
#pragma unroll
    for (int mi = 0; mi < 2; mi++)
#pragma unroll
      for (int f = 0; f < 8; f++)
#pragma unroll
        for (int r = 0; r < 4; r++) s[mi][f][r] = 0.f;
#pragma unroll
    for (int ks = 0; ks < 3; ks++) {
#pragma unroll
      for (int f = 0; f < 8; f++) {
        bf16x8 kf = *(const bf16x8*)&Ks[pb][f * 3 + ks][rbase];
#pragma unroll
        for (int mi = 0; mi < 2; mi++)
          s[mi][f] = __builtin_amdgcn_mfma_f32_16x16x32_bf16(qf[mi][ks], kf, s[mi][f], 0, 0, 0);
      }
    }

    // online softmax per row
#pragma unroll
    for (int mi = 0; mi < 2; mi++) {
#pragma unroll
      for (int r = 0; r < 4; r++) {
        float mx = s[mi][0][r];
#pragma unroll
        for (int f = 1; f < 8; f++) mx = fmaxf(mx, s[mi][f][r]);
        mx *= iscale;
#pragma unroll
        for (int o2 = 1; o2 <= 8; o2 <<= 1) mx = fmaxf(mx, __shfl_xor(mx, o2));
        float mn = fmaxf(m_[mi][r], mx);
        float corr = __expf(m_[mi][r] - mn);
        m_[mi][r] = mn;
        float rs = 0.f;
#pragma unroll
        for (int f = 0; f < 8; f++) {
          float p = __expf(s[mi][f][r] * iscale - mn);
          s[mi][f][r] = p;
          rs += p;
        }
#pragma unroll
        for (int o2 = 1; o2 <= 8; o2 <<= 1) rs += __shfl_xor(rs, o2);
        l_[mi][r] = l_[mi][r] * corr + rs;
#pragma unroll
        for (int df = 0; df < 5; df++) ao[mi][df][r] *= corr;
      }
    }

    // P -> LDS (per-wave private): addr(q,kv)=q*128 + ((kv>>3)^(q&7))*8 + (kv&7)
#pragma unroll
    for (int mi = 0; mi < 2; mi++) {
#pragma unroll
      for (int r = 0; r < 4; r++) {
        int qq = mi * 16 + qh * 4 + r;
        int base = qq * 128 + (m16 & 7);
        int ql = qq & 7;
#pragma unroll
        for (int f = 0; f < 8; f++) {
          int gr = (f * 2 + (m16 >> 3)) ^ ql;
          Pmy[base + gr * 8] = f2bf(s[mi][f][r]);
        }
      }
    }

    // PV: O[q][d] += P[q][kv] V^T[d][kv]
#pragma unroll
    for (int ks = 0; ks < 4; ks++) {
      bf16x8 pf[2];
#pragma unroll
      for (int mi = 0; mi < 2; mi++)
        pf[mi] = *(const bf16x8*)&Pmy[(mi * 16 + m16) * 128 +
                                      (((ks * 4 + qh) ^ (m16 & 7)) << 3)];
#pragma unroll
      for (int df = 0; df < 5; df++) {
        bf16x8 vf = *(const bf16x8*)&Vs[pb][df * 4 + ks][rbase];
#pragma unroll
        for (int mi = 0; mi < 2; mi++)
          ao[mi][df] = __builtin_amdgcn_mfma_f32_16x16x32_bf16(pf[mi], vf, ao[mi][df], 0, 0, 0);
      }
    }
  }

#pragma unroll
  for (int mi = 0; mi < 2; mi++) {
#pragma unroll
    for (int r = 0; r < 4; r++) {
      float rl = 1.f / l_[mi][r];
      long long rowb = (long long)(q0 + mi * 16 + qh * 4 + r) * DMODEL + h * 80;
#pragma unroll
      for (int df = 0; df < 5; df++)
        o[rowb + df * 16 + m16] = f2bf(ao[mi][df][r] * rl);
    }
  }
}

// ---------------------------------------------------------------------------
// Split-K reduce + epilogue (bf16 partials): out = [gelu](sum + bias) [+ res]
// ---------------------------------------------------------------------------
template <int S, int RES, int GELU, int OUTBF>
__global__ void reduce_k(const u16* __restrict__ Pp, long long mn, int Nn,
                         const float* __restrict__ bias,
                         const float* __restrict__ res, void* __restrict__ out) {
  long long i = ((long long)blockIdx.x * 256 + threadIdx.x) * 4;
  if (i >= mn) return;
  float vx = 0.f, vy = 0.f, vz = 0.f, vw = 0.f;
#pragma unroll
  for (int s = 0; s < S; s++) {
    ushort4 u4 = *(const ushort4*)(Pp + (long long)s * mn + i);
    vx += bf2f(u4.x); vy += bf2f(u4.y); vz += bf2f(u4.z); vw += bf2f(u4.w);
  }
  int col = (int)(i % Nn);
  vx += bias[col]; vy += bias[col + 1]; vz += bias[col + 2]; vw += bias[col + 3];
  if (GELU) {
    vx = gelu_tanh(vx); vy = gelu_tanh(vy);
    vz = gelu_tanh(vz); vw = gelu_tanh(vw);
  }
  if (RES) {
    float4 r4 = *(const float4*)(res + i);
    vx += r4.x; vy += r4.y; vz += r4.z; vw += r4.w;
  }
  if (OUTBF) {
    ushort4 o; o.x = f2bf(vx); o.y = f2bf(vy); o.z = f2bf(vz); o.w = f2bf(vw);
    *(ushort4*)((u16*)out + i) = o;
  } else {
    float4 o; o.x = vx; o.y = vy; o.z = vz; o.w = vw;
    *(float4*)((float*)out + i) = o;
  }
}

// ---------------------------------------------------------------------------
// Fused split-K reduce + residual + LayerNorm: one 320-thread block per row.
// ---------------------------------------------------------------------------
template <int S>
__global__ void redln_k(const u16* __restrict__ Pp, long long mn,
                        const float* __restrict__ bias,
                        float* __restrict__ x,
                        const float* __restrict__ s, const float* __restrict__ b,
                        u16* __restrict__ h) {
  int row = blockIdx.x;
  int d = threadIdx.x * 4;
  long long base = (long long)row * DMODEL + d;
  float vx = 0.f, vy = 0.f, vz = 0.f, vw = 0.f;
#pragma unroll
  for (int si = 0; si < S; si++) {
    ushort4 u4 = *(const ushort4*)(Pp + (long long)si * mn + base);
    vx += bf2f(u4.x); vy += bf2f(u4.y); vz += bf2f(u4.z); vw += bf2f(u4.w);
  }
  vx += bias[d]; vy += bias[d + 1]; vz += bias[d + 2]; vw += bias[d + 3];
  float4 r4 = *(const float4*)(x + base);
  vx += r4.x; vy += r4.y; vz += r4.z; vw += r4.w;
  float4 xv; xv.x = vx; xv.y = vy; xv.z = vz; xv.w = vw;
  *(float4*)(x + base) = xv;
  float sum = vx + vy + vz + vw;
#pragma unroll
  for (int o = 32; o; o >>= 1) sum += __shfl_xor(sum, o);
  __shared__ float red[8];
  int wv = threadIdx.x >> 6, lnn = threadIdx.x & 63;
  if (lnn == 0) red[wv] = sum;
  __syncthreads();
  float mu = 0.f;
  for (int i = 0; i < 5; i++) mu += red[i];
  mu *= (1.f / DMODEL);
  float dx = vx - mu, dy = vy - mu, dz = vz - mu, dw = vw - mu;
  float s2 = dx * dx + dy * dy + dz * dz + dw * dw;
#pragma unroll
  for (int o = 32; o; o >>= 1) s2 += __shfl_xor(s2, o);
  __syncthreads();
  if (lnn == 0) red[wv] = s2;
  __syncthreads();
  float var = 0.f;
  for (int i = 0; i < 5; i++) var += red[i];
  var *= (1.f / DMODEL);
  float rs = rsqrtf(var + 1e-6f);
  ushort4 o4;
  o4.x = f2bf(dx * rs * s[d] + b[d]);
  o4.y = f2bf(dy * rs * s[d + 1] + b[d + 1]);
  o4.z = f2bf(dz * rs * s[d + 2] + b[d + 2]);
  o4.w = f2bf(dw * rs * s[d + 3] + b[d + 3]);
  *(ushort4*)(h + base) = o4;
}

// ---------------------------------------------------------------------------
// Weight convert+transpose: in fp32 [K][N] -> out bf16 [N][K]. 32x32 tiles.
// ---------------------------------------------------------------------------
__global__ void wconv_k(const float* __restrict__ in, u16* __restrict__ out,
                        int K, int N) {
  __shared__ float tl[32][33];
  int n0 = blockIdx.x * 32, k0 = blockIdx.y * 32;
  int t = threadIdx.x;
  int r = t >> 5, c = t & 31;
#pragma unroll
  for (int i = 0; i < 4; i++)
    tl[r + 8 * i][c] = in[(long long)(k0 + r + 8 * i) * N + n0 + c];
  __syncthreads();
  int n = t >> 4, kp = (t & 15) * 2;
#pragma unroll
  for (int i = 0; i < 2; i++) {
    ushort2 o;
    o.x = f2bf(tl[kp][n + 16 * i]);
    o.y = f2bf(tl[kp + 1][n + 16 * i]);
    *(ushort2*)&out[(long long)(n0 + n + 16 * i) * K + k0 + kp] = o;
  }
}

// fp32 -> bf16 flat copy
__global__ void conv_k(const float* __restrict__ in, u16* __restrict__ out,
                       long long n) {
  long long i = ((long long)blockIdx.x * 256 + threadIdx.x) * 4;
  if (i >= n) return;
  float4 v = *(const float4*)(in + i);
  ushort4 o; o.x = f2bf(v.x); o.y = f2bf(v.y); o.z = f2bf(v.z); o.w = f2bf(v.w);
  *(ushort4*)&out[i] = o;
}

// V transpose per batch: in bf16 [b][512][128] -> out bf16 [b][128][512]
union U16x8 { uint4 v; u16 s[8]; };
__global__ void vtr_k(const u16* __restrict__ in, u16* __restrict__ out) {
  __shared__ u16 tl[64][65];
  int b = blockIdx.z;
  int m0 = blockIdx.x * 64;
  int d0 = blockIdx.y * 64;
  const u16* ib = in + (long long)b * SEG * 128;
  u16* ob = out + (long long)b * 128 * SEG;
  int t = threadIdx.x;
  int r = t >> 3, c8 = (t & 7) * 8;
#pragma unroll
  for (int i = 0; i < 2; i++) {
    U16x8 ld;
    ld.v = *(const uint4*)&ib[(long long)(m0 + r + 32 * i) * 128 + d0 + c8];
#pragma unroll
    for (int j = 0; j < 8; j++) tl[r + 32 * i][c8 + j] = ld.s[j];
  }
  __syncthreads();
  int d = t >> 3, m8 = (t & 7) * 8;
#pragma unroll
  for (int i = 0; i < 2; i++) {
    int dd = d + 32 * i;
    U16x8 st;
#pragma unroll
    for (int j = 0; j < 8; j++) st.s[j] = tl[m8 + j][dd];
    *(uint4*)&ob[(long long)(d0 + dd) * SEG + m0 + m8] = st.v;
  }
}

// ---------------------------------------------------------------------------
__global__ void coords_k(const int* __restrict__ g, int nimg,
                         int* __restrict__ rw, int* __restrict__ cl,
                         int* __restrict__ hh, int* __restrict__ ww, int N) {
  int t = blockIdx.x * 256 + threadIdx.x;
  if (t >= N) return;
  int c = 0, local = 0, H = 1, W = 1;
  for (int i = 0; i < nimg; i++) {
    int tpi = g[i * 3] * g[i * 3 + 1] * g[i * 3 + 2];
    if (t >= c && t < c + tpi) { local = t - c; H = g[i * 3 + 1]; W = g[i * 3 + 2]; }
    c += tpi;
  }
  int hw = H * W;
  int sp = local % hw;
  int mw = W >> 1;
  int gr = sp >> 2, intra = sp & 3;
  rw[t] = (gr / mw) * 2 + (intra >> 1);
  cl[t] = (gr % mw) * 2 + (intra & 1);
  hh[t] = H; ww[t] = W;
}

__global__ void peadd_k(float* __restrict__ x, const float* __restrict__ pe,
                        const int* __restrict__ rw, const int* __restrict__ cl,
                        const int* __restrict__ hh, const int* __restrict__ ww) {
  int n = blockIdx.x;
  int d = threadIdx.x * 4;
  int H = hh[n], W = ww[n];
  float rf = (H > 1) ? (float)rw[n] * (float)(GPOS - 1) / (float)(H - 1) : 0.f;
  float cf = (W > 1) ? (float)cl[n] * (float)(GPOS - 1) / (float)(W - 1) : 0.f;
  int r0 = (int)floorf(rf), c0 = (int)floorf(cf);
  int r1 = min(r0 + 1, GPOS - 1), c1 = min(c0 + 1, GPOS - 1);
  float wr = rf - (float)r0, wc = cf - (float)c0;
  float w00 = (1.f - wr) * (1.f - wc), w01 = (1.f - wr) * wc;
  float w10 = wr * (1.f - wc), w11 = wr * wc;
  float4 v00 = *(const float4*)(pe + (long long)(r0 * GPOS + c0) * DMODEL + d);
  float4 v01 = *(const float4*)(pe + (long long)(r0 * GPOS + c1) * DMODEL + d);
  float4 v10 = *(const float4*)(pe + (long long)(r1 * GPOS + c0) * DMODEL + d);
  float4 v11 = *(const float4*)(pe + (long long)(r1 * GPOS + c1) * DMODEL + d);
  float4 xv = *(float4*)(x + (long long)n * DMODEL + d);
  xv.x += w00 * v00.x + w01 * v01.x + w10 * v10.x + w11 * v11.x;
  xv.y += w00 * v00.y + w01 * v01.y + w10 * v10.y + w11 * v11.y;
  xv.z += w00 * v00.z + w01 * v01.z + w10 * v10.z + w11 * v11.z;
  xv.w += w00 * v00.w + w01 * v01.w + w10 * v10.w + w11 * v11.w;
  *(float4*)(x + (long long)n * DMODEL + d) = xv;
}

// LayerNorm fp32 in -> bf16 out (one 320-thread block per row of 1280)
__global__ void ln_k(const float* __restrict__ X, u16* __restrict__ Y,
                     const float* __restrict__ s, const float* __restrict__ b) {
  int row = blockIdx.x;
  int d = threadIdx.x * 4;
  const float* x = X + (long long)row * DMODEL;
  float4 v = *(const float4*)(x + d);
  float sum = v.x + v.y + v.z + v.w;
#pragma unroll
  for (int o = 32; o; o >>= 1) sum += __shfl_xor(sum, o);
  __shared__ float red[8];
  int wv = threadIdx.x >> 6, lnn = threadIdx.x & 63;
  if (lnn == 0) red[wv] = sum;
  __syncthreads();
  float mu = 0.f;
  for (int i = 0; i < 5; i++) mu += red[i];
  mu *= (1.f / DMODEL);
  float dx = v.x - mu, dy = v.y - mu, dz = v.z - mu, dw = v.w - mu;
  float s2 = dx * dx + dy * dy + dz * dz + dw * dw;
#pragma unroll
  for (int o = 32; o; o >>= 1) s2 += __shfl_xor(s2, o);
  __syncthreads();
  if (lnn == 0) red[wv] = s2;
  __syncthreads();
  float var = 0.f;
  for (int i = 0; i < 5; i++) var += red[i];
  var *= (1.f / DMODEL);
  float rs = rsqrtf(var + 1e-6f);
  ushort4 o4;
  o4.x = f2bf(dx * rs * s[d] + b[d]);
  o4.y = f2bf(dy * rs * s[d + 1] + b[d + 1]);
  o4.z = f2bf(dz * rs * s[d + 2] + b[d + 2]);
  o4.w = f2bf(dw * rs * s[d + 3] + b[d + 3]);
  *(ushort4*)(Y + (long long)row * DMODEL + d) = o4;
}

// RoPE from bf16 qkv -> qr/kr bf16 [h][N][96] (zero pad), v -> vp [h][N][128]
__global__ void rope_k(const u16* __restrict__ qkv, const int* __restrict__ rw,
                       const int* __restrict__ cl, u16* __restrict__ qr,
                       u16* __restrict__ kr, u16* __restrict__ vp, int N) {
  int n = blockIdx.x, h = blockIdx.y, t = threadIdx.x;
  const u16* src = qkv + (long long)n * (3 * DMODEL) + h * 80;
  long long ob96 = ((long long)h * N + n) * 96;
  long long ob128 = ((long long)h * N + n) * 128;
  if (t < 40) {
    float pos = (t < 20) ? (float)rw[n] : (float)cl[n];
    float infr = exp2f(-13.287712379549449f * (float)(t % 20) * 0.05f);
    float f = pos * infr;
    float cs = cosf(f), sn = sinf(f);
    float q0 = bf2f(src[t]), q1 = bf2f(src[t + 40]);
    qr[ob96 + t] = f2bf(q0 * cs - q1 * sn);
    qr[ob96 + t + 40] = f2bf(q1 * cs + q0 * sn);
    float k0 = bf2f(src[DMODEL + t]), k1 = bf2f(src[DMODEL + t + 40]);
    kr[ob96 + t] = f2bf(k0 * cs - k1 * sn);
    kr[ob96 + t + 40] = f2bf(k1 * cs + k0 * sn);
    vp[ob128 + t] = src[2 * DMODEL + t];
    vp[ob128 + t + 40] = src[2 * DMODEL + t + 40];
  } else {
    int u = t - 40;
    if (u < 16) { qr[ob96 + 80 + u] = 0; kr[ob96 + 80 + u] = 0; }
    vp[ob128 + 80 + u] = 0;
    vp[ob128 + 104 + u] = 0;
  }
}

// ---------------------------------------------------------------------------
// 256x256-tile path: M%256==0, Nn%256==0, (Kd/nsplit)%64==0.
static void gemm_big(hipStream_t st, int epi, const u16* A, const u16* B,
                     const float* bias, void* C, int M, int Nn, int Kd,
                     int lda, int ldb, int ldc, int nsplit) {
  dim3 g(M / 256, Nn / 256, nsplit), blk(512);
  long long ps = (long long)M * Nn;
  switch (epi) {
    case 0: gemm256<0><<<g, blk, 0, st>>>(A, B, bias, C, Kd, lda, ldb, ldc, nsplit, ps); break;
    case 1: gemm256<1><<<g, blk, 0, st>>>(A, B, bias, C, Kd, lda, ldb, ldc, nsplit, ps); break;
    default: gemm256<3><<<g, blk, 0, st>>>(A, B, bias, C, Kd, lda, ldb, ldc, nsplit, ps); break;
  }
}

extern "C" void kernel_launch(void* const* d_in, const int* in_sizes, int n_in,
                              void* d_out, int out_size, void* d_ws, size_t ws_size,
                              hipStream_t stream) {
  const float* pixels = (const float*)d_in[0];
  const int* grid_thw = (const int*)d_in[1];
  const float* pos_embed = (const float*)d_in[2];
  const float* patch_w = (const float*)d_in[3];
  const float* patch_b = (const float*)d_in[4];
  const float* ln1_s = (const float*)d_in[5];
  const float* ln1_b = (const float*)d_in[6];
  const float* qkv_w = (const float*)d_in[7];
  const float* qkv_b = (const float*)d_in[8];
  const float* proj_w = (const float*)d_in[9];
  const float* proj_b = (const float*)d_in[10];
  const float* ln2_s = (const float*)d_in[11];
  const float* ln2_b = (const float*)d_in[12];
  const float* fc1_w = (const float*)d_in[13];
  const float* fc1_b = (const float*)d_in[14];
  const float* fc2_w = (const float*)d_in[15];
  const float* fc2_b = (const float*)d_in[16];
  const float* mns = (const float*)d_in[17];
  const float* mnb = (const float*)d_in[18];
  const float* mf1w = (const float*)d_in[19];
  const float* mf1b = (const float*)d_in[20];
  const float* mf2w = (const float*)d_in[21];
  const float* mf2b = (const float*)d_in[22];
  float* out = (float*)d_out;

  const int N = in_sizes[0] / 1536;  // 2048
  const int nimg = in_sizes[1] / 3;  // 4
  const int nseg = N / SEG;          // 4
  const int nb = NHEADS * nseg;      // 64

  char* w = (char*)d_ws;
  size_t off = 0;
  auto alloc = [&](size_t bytes) -> void* {
    void* p = w + off;
    off += (bytes + 255) & ~(size_t)255;
    return p;
  };
  int* rw = (int*)alloc((size_t)N * 4);
  int* cl = (int*)alloc((size_t)N * 4);
  int* hh = (int*)alloc((size_t)N * 4);
  int* ww = (int*)alloc((size_t)N * 4);
  float* x = (float*)alloc((size_t)N * DMODEL * 4);
  u16* h = (u16*)alloc((size_t)N * DMODEL * 2);
  u16* pixbf = (u16*)alloc((size_t)N * 1536 * 2);      // mfc2T overlay base
  u16* patchT = (u16*)alloc((size_t)DMODEL * 1536 * 2);
  u16* qkvT = (u16*)alloc((size_t)3 * DMODEL * DMODEL * 2);
  u16* projT = (u16*)alloc((size_t)DMODEL * DMODEL * 2);
  u16* fc1T = (u16*)alloc((size_t)FDIM * DMODEL * 2);
  u16* fc2T = (u16*)alloc((size_t)DMODEL * FDIM * 2);
  u16* qkvb = (u16*)alloc((size_t)N * 3 * DMODEL * 2);  // mfc1T overlay base
  u16* qr = (u16*)alloc((size_t)NHEADS * N * 96 * 2);
  u16* kr = (u16*)alloc((size_t)NHEADS * N * 96 * 2);
  u16* vp = (u16*)alloc((size_t)NHEADS * N * 128 * 2);
  u16* vpT = (u16*)alloc((size_t)NHEADS * N * 128 * 2);
  u16* pad0 = (u16*)alloc((size_t)nb * 2 * SEG * 128 * 2);  // keeps mfc1T overlay in bounds
  u16* o = (u16*)alloc((size_t)N * DMODEL * 2);
  float* bigA = (float*)alloc((size_t)nb * SEG * SEG * 4);  // ffb / mf
  float* bigB = (float*)alloc((size_t)nb * SEG * SEG * 2);  // split-K partials
  (void)ws_size; (void)pad0;
  // overlays (lifetimes disjoint with originals)
  u16* mfc1T = qkvb;         // 52.4 MB over qkvb..pad0 region
  u16* mfc2T = pixbf;        // 21.0 MB over pixbf..projT
  u16* ffb = (u16*)bigA;     // fc1 out, 21 MB at bigA base
  u16* mf = (u16*)bigA;      // merger hidden 5.2 MB at bigA base
  u16* part = (u16*)bigB;    // split-K bf16 partial planes (<= 33.5 MB)

  const float iscale = 0.11180339887498949f;  // 80^-0.5
  const long long mnD = (long long)N * DMODEL;

  coords_k<<<dim3((N + 255) / 256), 256, 0, stream>>>(grid_thw, nimg, rw, cl, hh, ww, N);
  conv_k<<<dim3((int)(((long long)N * 1536 / 4 + 255) / 256)), 256, 0, stream>>>(
      pixels, pixbf, (long long)N * 1536);
  wconv_k<<<dim3(DMODEL / 32, 1536 / 32), 256, 0, stream>>>(patch_w, patchT, 1536, DMODEL);
  // patch embed, split-K=4 (160 blocks)
  gemm_big(stream, 0, pixbf, patchT, nullptr, part, N, DMODEL, 1536, 1536, 1536,
           DMODEL, 4);
  reduce_k<4, 0, 0, 0><<<dim3((int)((mnD / 4 + 255) / 256)), 256, 0, stream>>>(
      part, mnD, DMODEL, patch_b, nullptr, x);
  peadd_k<<<dim3(N), 320, 0, stream>>>(x, pos_embed, rw, cl, hh, ww);
  // ln1 of layer 0 (subsequent LNs fused into split-K reduces)
  ln_k<<<dim3(N), 320, 0, stream>>>(x, h, ln1_s, ln1_b);

  for (int l = 0; l < 4; l++) {
    wconv_k<<<dim3(3 * DMODEL / 32, DMODEL / 32), 256, 0, stream>>>(
        qkv_w + (size_t)l * DMODEL * 3 * DMODEL, qkvT, DMODEL, 3 * DMODEL);
    wconv_k<<<dim3(DMODEL / 32, DMODEL / 32), 256, 0, stream>>>(
        proj_w + (size_t)l * DMODEL * DMODEL, projT, DMODEL, DMODEL);
    wconv_k<<<dim3(FDIM / 32, DMODEL / 32), 256, 0, stream>>>(
        fc1_w + (size_t)l * DMODEL * FDIM, fc1T, DMODEL, FDIM);
    wconv_k<<<dim3(DMODEL / 32, FDIM / 32), 256, 0, stream>>>(
        fc2_w + (size_t)l * FDIM * DMODEL, fc2T, FDIM, DMODEL);

    // qkv direct +bias (120 blocks, NT=20, no split / no reduce)
    gemm_big(stream, 1, h, qkvT, qkv_b + (size_t)l * 3 * DMODEL, qkvb, N,
             3 * DMODEL, DMODEL, DMODEL, DMODEL, 3 * DMODEL, 1);
    rope_k<<<dim3(N, NHEADS), 64, 0, stream>>>(qkvb, rw, cl, qr, kr, vp, N);
    vtr_k<<<dim3(8, 2, nb), 256, 0, stream>>>(vp, vpT);
    // fused flash attention -> o (256 blocks, 1/CU, XCD-chunked)
    fattn_k<<<dim3(SEG / 128, nb), 256, 0, stream>>>(qr, kr, vpT, o, N, iscale);
    // proj split-K=4 (160 blocks); fused reduce + bias + residual + ln2 -> h
    gemm_big(stream, 0, o, projT, nullptr, part, N, DMODEL, DMODEL, DMODEL,
             DMODEL, DMODEL, 4);
    redln_k<4><<<dim3(N), 320, 0, stream>>>(part, mnD, proj_b + (size_t)l * DMODEL,
                                            x, ln2_s + (size_t)l * DMODEL,
                                            ln2_b + (size_t)l * DMODEL, h);
    // fc1 fused bias+gelu -> bf16 (160 blocks, NT=20, direct)
    gemm_big(stream, 3, h, fc1T, fc1_b + (size_t)l * FDIM, ffb, N, FDIM, DMODEL,
             DMODEL, DMODEL, FDIM, 1);
    // fc2 split-K=4 (160 blocks); fused reduce + bias + residual + next LN -> h
    gemm_big(stream, 0, ffb, fc2T, nullptr, part, N, DMODEL, FDIM, FDIM, FDIM,
             DMODEL, 4);
    const float* nsl = (l < 3) ? ln1_s + (size_t)(l + 1) * DMODEL : mns;
    const float* nbl = (l < 3) ? ln1_b + (size_t)(l + 1) * DMODEL : mnb;
    redln_k<4><<<dim3(N), 320, 0, stream>>>(part, mnD, fc2_b + (size_t)l * DMODEL,
                                            x, nsl, nbl, h);
  }

  // merger (h already = LN(x; mns,mnb), viewed as [512][5120])
  const int Mm = N / 4;  // 512
  wconv_k<<<dim3(FDIM / 32, FDIM / 32), 256, 0, stream>>>(mf1w, mfc1T, FDIM, FDIM);
  // mfc1 split-K=4 (160 blocks); reduce + bias + gelu -> mf
  gemm_big(stream, 0, h, mfc1T, nullptr, part, Mm, FDIM, FDIM, FDIM, FDIM, FDIM, 4);
  reduce_k<4, 0, 1, 1><<<dim3((int)(((long long)Mm * FDIM / 4 + 255) / 256)), 256, 0, stream>>>(
      part, (long long)Mm * FDIM, FDIM, mf1b, nullptr, mf);
  wconv_k<<<dim3(2048 / 32, FDIM / 32), 256, 0, stream>>>(mf2w, mfc2T, FDIM, 2048);
  // mfc2 split-K=16 (256 blocks)
  gemm_big(stream, 0, mf, mfc2T, nullptr, part, Mm, 2048, FDIM, FDIM, FDIM, 2048, 16);
  reduce_k<16, 0, 0, 0><<<dim3((int)(((long long)Mm * 2048 / 4 + 255) / 256)), 256, 0, stream>>>(
      part, (long long)Mm * 2048, 2048, mf2b, nullptr, out);
}

// Round 7
// 1365.659 us; speedup vs baseline: 1.1112x; 1.0550x over previous
//
#include <hip/hip_runtime.h>
#include <math.h>

#define DMODEL 1280
#define NHEADS 16
#define FDIM   5120
#define GPOS   48
#define SEG    512

typedef __attribute__((ext_vector_type(8))) short bf16x8;
typedef __attribute__((ext_vector_type(4))) float f32x4;
typedef unsigned short u16;

__device__ __forceinline__ u16 f2bf(float f) {
  unsigned int u = __float_as_uint(f);
  u = (u + 0x7FFFu + ((u >> 16) & 1u)) >> 16;  // RNE
  return (u16)u;
}
__device__ __forceinline__ float bf2f(u16 u) {
  return __uint_as_float((unsigned int)u << 16);
}
__device__ __forceinline__ float gelu_tanh(float x) {
  float u = 0.7978845608028654f * (x + 0.044715f * x * x * x);
  float t = __expf(2.f * u);
  float th = 1.f - 2.f / (t + 1.f);
  return 0.5f * x * (1.f + th);
}

typedef const __attribute__((address_space(1))) unsigned int* gas_t;
typedef __attribute__((address_space(3))) unsigned int* las_t;
__device__ __forceinline__ void async16(const void* g, void* l) {
  __builtin_amdgcn_global_load_lds((gas_t)g, (las_t)l, 16, 0, 0);
}

// Bijective XCD chunk remap (T1, m204 form).
__device__ __forceinline__ int xcd_remap(int b, int nwg) {
  int q = nwg >> 3, r = nwg & 7, x = b & 7, d = b >> 3;
  return (x < r ? x * (q + 1) : r * (q + 1) + (x - r) * q) + d;
}

// ---------------------------------------------------------------------------
// gemm128: 128x128 tile, BK=64, 4 waves (2Mx2N), 64 KiB dbuf LDS ->
// **2 blocks/CU co-resident** (the m97/m102/m114 mechanism: a co-resident
// block's MFMA waves hide this block's barrier drains; our previous 256²
// kernel's 128 KiB LDS forced 1/CU and grids of 120-160 left half the CUs
// idle with zero overlap). Same verified R2 subtile swizzle ([16][32]
// subtiles, csw/rbase) and the same counted-vmcnt 4-phase dependency
// structure: A(t+1)->other buf in ph1/2, B(t+2)->current buf in ph3/4
// (B(t) reads complete at ph2-end barrier), tile-end vmcnt(4).
// Per-element accumulation order identical to the 256² kernel (same BK
// sequence, kh0->kh1) -> bit-identical results expected.
// A:[M][K] bf16, B:[N][K] bf16, C = A.B^T.
// EPI 0: bf16 partial planes (split-K). EPI 1: +bias bf16. EPI 3: +bias+gelu.
// ---------------------------------------------------------------------------
#define STG1(mat, PW, ldx, rb, kh, kk, pp)                                  \
  async16((PW) + (long long)(rb) * 16 * (ldx) + (kk) + (kh) * 32,           \
          &L[pp][mat][((rb) * 2 + (kh)) * 512])

#define MM1(ii, ff)                                                          \
  acc[ii][ff] = __builtin_amdgcn_mfma_f32_16x16x32_bf16(aR[ii][0],           \
                    bR[ff][0], acc[ii][ff], 0, 0, 0);                        \
  acc[ii][ff] = __builtin_amdgcn_mfma_f32_16x16x32_bf16(aR[ii][1],           \
                    bR[ff][1], acc[ii][ff], 0, 0, 0);

#define BARX() asm volatile("s_barrier" ::: "memory")
#define LGKM0() asm volatile("s_waitcnt lgkmcnt(0)" ::: "memory")

template <int EPI>
__global__ __launch_bounds__(256, 2) void gemm128(
    const u16* __restrict__ A, const u16* __restrict__ B,
    const float* __restrict__ bias, void* __restrict__ Cv,
    int Kd, int lda, int ldb, int ldc, int nsplit, long long pstride) {
  __shared__ __align__(16) u16 L[2][2][8192];  // [buf][A|B][8rb x 2kh x 512]
  const int sp = blockIdx.z;
  const int Ks = Kd / nsplit;
  const int NT = Ks >> 6;
  const u16* Ab = A + (long long)sp * Ks;
  const u16* Bb = B + (long long)sp * Ks;
  const int gx = gridDim.x;
  const int lg = xcd_remap(blockIdx.x + gx * blockIdx.y, gx * gridDim.y);
  const int m0 = (lg % gx) * 128, n0 = (lg / gx) * 128;
  const int t = threadIdx.x, ln = t & 63, w = t >> 6;
  const int wr = w >> 1, wc = w & 1;
  const int m16 = ln & 15, q = ln >> 4;
  const int r16 = ln >> 2;
  const int csw = (ln & 3) ^ ((ln >> 5) << 1);               // R2 source swz
  const int rbase = m16 * 32 + (q ^ ((m16 >> 3) << 1)) * 8;  // R2 read swz

  const u16* Aw = Ab + (long long)(m0 + r16) * lda + csw * 8;
  const u16* Bw = Bb + (long long)(n0 + r16) * ldb + csw * 8;
  const int w4 = w + 4;

  f32x4 acc[4][4];
#pragma unroll
  for (int i = 0; i < 4; i++)
#pragma unroll
    for (int j = 0; j < 4; j++)
#pragma unroll
      for (int r = 0; r < 4; r++) acc[i][j][r] = 0.f;

  // prologue: tile0 A+B (8 loads) + B(t1) (4 loads); vmcnt(4) -> t0 landed.
  STG1(0, Aw, lda, w, 0, 0, 0);  STG1(0, Aw, lda, w, 1, 0, 0);
  STG1(0, Aw, lda, w4, 0, 0, 0); STG1(0, Aw, lda, w4, 1, 0, 0);
  STG1(1, Bw, ldb, w, 0, 0, 0);  STG1(1, Bw, ldb, w, 1, 0, 0);
  STG1(1, Bw, ldb, w4, 0, 0, 0); STG1(1, Bw, ldb, w4, 1, 0, 0);
  if (NT > 1) {
    STG1(1, Bw, ldb, w, 0, 64, 1);  STG1(1, Bw, ldb, w, 1, 64, 1);
    STG1(1, Bw, ldb, w4, 0, 64, 1); STG1(1, Bw, ldb, w4, 1, 64, 1);
    asm volatile("s_waitcnt vmcnt(4)" ::: "memory");
  } else {
    asm volatile("s_waitcnt vmcnt(0)" ::: "memory");
  }
  BARX();

  for (int tt = 0; tt < NT; ++tt) {
    const int p = tt & 1;
    const u16* Abuf = &L[p][0][0];
    const u16* Bbuf = &L[p][1][0];
    bf16x8 aR[4][2], bR[4][2];

    // ph1: ds all aR (8) + bR[0] (2); stage A(t+1) rb=w -> buf p^1
#pragma unroll
    for (int i = 0; i < 4; ++i) {
      aR[i][0] = *(const bf16x8*)(Abuf + ((wr * 4 + i) * 2 + 0) * 512 + rbase);
      aR[i][1] = *(const bf16x8*)(Abuf + ((wr * 4 + i) * 2 + 1) * 512 + rbase);
    }
    bR[0][0] = *(const bf16x8*)(Bbuf + ((wc * 4 + 0) * 2 + 0) * 512 + rbase);
    bR[0][1] = *(const bf16x8*)(Bbuf + ((wc * 4 + 0) * 2 + 1) * 512 + rbase);
    if (tt + 1 < NT) {
      STG1(0, Aw, lda, w, 0, (tt + 1) * 64, p ^ 1);
      STG1(0, Aw, lda, w, 1, (tt + 1) * 64, p ^ 1);
    }
    BARX();
    LGKM0();
    __builtin_amdgcn_s_setprio(1);
    MM1(0, 0); MM1(1, 0); MM1(2, 0); MM1(3, 0);
    __builtin_amdgcn_s_setprio(0);
    BARX();

    // ph2: ds bR[1..3] (6); stage A(t+1) rb=w+4
#pragma unroll
    for (int j = 1; j < 4; ++j) {
      bR[j][0] = *(const bf16x8*)(Bbuf + ((wc * 4 + j) * 2 + 0) * 512 + rbase);
      bR[j][1] = *(const bf16x8*)(Bbuf + ((wc * 4 + j) * 2 + 1) * 512 + rbase);
    }
    if (tt + 1 < NT) {
      STG1(0, Aw, lda, w4, 0, (tt + 1) * 64, p ^ 1);
      STG1(0, Aw, lda, w4, 1, (tt + 1) * 64, p ^ 1);
    }
    BARX();
    LGKM0();
    __builtin_amdgcn_s_setprio(1);
    MM1(0, 1); MM1(1, 1); MM1(2, 1); MM1(3, 1);
    __builtin_amdgcn_s_setprio(0);
    BARX();

    // ph3: stage B(t+2) rb=w into buf p (B(t) reads done at ph2-end barrier)
    if (tt + 2 < NT) {
      STG1(1, Bw, ldb, w, 0, (tt + 2) * 64, p);
      STG1(1, Bw, ldb, w, 1, (tt + 2) * 64, p);
    }
    BARX();
    __builtin_amdgcn_s_setprio(1);
    MM1(0, 2); MM1(1, 2); MM1(2, 2); MM1(3, 2);
    __builtin_amdgcn_s_setprio(0);
    BARX();

    // ph4: stage B(t+2) rb=w+4; tile-end counted wait
    if (tt + 2 < NT) {
      STG1(1, Bw, ldb, w4, 0, (tt + 2) * 64, p);
      STG1(1, Bw, ldb, w4, 1, (tt + 2) * 64, p);
    }
    BARX();
    __builtin_amdgcn_s_setprio(1);
    MM1(0, 3); MM1(1, 3); MM1(2, 3); MM1(3, 3);
    __builtin_amdgcn_s_setprio(0);
    if (tt + 1 < NT) {
      if (tt + 2 < NT) asm volatile("s_waitcnt vmcnt(4)" ::: "memory");
      else             asm volatile("s_waitcnt vmcnt(0)" ::: "memory");
    }
    BARX();
  }

#pragma unroll
  for (int fr = 0; fr < 4; fr++) {
#pragma unroll
    for (int r = 0; r < 4; r++) {
      int row = m0 + wr * 64 + fr * 16 + q * 4 + r;
      if (EPI == 0) {
        u16* Cp = (u16*)Cv + (long long)sp * pstride + (long long)row * ldc;
#pragma unroll
        for (int fc = 0; fc < 4; fc++)
          Cp[n0 + wc * 64 + fc * 16 + m16] = f2bf(acc[fr][fc][r]);
      } else if (EPI == 1) {
        u16* Cb = (u16*)Cv + (long long)row * ldc;
#pragma unroll
        for (int fc = 0; fc < 4; fc++) {
          int col = n0 + wc * 64 + fc * 16 + m16;
          Cb[col] = f2bf(acc[fr][fc][r] + bias[col]);
        }
      } else {  // EPI == 3
        u16* Cb = (u16*)Cv + (long long)row * ldc;
#pragma unroll
        for (int fc = 0; fc < 4; fc++) {
          int col = n0 + wc * 64 + fc * 16 + m16;
          Cb[col] = f2bf(gelu_tanh(acc[fr][fc][r] + bias[col]));
        }
      }
    }
  }
}

// ---------------------------------------------------------------------------
// Fused flash attention (R6-verified form, T1-chunked).
// Grid: (SEG/128, NHEADS*nseg).
// ---------------------------------------------------------------------------
__global__ __launch_bounds__(256) void fattn_k(
    const u16* __restrict__ qr, const u16* __restrict__ kr,
    const u16* __restrict__ vpT, u16* __restrict__ o, int N, float iscale) {
  __shared__ __align__(16) u16 Ks[2][24][512];   // [buf][f*3+kg][16kv x 32hd]
  __shared__ __align__(16) u16 Vs[2][20][512];   // [buf][df*4+kvg][16d x 32kv]
  __shared__ __align__(16) u16 Ps[4][32 * 128];  // per-wave P panel
  const int nseg = N >> 9;
  const int gx = gridDim.x;
  const int lg = xcd_remap(blockIdx.x + gx * blockIdx.y, gx * gridDim.y);
  const int strip = lg % gx, hb = lg / gx;
  const int h = hb / nseg, seg = hb - h * nseg;
  const int t = threadIdx.x, ln = t & 63, w = t >> 6;
  const int m16 = ln & 15, qh = ln >> 4;
  const int r4 = ln >> 2, gsw = (ln & 3) ^ ((ln >> 5) << 1);
  const int rbase = m16 * 32 + ((qh ^ ((m16 >> 3) << 1)) << 3);
  const long long hN = (long long)h * N;
  const int segbase = seg * SEG;
  const int q0 = segbase + strip * 128 + w * 32;

  bf16x8 qf[2][3];
#pragma unroll
  for (int mi = 0; mi < 2; mi++)
#pragma unroll
    for (int ks = 0; ks < 3; ks++)
      qf[mi][ks] = *(const bf16x8*)&qr[(hN + q0 + mi * 16 + m16) * 96 + ks * 32 + qh * 8];

  f32x4 ao[2][5];
#pragma unroll
  for (int mi = 0; mi < 2; mi++)
#pragma unroll
    for (int df = 0; df < 5; df++)
#pragma unroll
      for (int r = 0; r < 4; r++) ao[mi][df][r] = 0.f;
  float m_[2][4], l_[2][4];
#pragma unroll
  for (int mi = 0; mi < 2; mi++)
#pragma unroll
    for (int r = 0; r < 4; r++) { m_[mi][r] = -1e30f; l_[mi][r] = 0.f; }

  auto stage = [&](int c, int pb) {
#pragma unroll
    for (int i = 0; i < 6; i++) {
      int sK = w * 6 + i, f = sK / 3, kg = sK - f * 3;
      async16(&kr[(hN + segbase + c * 128 + f * 16 + r4) * 96 + kg * 32 + gsw * 8],
              &Ks[pb][sK][0]);
    }
#pragma unroll
    for (int i = 0; i < 5; i++) {
      int sV = w * 5 + i, df = sV >> 2, kvg = sV & 3;
      async16(&vpT[((long long)hb * 128 + df * 16 + r4) * SEG + c * 128 + kvg * 32 + gsw * 8],
              &Vs[pb][sV][0]);
    }
  };

  stage(0, 0);
  u16* Pmy = &Ps[w][0];
  for (int c = 0; c < 4; c++) {
    const int pb = c & 1;
    __syncthreads();  // implicit vmcnt(0)+lgkmcnt(0): buf[pb] staged by all waves
    if (c < 3) stage(c + 1, pb ^ 1);

    f32x4 s[2][8];
#pragma unroll
    for (int mi = 0; mi < 2; mi++)
#pragma unroll
      for (int f = 0; f < 8; f++)
#pragma unroll
        for (int r = 0; r < 4; r++) s[mi][f][r] = 0.f;
#pragma unroll
    for (int ks = 0; ks < 3; ks++) {
#pragma unroll
      for (int f = 0; f < 8; f++) {
        bf16x8 kf = *(const bf16x8*)&Ks[pb][f * 3 + ks][rbase];
#pragma unroll
        for (int mi = 0; mi < 2; mi++)
          s[mi][f] = __builtin_amdgcn_mfma_f32_16x16x32_bf16(qf[mi][ks], kf, s[mi][f], 0, 0, 0);
      }
    }

#pragma unroll
    for (int mi = 0; mi < 2; mi++) {
#pragma unroll
      for (int r = 0; r < 4; r++) {
        float mx = s[mi][0][r];
#pragma unroll
        for (int f = 1; f < 8; f++) mx = fmaxf(mx, s[mi][f][r]);
        mx *= iscale;
#pragma unroll
        for (int o2 = 1; o2 <= 8; o2 <<= 1) mx = fmaxf(mx, __shfl_xor(mx, o2));
        float mn = fmaxf(m_[mi][r], mx);
        float corr = __expf(m_[mi][r] - mn);
        m_[mi][r] = mn;
        float rs = 0.f;
#pragma unroll
        for (int f = 0; f < 8; f++) {
          float p = __expf(s[mi][f][r] * iscale - mn);
          s[mi][f][r] = p;
          rs += p;
        }
#pragma unroll
        for (int o2 = 1; o2 <= 8; o2 <<= 1) rs += __shfl_xor(rs, o2);
        l_[mi][r] = l_[mi][r] * corr + rs;
#pragma unroll
        for (int df = 0; df < 5; df++) ao[mi][df][r] *= corr;
      }
    }

#pragma unroll
    for (int mi = 0; mi < 2; mi++) {
#pragma unroll
      for (int r = 0; r < 4; r++) {
        int qq = mi * 16 + qh * 4 + r;
        int base = qq * 128 + (m16 & 7);
        int ql = qq & 7;
#pragma unroll
        for (int f = 0; f < 8; f++) {
          int gr = (f * 2 + (m16 >> 3)) ^ ql;
          Pmy[base + gr * 8] = f2bf(s[mi][f][r]);
        }
      }
    }

#pragma unroll
    for (int ks = 0; ks < 4; ks++) {
      bf16x8 pf[2];
#pragma unroll
      for (int mi = 0; mi < 2; mi++)
        pf[mi] = *(const bf16x8*)&Pmy[(mi * 16 + m16) * 128 +
                                      (((ks * 4 + qh) ^ (m16 & 7)) << 3)];
#pragma unroll
      for (int df = 0; df < 5; df++) {
        bf16x8 vf = *(const bf16x8*)&Vs[pb][df * 4 + ks][rbase];
#pragma unroll
        for (int mi = 0; mi < 2; mi++)
          ao[mi][df] = __builtin_amdgcn_mfma_f32_16x16x32_bf16(pf[mi], vf, ao[mi][df], 0, 0, 0);
      }
    }
  }

#pragma unroll
  for (int mi = 0; mi < 2; mi++) {
#pragma unroll
    for (int r = 0; r < 4; r++) {
      float rl = 1.f / l_[mi][r];
      long long rowb = (long long)(q0 + mi * 16 + qh * 4 + r) * DMODEL + h * 80;
#pragma unroll
      for (int df = 0; df < 5; df++)
        o[rowb + df * 16 + m16] = f2bf(ao[mi][df][r] * rl);
    }
  }
}

// ---------------------------------------------------------------------------
// Split-K reduce + epilogue (bf16 partials): out = [gelu](sum + bias) [+ res]
// ---------------------------------------------------------------------------
template <int S, int RES, int GELU, int OUTBF>
__global__ void reduce_k(const u16* __restrict__ Pp, long long mn, int Nn,
                         const float* __restrict__ bias,
                         const float* __restrict__ res, void* __restrict__ out) {
  long long i = ((long long)blockIdx.x * 256 + threadIdx.x) * 4;
  if (i >= mn) return;
  float vx = 0.f, vy = 0.f, vz = 0.f, vw = 0.f;
#pragma unroll
  for (int s = 0; s < S; s++) {
    ushort4 u4 = *(const ushort4*)(Pp + (long long)s * mn + i);
    vx += bf2f(u4.x); vy += bf2f(u4.y); vz += bf2f(u4.z); vw += bf2f(u4.w);
  }
  int col = (int)(i % Nn);
  vx += bias[col]; vy += bias[col + 1]; vz += bias[col + 2]; vw += bias[col + 3];
  if (GELU) {
    vx = gelu_tanh(vx); vy = gelu_tanh(vy);
    vz = gelu_tanh(vz); vw = gelu_tanh(vw);
  }
  if (RES) {
    float4 r4 = *(const float4*)(res + i);
    vx += r4.x; vy += r4.y; vz += r4.z; vw += r4.w;
  }
  if (OUTBF) {
    ushort4 o; o.x = f2bf(vx); o.y = f2bf(vy); o.z = f2bf(vz); o.w = f2bf(vw);
    *(ushort4*)((u16*)out + i) = o;
  } else {
    float4 o; o.x = vx; o.y = vy; o.z = vz; o.w = vw;
    *(float4*)((float*)out + i) = o;
  }
}

// ---------------------------------------------------------------------------
// Fused split-K reduce + residual + LayerNorm: one 320-thread block per row.
// ---------------------------------------------------------------------------
template <int S>
__global__ void redln_k(const u16* __restrict__ Pp, long long mn,
                        const float* __restrict__ bias,
                        float* __restrict__ x,
                        const float* __restrict__ s, const float* __restrict__ b,
                        u16* __restrict__ h) {
  int row = blockIdx.x;
  int d = threadIdx.x * 4;
  long long base = (long long)row * DMODEL + d;
  float vx = 0.f, vy = 0.f, vz = 0.f, vw = 0.f;
#pragma unroll
  for (int si = 0; si < S; si++) {
    ushort4 u4 = *(const ushort4*)(Pp + (long long)si * mn + base);
    vx += bf2f(u4.x); vy += bf2f(u4.y); vz += bf2f(u4.z); vw += bf2f(u4.w);
  }
  vx += bias[d]; vy += bias[d + 1]; vz += bias[d + 2]; vw += bias[d + 3];
  float4 r4 = *(const float4*)(x + base);
  vx += r4.x; vy += r4.y; vz += r4.z; vw += r4.w;
  float4 xv; xv.x = vx; xv.y = vy; xv.z = vz; xv.w = vw;
  *(float4*)(x + base) = xv;
  float sum = vx + vy + vz + vw;
#pragma unroll
  for (int o = 32; o; o >>= 1) sum += __shfl_xor(sum, o);
  __shared__ float red[8];
  int wv = threadIdx.x >> 6, lnn = threadIdx.x & 63;
  if (lnn == 0) red[wv] = sum;
  __syncthreads();
  float mu = 0.f;
  for (int i = 0; i < 5; i++) mu += red[i];
  mu *= (1.f / DMODEL);
  float dx = vx - mu, dy = vy - mu, dz = vz - mu, dw = vw - mu;
  float s2 = dx * dx + dy * dy + dz * dz + dw * dw;
#pragma unroll
  for (int o = 32; o; o >>= 1) s2 += __shfl_xor(s2, o);
  __syncthreads();
  if (lnn == 0) red[wv] = s2;
  __syncthreads();
  float var = 0.f;
  for (int i = 0; i < 5; i++) var += red[i];
  var *= (1.f / DMODEL);
  float rs = rsqrtf(var + 1e-6f);
  ushort4 o4;
  o4.x = f2bf(dx * rs * s[d] + b[d]);
  o4.y = f2bf(dy * rs * s[d + 1] + b[d + 1]);
  o4.z = f2bf(dz * rs * s[d + 2] + b[d + 2]);
  o4.w = f2bf(dw * rs * s[d + 3] + b[d + 3]);
  *(ushort4*)(h + base) = o4;
}

// ---------------------------------------------------------------------------
// Weight convert+transpose: in fp32 [K][N] -> out bf16 [N][K]. 32x32 tiles.
// ---------------------------------------------------------------------------
__global__ void wconv_k(const float* __restrict__ in, u16* __restrict__ out,
                        int K, int N) {
  __shared__ float tl[32][33];
  int n0 = blockIdx.x * 32, k0 = blockIdx.y * 32;
  int t = threadIdx.x;
  int r = t >> 5, c = t & 31;
#pragma unroll
  for (int i = 0; i < 4; i++)
    tl[r + 8 * i][c] = in[(long long)(k0 + r + 8 * i) * N + n0 + c];
  __syncthreads();
  int n = t >> 4, kp = (t & 15) * 2;
#pragma unroll
  for (int i = 0; i < 2; i++) {
    ushort2 o;
    o.x = f2bf(tl[kp][n + 16 * i]);
    o.y = f2bf(tl[kp + 1][n + 16 * i]);
    *(ushort2*)&out[(long long)(n0 + n + 16 * i) * K + k0 + kp] = o;
  }
}

// fp32 -> bf16 flat copy
__global__ void conv_k(const float* __restrict__ in, u16* __restrict__ out,
                       long long n) {
  long long i = ((long long)blockIdx.x * 256 + threadIdx.x) * 4;
  if (i >= n) return;
  float4 v = *(const float4*)(in + i);
  ushort4 o; o.x = f2bf(v.x); o.y = f2bf(v.y); o.z = f2bf(v.z); o.w = f2bf(v.w);
  *(ushort4*)&out[i] = o;
}

// V transpose per batch: in bf16 [b][512][128] -> out bf16 [b][128][512]
union U16x8 { uint4 v; u16 s[8]; };
__global__ void vtr_k(const u16* __restrict__ in, u16* __restrict__ out) {
  __shared__ u16 tl[64][65];
  int b = blockIdx.z;
  int m0 = blockIdx.x * 64;
  int d0 = blockIdx.y * 64;
  const u16* ib = in + (long long)b * SEG * 128;
  u16* ob = out + (long long)b * 128 * SEG;
  int t = threadIdx.x;
  int r = t >> 3, c8 = (t & 7) * 8;
#pragma unroll
  for (int i = 0; i < 2; i++) {
    U16x8 ld;
    ld.v = *(const uint4*)&ib[(long long)(m0 + r + 32 * i) * 128 + d0 + c8];
#pragma unroll
    for (int j = 0; j < 8; j++) tl[r + 32 * i][c8 + j] = ld.s[j];
  }
  __syncthreads();
  int d = t >> 3, m8 = (t & 7) * 8;
#pragma unroll
  for (int i = 0; i < 2; i++) {
    int dd = d + 32 * i;
    U16x8 st;
#pragma unroll
    for (int j = 0; j < 8; j++) st.s[j] = tl[m8 + j][dd];
    *(uint4*)&ob[(long long)(d0 + dd) * SEG + m0 + m8] = st.v;
  }
}

// ---------------------------------------------------------------------------
__global__ void coords_k(const int* __restrict__ g, int nimg,
                         int* __restrict__ rw, int* __restrict__ cl,
                         int* __restrict__ hh, int* __restrict__ ww, int N) {
  int t = blockIdx.x * 256 + threadIdx.x;
  if (t >= N) return;
  int c = 0, local = 0, H = 1, W = 1;
  for (int i = 0; i < nimg; i++) {
    int tpi = g[i * 3] * g[i * 3 + 1] * g[i * 3 + 2];
    if (t >= c && t < c + tpi) { local = t - c; H = g[i * 3 + 1]; W = g[i * 3 + 2]; }
    c += tpi;
  }
  int hw = H * W;
  int sp = local % hw;
  int mw = W >> 1;
  int gr = sp >> 2, intra = sp & 3;
  rw[t] = (gr / mw) * 2 + (intra >> 1);
  cl[t] = (gr % mw) * 2 + (intra & 1);
  hh[t] = H; ww[t] = W;
}

__global__ void peadd_k(float* __restrict__ x, const float* __restrict__ pe,
                        const int* __restrict__ rw, const int* __restrict__ cl,
                        const int* __restrict__ hh, const int* __restrict__ ww) {
  int n = blockIdx.x;
  int d = threadIdx.x * 4;
  int H = hh[n], W = ww[n];
  float rf = (H > 1) ? (float)rw[n] * (float)(GPOS - 1) / (float)(H - 1) : 0.f;
  float cf = (W > 1) ? (float)cl[n] * (float)(GPOS - 1) / (float)(W - 1) : 0.f;
  int r0 = (int)floorf(rf), c0 = (int)floorf(cf);
  int r1 = min(r0 + 1, GPOS - 1), c1 = min(c0 + 1, GPOS - 1);
  float wr = rf - (float)r0, wc = cf - (float)c0;
  float w00 = (1.f - wr) * (1.f - wc), w01 = (1.f - wr) * wc;
  float w10 = wr * (1.f - wc), w11 = wr * wc;
  float4 v00 = *(const float4*)(pe + (long long)(r0 * GPOS + c0) * DMODEL + d);
  float4 v01 = *(const float4*)(pe + (long long)(r0 * GPOS + c1) * DMODEL + d);
  float4 v10 = *(const float4*)(pe + (long long)(r1 * GPOS + c0) * DMODEL + d);
  float4 v11 = *(const float4*)(pe + (long long)(r1 * GPOS + c1) * DMODEL + d);
  float4 xv = *(float4*)(x + (long long)n * DMODEL + d);
  xv.x += w00 * v00.x + w01 * v01.x + w10 * v10.x + w11 * v11.x;
  xv.y += w00 * v00.y + w01 * v01.y + w10 * v10.y + w11 * v11.y;
  xv.z += w00 * v00.z + w01 * v01.z + w10 * v10.z + w11 * v11.z;
  xv.w += w00 * v00.w + w01 * v01.w + w10 * v10.w + w11 * v11.w;
  *(float4*)(x + (long long)n * DMODEL + d) = xv;
}

// LayerNorm fp32 in -> bf16 out (one 320-thread block per row of 1280)
__global__ void ln_k(const float* __restrict__ X, u16* __restrict__ Y,
                     const float* __restrict__ s, const float* __restrict__ b) {
  int row = blockIdx.x;
  int d = threadIdx.x * 4;
  const float* x = X + (long long)row * DMODEL;
  float4 v = *(const float4*)(x + d);
  float sum = v.x + v.y + v.z + v.w;
#pragma unroll
  for (int o = 32; o; o >>= 1) sum += __shfl_xor(sum, o);
  __shared__ float red[8];
  int wv = threadIdx.x >> 6, lnn = threadIdx.x & 63;
  if (lnn == 0) red[wv] = sum;
  __syncthreads();
  float mu = 0.f;
  for (int i = 0; i < 5; i++) mu += red[i];
  mu *= (1.f / DMODEL);
  float dx = v.x - mu, dy = v.y - mu, dz = v.z - mu, dw = v.w - mu;
  float s2 = dx * dx + dy * dy + dz * dz + dw * dw;
#pragma unroll
  for (int o = 32; o; o >>= 1) s2 += __shfl_xor(s2, o);
  __syncthreads();
  if (lnn == 0) red[wv] = s2;
  __syncthreads();
  float var = 0.f;
  for (int i = 0; i < 5; i++) var += red[i];
  var *= (1.f / DMODEL);
  float rs = rsqrtf(var + 1e-6f);
  ushort4 o4;
  o4.x = f2bf(dx * rs * s[d] + b[d]);
  o4.y = f2bf(dy * rs * s[d + 1] + b[d + 1]);
  o4.z = f2bf(dz * rs * s[d + 2] + b[d + 2]);
  o4.w = f2bf(dw * rs * s[d + 3] + b[d + 3]);
  *(ushort4*)(Y + (long long)row * DMODEL + d) = o4;
}

// RoPE from bf16 qkv -> qr/kr bf16 [h][N][96] (zero pad), v -> vp [h][N][128]
__global__ void rope_k(const u16* __restrict__ qkv, const int* __restrict__ rw,
                       const int* __restrict__ cl, u16* __restrict__ qr,
                       u16* __restrict__ kr, u16* __restrict__ vp, int N) {
  int n = blockIdx.x, h = blockIdx.y, t = threadIdx.x;
  const u16* src = qkv + (long long)n * (3 * DMODEL) + h * 80;
  long long ob96 = ((long long)h * N + n) * 96;
  long long ob128 = ((long long)h * N + n) * 128;
  if (t < 40) {
    float pos = (t < 20) ? (float)rw[n] : (float)cl[n];
    float infr = exp2f(-13.287712379549449f * (float)(t % 20) * 0.05f);
    float f = pos * infr;
    float cs = cosf(f), sn = sinf(f);
    float q0 = bf2f(src[t]), q1 = bf2f(src[t + 40]);
    qr[ob96 + t] = f2bf(q0 * cs - q1 * sn);
    qr[ob96 + t + 40] = f2bf(q1 * cs + q0 * sn);
    float k0 = bf2f(src[DMODEL + t]), k1 = bf2f(src[DMODEL + t + 40]);
    kr[ob96 + t] = f2bf(k0 * cs - k1 * sn);
    kr[ob96 + t + 40] = f2bf(k1 * cs + k0 * sn);
    vp[ob128 + t] = src[2 * DMODEL + t];
    vp[ob128 + t + 40] = src[2 * DMODEL + t + 40];
  } else {
    int u = t - 40;
    if (u < 16) { qr[ob96 + 80 + u] = 0; kr[ob96 + 80 + u] = 0; }
    vp[ob128 + 80 + u] = 0;
    vp[ob128 + 104 + u] = 0;
  }
}

// ---------------------------------------------------------------------------
// 128x128-tile path: M%128==0, Nn%128==0, (Kd/nsplit)%64==0.
static void gemm_big(hipStream_t st, int epi, const u16* A, const u16* B,
                     const float* bias, void* C, int M, int Nn, int Kd,
                     int lda, int ldb, int ldc, int nsplit) {
  dim3 g(M / 128, Nn / 128, nsplit), blk(256);
  long long ps = (long long)M * Nn;
  switch (epi) {
    case 0: gemm128<0><<<g, blk, 0, st>>>(A, B, bias, C, Kd, lda, ldb, ldc, nsplit, ps); break;
    case 1: gemm128<1><<<g, blk, 0, st>>>(A, B, bias, C, Kd, lda, ldb, ldc, nsplit, ps); break;
    default: gemm128<3><<<g, blk, 0, st>>>(A, B, bias, C, Kd, lda, ldb, ldc, nsplit, ps); break;
  }
}

extern "C" void kernel_launch(void* const* d_in, const int* in_sizes, int n_in,
                              void* d_out, int out_size, void* d_ws, size_t ws_size,
                              hipStream_t stream) {
  const float* pixels = (const float*)d_in[0];
  const int* grid_thw = (const int*)d_in[1];
  const float* pos_embed = (const float*)d_in[2];
  const float* patch_w = (const float*)d_in[3];
  const float* patch_b = (const float*)d_in[4];
  const float* ln1_s = (const float*)d_in[5];
  const float* ln1_b = (const float*)d_in[6];
  const float* qkv_w = (const float*)d_in[7];
  const float* qkv_b = (const float*)d_in[8];
  const float* proj_w = (const float*)d_in[9];
  const float* proj_b = (const float*)d_in[10];
  const float* ln2_s = (const float*)d_in[11];
  const float* ln2_b = (const float*)d_in[12];
  const float* fc1_w = (const float*)d_in[13];
  const float* fc1_b = (const float*)d_in[14];
  const float* fc2_w = (const float*)d_in[15];
  const float* fc2_b = (const float*)d_in[16];
  const float* mns = (const float*)d_in[17];
  const float* mnb = (const float*)d_in[18];
  const float* mf1w = (const float*)d_in[19];
  const float* mf1b = (const float*)d_in[20];
  const float* mf2w = (const float*)d_in[21];
  const float* mf2b = (const float*)d_in[22];
  float* out = (float*)d_out;

  const int N = in_sizes[0] / 1536;  // 2048
  const int nimg = in_sizes[1] / 3;  // 4
  const int nseg = N / SEG;          // 4
  const int nb = NHEADS * nseg;      // 64

  char* w = (char*)d_ws;
  size_t off = 0;
  auto alloc = [&](size_t bytes) -> void* {
    void* p = w + off;
    off += (bytes + 255) & ~(size_t)255;
    return p;
  };
  int* rw = (int*)alloc((size_t)N * 4);
  int* cl = (int*)alloc((size_t)N * 4);
  int* hh = (int*)alloc((size_t)N * 4);
  int* ww = (int*)alloc((size_t)N * 4);
  float* x = (float*)alloc((size_t)N * DMODEL * 4);
  u16* h = (u16*)alloc((size_t)N * DMODEL * 2);
  u16* pixbf = (u16*)alloc((size_t)N * 1536 * 2);      // mfc2T overlay base
  u16* patchT = (u16*)alloc((size_t)DMODEL * 1536 * 2);
  u16* qkvT = (u16*)alloc((size_t)3 * DMODEL * DMODEL * 2);
  u16* projT = (u16*)alloc((size_t)DMODEL * DMODEL * 2);
  u16* fc1T = (u16*)alloc((size_t)FDIM * DMODEL * 2);
  u16* fc2T = (u16*)alloc((size_t)DMODEL * FDIM * 2);
  u16* qkvb = (u16*)alloc((size_t)N * 3 * DMODEL * 2);  // mfc1T overlay base
  u16* qr = (u16*)alloc((size_t)NHEADS * N * 96 * 2);
  u16* kr = (u16*)alloc((size_t)NHEADS * N * 96 * 2);
  u16* vp = (u16*)alloc((size_t)NHEADS * N * 128 * 2);
  u16* vpT = (u16*)alloc((size_t)NHEADS * N * 128 * 2);
  u16* pad0 = (u16*)alloc((size_t)nb * 2 * SEG * 128 * 2);  // keeps mfc1T overlay in bounds
  u16* o = (u16*)alloc((size_t)N * DMODEL * 2);
  float* bigA = (float*)alloc((size_t)nb * SEG * SEG * 4);  // ffb / mf
  float* bigB = (float*)alloc((size_t)nb * SEG * SEG * 2);  // split-K partials
  (void)ws_size; (void)pad0;
  // overlays (lifetimes disjoint with originals)
  u16* mfc1T = qkvb;         // 52.4 MB over qkvb..pad0 region
  u16* mfc2T = pixbf;        // 21.0 MB over pixbf..projT
  u16* ffb = (u16*)bigA;     // fc1 out, 21 MB at bigA base
  u16* mf = (u16*)bigA;      // merger hidden 5.2 MB at bigA base
  u16* part = (u16*)bigB;    // split-K bf16 partial planes (<= 33.5 MB)

  const float iscale = 0.11180339887498949f;  // 80^-0.5
  const long long mnD = (long long)N * DMODEL;

  coords_k<<<dim3((N + 255) / 256), 256, 0, stream>>>(grid_thw, nimg, rw, cl, hh, ww, N);
  conv_k<<<dim3((int)(((long long)N * 1536 / 4 + 255) / 256)), 256, 0, stream>>>(
      pixels, pixbf, (long long)N * 1536);
  wconv_k<<<dim3(DMODEL / 32, 1536 / 32), 256, 0, stream>>>(patch_w, patchT, 1536, DMODEL);
  // patch embed, split-K=4 (640 blocks)
  gemm_big(stream, 0, pixbf, patchT, nullptr, part, N, DMODEL, 1536, 1536, 1536,
           DMODEL, 4);
  reduce_k<4, 0, 0, 0><<<dim3((int)((mnD / 4 + 255) / 256)), 256, 0, stream>>>(
      part, mnD, DMODEL, patch_b, nullptr, x);
  peadd_k<<<dim3(N), 320, 0, stream>>>(x, pos_embed, rw, cl, hh, ww);
  // ln1 of layer 0 (subsequent LNs fused into split-K reduces)
  ln_k<<<dim3(N), 320, 0, stream>>>(x, h, ln1_s, ln1_b);

  for (int l = 0; l < 4; l++) {
    wconv_k<<<dim3(3 * DMODEL / 32, DMODEL / 32), 256, 0, stream>>>(
        qkv_w + (size_t)l * DMODEL * 3 * DMODEL, qkvT, DMODEL, 3 * DMODEL);
    wconv_k<<<dim3(DMODEL / 32, DMODEL / 32), 256, 0, stream>>>(
        proj_w + (size_t)l * DMODEL * DMODEL, projT, DMODEL, DMODEL);
    wconv_k<<<dim3(FDIM / 32, DMODEL / 32), 256, 0, stream>>>(
        fc1_w + (size_t)l * DMODEL * FDIM, fc1T, DMODEL, FDIM);
    wconv_k<<<dim3(DMODEL / 32, FDIM / 32), 256, 0, stream>>>(
        fc2_w + (size_t)l * FDIM * DMODEL, fc2T, FDIM, DMODEL);

    // qkv direct +bias (480 blocks, NT=20)
    gemm_big(stream, 1, h, qkvT, qkv_b + (size_t)l * 3 * DMODEL, qkvb, N,
             3 * DMODEL, DMODEL, DMODEL, DMODEL, 3 * DMODEL, 1);
    rope_k<<<dim3(N, NHEADS), 64, 0, stream>>>(qkvb, rw, cl, qr, kr, vp, N);
    vtr_k<<<dim3(8, 2, nb), 256, 0, stream>>>(vp, vpT);
    // fused flash attention -> o (256 blocks, 1/CU, XCD-chunked)
    fattn_k<<<dim3(SEG / 128, nb), 256, 0, stream>>>(qr, kr, vpT, o, N, iscale);
    // proj split-K=4 (640 blocks); fused reduce + bias + residual + ln2 -> h
    gemm_big(stream, 0, o, projT, nullptr, part, N, DMODEL, DMODEL, DMODEL,
             DMODEL, DMODEL, 4);
    redln_k<4><<<dim3(N), 320, 0, stream>>>(part, mnD, proj_b + (size_t)l * DMODEL,
                                            x, ln2_s + (size_t)l * DMODEL,
                                            ln2_b + (size_t)l * DMODEL, h);
    // fc1 fused bias+gelu -> bf16 (640 blocks, NT=20, direct)
    gemm_big(stream, 3, h, fc1T, fc1_b + (size_t)l * FDIM, ffb, N, FDIM, DMODEL,
             DMODEL, DMODEL, FDIM, 1);
    // fc2 split-K=4 (640 blocks); fused reduce + bias + residual + next LN -> h
    gemm_big(stream, 0, ffb, fc2T, nullptr, part, N, DMODEL, FDIM, FDIM, FDIM,
             DMODEL, 4);
    const float* nsl = (l < 3) ? ln1_s + (size_t)(l + 1) * DMODEL : mns;
    const float* nbl = (l < 3) ? ln1_b + (size_t)(l + 1) * DMODEL : mnb;
    redln_k<4><<<dim3(N), 320, 0, stream>>>(part, mnD, fc2_b + (size_t)l * DMODEL,
                                            x, nsl, nbl, h);
  }

  // merger (h already = LN(x; mns,mnb), viewed as [512][5120])
  const int Mm = N / 4;  // 512
  wconv_k<<<dim3(FDIM / 32, FDIM / 32), 256, 0, stream>>>(mf1w, mfc1T, FDIM, FDIM);
  // mfc1 split-K=4 (640 blocks); reduce + bias + gelu -> mf
  gemm_big(stream, 0, h, mfc1T, nullptr, part, Mm, FDIM, FDIM, FDIM, FDIM, FDIM, 4);
  reduce_k<4, 0, 1, 1><<<dim3((int)(((long long)Mm * FDIM / 4 + 255) / 256)), 256, 0, stream>>>(
      part, (long long)Mm * FDIM, FDIM, mf1b, nullptr, mf);
  wconv_k<<<dim3(2048 / 32, FDIM / 32), 256, 0, stream>>>(mf2w, mfc2T, FDIM, 2048);
  // mfc2 split-K=16 (1024 blocks)
  gemm_big(stream, 0, mf, mfc2T, nullptr, part, Mm, 2048, FDIM, FDIM, FDIM, 2048, 16);
  reduce_k<16, 0, 0, 0><<<dim3((int)(((long long)Mm * 2048 / 4 + 255) / 256)), 256, 0, stream>>>(
      part, (long long)Mm * 2048, 2048, mf2b, nullptr, out);
}

// Round 8
// 1362.494 us; speedup vs baseline: 1.1138x; 1.0023x over previous
//
#include <hip/hip_runtime.h>
#include <math.h>

#define DMODEL 1280
#define NHEADS 16
#define FDIM   5120
#define GPOS   48
#define SEG    512

typedef __attribute__((ext_vector_type(8))) short bf16x8;
typedef __attribute__((ext_vector_type(4))) float f32x4;
typedef unsigned short u16;

__device__ __forceinline__ u16 f2bf(float f) {
  unsigned int u = __float_as_uint(f);
  u = (u + 0x7FFFu + ((u >> 16) & 1u)) >> 16;  // RNE
  return (u16)u;
}
__device__ __forceinline__ float bf2f(u16 u) {
  return __uint_as_float((unsigned int)u << 16);
}
__device__ __forceinline__ float gelu_tanh(float x) {
  float u = 0.7978845608028654f * (x + 0.044715f * x * x * x);
  float t = __expf(2.f * u);
  float th = 1.f - 2.f / (t + 1.f);
  return 0.5f * x * (1.f + th);
}

typedef const __attribute__((address_space(1))) unsigned int* gas_t;
typedef __attribute__((address_space(3))) unsigned int* las_t;
__device__ __forceinline__ void async16(const void* g, void* l) {
  __builtin_amdgcn_global_load_lds((gas_t)g, (las_t)l, 16, 0, 0);
}

// Bijective XCD chunk remap (T1, m204 form).
__device__ __forceinline__ int xcd_remap(int b, int nwg) {
  int q = nwg >> 3, r = nwg & 7, x = b & 7, d = b >> 3;
  return (x < r ? x * (q + 1) : r * (q + 1) + (x - r) * q) + d;
}

// ---------------------------------------------------------------------------
// gemm128: 128x128 tile, BK=32, 4 waves (2Mx2N), 32 KiB dbuf LDS,
// __launch_bounds__(256,3) -> **3 blocks/CU co-resident** (R7 proved the
// co-residency lever: 1->2 blocks/CU was the only GEMM win since R1; this
// pushes 2->3 and lifts grid fill from 1.25 rounds/62% to 83% single-round
// for the 640-block GEMMs). Same verified R2 subtile swizzle ([16][32]
// subtiles, csw/rbase) and T1 remap. 2 phases/tile, depth-1 prefetch into
// the other buffer (A(t+1)@ph1, B(t+1)@ph2; race-free: the target buffer's
// reads finished a full tile ago behind two barriers), tile-end vmcnt(0) —
// the drain is hidden by the other resident blocks (m114), which R0's
// conflict-ridden 2-phase kernel could not exploit.
// Per-element k-accumulation order identical to R7 (k0,k32,...) ->
// bit-identical results (absmax invariant must hold).
// A:[M][K] bf16, B:[N][K] bf16, C = A.B^T.
// EPI 0: bf16 partial planes (split-K). EPI 1: +bias bf16. EPI 3: +bias+gelu.
// ---------------------------------------------------------------------------
#define STG1(mat, PW, ldx, rb, kk, pp)                                      \
  async16((PW) + (long long)(rb) * 16 * (ldx) + (kk),                       \
          &L[pp][mat][(rb) * 512])

#define BARX() asm volatile("s_barrier" ::: "memory")
#define LGKM0() asm volatile("s_waitcnt lgkmcnt(0)" ::: "memory")

template <int EPI>
__global__ __launch_bounds__(256, 3) void gemm128(
    const u16* __restrict__ A, const u16* __restrict__ B,
    const float* __restrict__ bias, void* __restrict__ Cv,
    int Kd, int lda, int ldb, int ldc, int nsplit, long long pstride) {
  __shared__ __align__(16) u16 L[2][2][4096];  // [buf][A|B][8rb x 512]
  const int sp = blockIdx.z;
  const int Ks = Kd / nsplit;
  const int NT = Ks >> 5;
  const u16* Ab = A + (long long)sp * Ks;
  const u16* Bb = B + (long long)sp * Ks;
  const int gx = gridDim.x;
  const int lg = xcd_remap(blockIdx.x + gx * blockIdx.y, gx * gridDim.y);
  const int m0 = (lg % gx) * 128, n0 = (lg / gx) * 128;
  const int t = threadIdx.x, ln = t & 63, w = t >> 6;
  const int wr = w >> 1, wc = w & 1;
  const int m16 = ln & 15, q = ln >> 4;
  const int r16 = ln >> 2;
  const int csw = (ln & 3) ^ ((ln >> 5) << 1);               // R2 source swz
  const int rbase = m16 * 32 + (q ^ ((m16 >> 3) << 1)) * 8;  // R2 read swz

  const u16* Aw = Ab + (long long)(m0 + r16) * lda + csw * 8;
  const u16* Bw = Bb + (long long)(n0 + r16) * ldb + csw * 8;
  const int w4 = w + 4;

  f32x4 acc[4][4];
#pragma unroll
  for (int i = 0; i < 4; i++)
#pragma unroll
    for (int j = 0; j < 4; j++)
#pragma unroll
      for (int r = 0; r < 4; r++) acc[i][j][r] = 0.f;

  // prologue: tile0 (4 loads/wave) + tile1 (4); vmcnt(4) -> tile0 landed.
  STG1(0, Aw, lda, w, 0, 0);  STG1(0, Aw, lda, w4, 0, 0);
  STG1(1, Bw, ldb, w, 0, 0);  STG1(1, Bw, ldb, w4, 0, 0);
  if (NT > 1) {
    STG1(0, Aw, lda, w, 32, 1);  STG1(0, Aw, lda, w4, 32, 1);
    STG1(1, Bw, ldb, w, 32, 1);  STG1(1, Bw, ldb, w4, 32, 1);
    asm volatile("s_waitcnt vmcnt(4)" ::: "memory");
  } else {
    asm volatile("s_waitcnt vmcnt(0)" ::: "memory");
  }
  BARX();

  for (int tt = 0; tt < NT; ++tt) {
    const int p = tt & 1;
    const u16* Abuf = &L[p][0][0];
    const u16* Bbuf = &L[p][1][0];
    bf16x8 aR[4], bR[4];

    // ph1: ds all aR (4) + bR[0..1] (2); stage A(t+1) -> buf p^1
#pragma unroll
    for (int i = 0; i < 4; ++i)
      aR[i] = *(const bf16x8*)(Abuf + (wr * 4 + i) * 512 + rbase);
    bR[0] = *(const bf16x8*)(Bbuf + (wc * 4 + 0) * 512 + rbase);
    bR[1] = *(const bf16x8*)(Bbuf + (wc * 4 + 1) * 512 + rbase);
    if (tt + 1 < NT) {
      STG1(0, Aw, lda, w, (tt + 1) * 32, p ^ 1);
      STG1(0, Aw, lda, w4, (tt + 1) * 32, p ^ 1);
    }
    BARX();
    LGKM0();
    __builtin_amdgcn_s_setprio(1);
#pragma unroll
    for (int i = 0; i < 4; ++i) {
      acc[i][0] = __builtin_amdgcn_mfma_f32_16x16x32_bf16(aR[i], bR[0], acc[i][0], 0, 0, 0);
      acc[i][1] = __builtin_amdgcn_mfma_f32_16x16x32_bf16(aR[i], bR[1], acc[i][1], 0, 0, 0);
    }
    __builtin_amdgcn_s_setprio(0);
    BARX();

    // ph2: ds bR[2..3] (2); stage B(t+1) -> buf p^1; tile-end drain
    bR[2] = *(const bf16x8*)(Bbuf + (wc * 4 + 2) * 512 + rbase);
    bR[3] = *(const bf16x8*)(Bbuf + (wc * 4 + 3) * 512 + rbase);
    if (tt + 1 < NT) {
      STG1(1, Bw, ldb, w, (tt + 1) * 32, p ^ 1);
      STG1(1, Bw, ldb, w4, (tt + 1) * 32, p ^ 1);
    }
    BARX();
    LGKM0();
    __builtin_amdgcn_s_setprio(1);
#pragma unroll
    for (int i = 0; i < 4; ++i) {
      acc[i][2] = __builtin_amdgcn_mfma_f32_16x16x32_bf16(aR[i], bR[2], acc[i][2], 0, 0, 0);
      acc[i][3] = __builtin_amdgcn_mfma_f32_16x16x32_bf16(aR[i], bR[3], acc[i][3], 0, 0, 0);
    }
    __builtin_amdgcn_s_setprio(0);
    if (tt + 1 < NT) asm volatile("s_waitcnt vmcnt(0)" ::: "memory");
    BARX();
  }

#pragma unroll
  for (int fr = 0; fr < 4; fr++) {
#pragma unroll
    for (int r = 0; r < 4; r++) {
      int row = m0 + wr * 64 + fr * 16 + q * 4 + r;
      if (EPI == 0) {
        u16* Cp = (u16*)Cv + (long long)sp * pstride + (long long)row * ldc;
#pragma unroll
        for (int fc = 0; fc < 4; fc++)
          Cp[n0 + wc * 64 + fc * 16 + m16] = f2bf(acc[fr][fc][r]);
      } else if (EPI == 1) {
        u16* Cb = (u16*)Cv + (long long)row * ldc;
#pragma unroll
        for (int fc = 0; fc < 4; fc++) {
          int col = n0 + wc * 64 + fc * 16 + m16;
          Cb[col] = f2bf(acc[fr][fc][r] + bias[col]);
        }
      } else {  // EPI == 3
        u16* Cb = (u16*)Cv + (long long)row * ldc;
#pragma unroll
        for (int fc = 0; fc < 4; fc++) {
          int col = n0 + wc * 64 + fc * 16 + m16;
          Cb[col] = f2bf(gelu_tanh(acc[fr][fc][r] + bias[col]));
        }
      }
    }
  }
}

// ---------------------------------------------------------------------------
// Fused flash attention (R6-verified form, T1-chunked).
// Grid: (SEG/128, NHEADS*nseg).
// ---------------------------------------------------------------------------
__global__ __launch_bounds__(256) void fattn_k(
    const u16* __restrict__ qr, const u16* __restrict__ kr,
    const u16* __restrict__ vpT, u16* __restrict__ o, int N, float iscale) {
  __shared__ __align__(16) u16 Ks[2][24][512];   // [buf][f*3+kg][16kv x 32hd]
  __shared__ __align__(16) u16 Vs[2][20][512];   // [buf][df*4+kvg][16d x 32kv]
  __shared__ __align__(16) u16 Ps[4][32 * 128];  // per-wave P panel
  const int nseg = N >> 9;
  const int gx = gridDim.x;
  const int lg = xcd_remap(blockIdx.x + gx * blockIdx.y, gx * gridDim.y);
  const int strip = lg % gx, hb = lg / gx;
  const int h = hb / nseg, seg = hb - h * nseg;
  const int t = threadIdx.x, ln = t & 63, w = t >> 6;
  const int m16 = ln & 15, qh = ln >> 4;
  const int r4 = ln >> 2, gsw = (ln & 3) ^ ((ln >> 5) << 1);
  const int rbase = m16 * 32 + ((qh ^ ((m16 >> 3) << 1)) << 3);
  const long long hN = (long long)h * N;
  const int segbase = seg * SEG;
  const int q0 = segbase + strip * 128 + w * 32;

  bf16x8 qf[2][3];
#pragma unroll
  for (int mi = 0; mi < 2; mi++)
#pragma unroll
    for (int ks = 0; ks < 3; ks++)
      qf[mi][ks] = *(const bf16x8*)&qr[(hN + q0 + mi * 16 + m16) * 96 + ks * 32 + qh * 8];

  f32x4 ao[2][5];
#pragma unroll
  for (int mi = 0; mi < 2; mi++)
#pragma unroll
    for (int df = 0; df < 5; df++)
#pragma unroll
      for (int r = 0; r < 4; r++) ao[mi][df][r] = 0.f;
  float m_[2][4], l_[2][4];
#pragma unroll
  for (int mi = 0; mi < 2; mi++)
#pragma unroll
    for (int r = 0; r < 4; r++) { m_[mi][r] = -1e30f; l_[mi][r] = 0.f; }

  auto stage = [&](int c, int pb) {
#pragma unroll
    for (int i = 0; i < 6; i++) {
      int sK = w * 6 + i, f = sK / 3, kg = sK - f * 3;
      async16(&kr[(hN + segbase + c * 128 + f * 16 + r4) * 96 + kg * 32 + gsw * 8],
              &Ks[pb][sK][0]);
    }
#pragma unroll
    for (int i = 0; i < 5; i++) {
      int sV = w * 5 + i, df = sV >> 2, kvg = sV & 3;
      async16(&vpT[((long long)hb * 128 + df * 16 + r4) * SEG + c * 128 + kvg * 32 + gsw * 8],
              &Vs[pb][sV][0]);
    }
  };

  stage(0, 0);
  u16* Pmy = &Ps[w][0];
  for (int c = 0; c < 4; c++) {
    const int pb = c & 1;
    __syncthreads();  // implicit vmcnt(0)+lgkmcnt(0): buf[pb] staged by all waves
    if (c < 3) stage(c + 1, pb ^ 1);

    f32x4 s[2][8];
#pragma unroll
    for (int mi = 0; mi < 2; mi++)
#pragma unroll
      for (int f = 0; f < 8; f++)
#pragma unroll
        for (int r = 0; r < 4; r++) s[mi][f][r] = 0.f;
#pragma unroll
    for (int ks = 0; ks < 3; ks++) {
#pragma unroll
      for (int f = 0; f < 8; f++) {
        bf16x8 kf = *(const bf16x8*)&Ks[pb][f * 3 + ks][rbase];
#pragma unroll
        for (int mi = 0; mi < 2; mi++)
          s[mi][f] = __builtin_amdgcn_mfma_f32_16x16x32_bf16(qf[mi][ks], kf, s[mi][f], 0, 0, 0);
      }
    }

#pragma unroll
    for (int mi = 0; mi < 2; mi++) {
#pragma unroll
      for (int r = 0; r < 4; r++) {
        float mx = s[mi][0][r];
#pragma unroll
        for (int f = 1; f < 8; f++) mx = fmaxf(mx, s[mi][f][r]);
        mx *= iscale;
#pragma unroll
        for (int o2 = 1; o2 <= 8; o2 <<= 1) mx = fmaxf(mx, __shfl_xor(mx, o2));
        float mn = fmaxf(m_[mi][r], mx);
        float corr = __expf(m_[mi][r] - mn);
        m_[mi][r] = mn;
        float rs = 0.f;
#pragma unroll
        for (int f = 0; f < 8; f++) {
          float p = __expf(s[mi][f][r] * iscale - mn);
          s[mi][f][r] = p;
          rs += p;
        }
#pragma unroll
        for (int o2 = 1; o2 <= 8; o2 <<= 1) rs += __shfl_xor(rs, o2);
        l_[mi][r] = l_[mi][r] * corr + rs;
#pragma unroll
        for (int df = 0; df < 5; df++) ao[mi][df][r] *= corr;
      }
    }

#pragma unroll
    for (int mi = 0; mi < 2; mi++) {
#pragma unroll
      for (int r = 0; r < 4; r++) {
        int qq = mi * 16 + qh * 4 + r;
        int base = qq * 128 + (m16 & 7);
        int ql = qq & 7;
#pragma unroll
        for (int f = 0; f < 8; f++) {
          int gr = (f * 2 + (m16 >> 3)) ^ ql;
          Pmy[base + gr * 8] = f2bf(s[mi][f][r]);
        }
      }
    }

#pragma unroll
    for (int ks = 0; ks < 4; ks++) {
      bf16x8 pf[2];
#pragma unroll
      for (int mi = 0; mi < 2; mi++)
        pf[mi] = *(const bf16x8*)&Pmy[(mi * 16 + m16) * 128 +
                                      (((ks * 4 + qh) ^ (m16 & 7)) << 3)];
#pragma unroll
      for (int df = 0; df < 5; df++) {
        bf16x8 vf = *(const bf16x8*)&Vs[pb][df * 4 + ks][rbase];
#pragma unroll
        for (int mi = 0; mi < 2; mi++)
          ao[mi][df] = __builtin_amdgcn_mfma_f32_16x16x32_bf16(pf[mi], vf, ao[mi][df], 0, 0, 0);
      }
    }
  }

#pragma unroll
  for (int mi = 0; mi < 2; mi++) {
#pragma unroll
    for (int r = 0; r < 4; r++) {
      float rl = 1.f / l_[mi][r];
      long long rowb = (long long)(q0 + mi * 16 + qh * 4 + r) * DMODEL + h * 80;
#pragma unroll
      for (int df = 0; df < 5; df++)
        o[rowb + df * 16 + m16] = f2bf(ao[mi][df][r] * rl);
    }
  }
}

// ---------------------------------------------------------------------------
// Split-K reduce + epilogue (bf16 partials): out = [gelu](sum + bias) [+ res]
// ---------------------------------------------------------------------------
template <int S, int RES, int GELU, int OUTBF>
__global__ void reduce_k(const u16* __restrict__ Pp, long long mn, int Nn,
                         const float* __restrict__ bias,
                         const float* __restrict__ res, void* __restrict__ out) {
  long long i = ((long long)blockIdx.x * 256 + threadIdx.x) * 4;
  if (i >= mn) return;
  float vx = 0.f, vy = 0.f, vz = 0.f, vw = 0.f;
#pragma unroll
  for (int s = 0; s < S; s++) {
    ushort4 u4 = *(const ushort4*)(Pp + (long long)s * mn + i);
    vx += bf2f(u4.x); vy += bf2f(u4.y); vz += bf2f(u4.z); vw += bf2f(u4.w);
  }
  int col = (int)(i % Nn);
  vx += bias[col]; vy += bias[col + 1]; vz += bias[col + 2]; vw += bias[col + 3];
  if (GELU) {
    vx = gelu_tanh(vx); vy = gelu_tanh(vy);
    vz = gelu_tanh(vz); vw = gelu_tanh(vw);
  }
  if (RES) {
    float4 r4 = *(const float4*)(res + i);
    vx += r4.x; vy += r4.y; vz += r4.z; vw += r4.w;
  }
  if (OUTBF) {
    ushort4 o; o.x = f2bf(vx); o.y = f2bf(vy); o.z = f2bf(vz); o.w = f2bf(vw);
    *(ushort4*)((u16*)out + i) = o;
  } else {
    float4 o; o.x = vx; o.y = vy; o.z = vz; o.w = vw;
    *(float4*)((float*)out + i) = o;
  }
}

// ---------------------------------------------------------------------------
// Fused split-K reduce + residual + LayerNorm: one 320-thread block per row.
// ---------------------------------------------------------------------------
template <int S>
__global__ void redln_k(const u16* __restrict__ Pp, long long mn,
                        const float* __restrict__ bias,
                        float* __restrict__ x,
                        const float* __restrict__ s, const float* __restrict__ b,
                        u16* __restrict__ h) {
  int row = blockIdx.x;
  int d = threadIdx.x * 4;
  long long base = (long long)row * DMODEL + d;
  float vx = 0.f, vy = 0.f, vz = 0.f, vw = 0.f;
#pragma unroll
  for (int si = 0; si < S; si++) {
    ushort4 u4 = *(const ushort4*)(Pp + (long long)si * mn + base);
    vx += bf2f(u4.x); vy += bf2f(u4.y); vz += bf2f(u4.z); vw += bf2f(u4.w);
  }
  vx += bias[d]; vy += bias[d + 1]; vz += bias[d + 2]; vw += bias[d + 3];
  float4 r4 = *(const float4*)(x + base);
  vx += r4.x; vy += r4.y; vz += r4.z; vw += r4.w;
  float4 xv; xv.x = vx; xv.y = vy; xv.z = vz; xv.w = vw;
  *(float4*)(x + base) = xv;
  float sum = vx + vy + vz + vw;
#pragma unroll
  for (int o = 32; o; o >>= 1) sum += __shfl_xor(sum, o);
  __shared__ float red[8];
  int wv = threadIdx.x >> 6, lnn = threadIdx.x & 63;
  if (lnn == 0) red[wv] = sum;
  __syncthreads();
  float mu = 0.f;
  for (int i = 0; i < 5; i++) mu += red[i];
  mu *= (1.f / DMODEL);
  float dx = vx - mu, dy = vy - mu, dz = vz - mu, dw = vw - mu;
  float s2 = dx * dx + dy * dy + dz * dz + dw * dw;
#pragma unroll
  for (int o = 32; o; o >>= 1) s2 += __shfl_xor(s2, o);
  __syncthreads();
  if (lnn == 0) red[wv] = s2;
  __syncthreads();
  float var = 0.f;
  for (int i = 0; i < 5; i++) var += red[i];
  var *= (1.f / DMODEL);
  float rs = rsqrtf(var + 1e-6f);
  ushort4 o4;
  o4.x = f2bf(dx * rs * s[d] + b[d]);
  o4.y = f2bf(dy * rs * s[d + 1] + b[d + 1]);
  o4.z = f2bf(dz * rs * s[d + 2] + b[d + 2]);
  o4.w = f2bf(dw * rs * s[d + 3] + b[d + 3]);
  *(ushort4*)(h + base) = o4;
}

// ---------------------------------------------------------------------------
// Weight convert+transpose: in fp32 [K][N] -> out bf16 [N][K]. 32x32 tiles.
// ---------------------------------------------------------------------------
__global__ void wconv_k(const float* __restrict__ in, u16* __restrict__ out,
                        int K, int N) {
  __shared__ float tl[32][33];
  int n0 = blockIdx.x * 32, k0 = blockIdx.y * 32;
  int t = threadIdx.x;
  int r = t >> 5, c = t & 31;
#pragma unroll
  for (int i = 0; i < 4; i++)
    tl[r + 8 * i][c] = in[(long long)(k0 + r + 8 * i) * N + n0 + c];
  __syncthreads();
  int n = t >> 4, kp = (t & 15) * 2;
#pragma unroll
  for (int i = 0; i < 2; i++) {
    ushort2 o;
    o.x = f2bf(tl[kp][n + 16 * i]);
    o.y = f2bf(tl[kp + 1][n + 16 * i]);
    *(ushort2*)&out[(long long)(n0 + n + 16 * i) * K + k0 + kp] = o;
  }
}

// fp32 -> bf16 flat copy
__global__ void conv_k(const float* __restrict__ in, u16* __restrict__ out,
                       long long n) {
  long long i = ((long long)blockIdx.x * 256 + threadIdx.x) * 4;
  if (i >= n) return;
  float4 v = *(const float4*)(in + i);
  ushort4 o; o.x = f2bf(v.x); o.y = f2bf(v.y); o.z = f2bf(v.z); o.w = f2bf(v.w);
  *(ushort4*)&out[i] = o;
}

// V transpose per batch: in bf16 [b][512][128] -> out bf16 [b][128][512]
union U16x8 { uint4 v; u16 s[8]; };
__global__ void vtr_k(const u16* __restrict__ in, u16* __restrict__ out) {
  __shared__ u16 tl[64][65];
  int b = blockIdx.z;
  int m0 = blockIdx.x * 64;
  int d0 = blockIdx.y * 64;
  const u16* ib = in + (long long)b * SEG * 128;
  u16* ob = out + (long long)b * 128 * SEG;
  int t = threadIdx.x;
  int r = t >> 3, c8 = (t & 7) * 8;
#pragma unroll
  for (int i = 0; i < 2; i++) {
    U16x8 ld;
    ld.v = *(const uint4*)&ib[(long long)(m0 + r + 32 * i) * 128 + d0 + c8];
#pragma unroll
    for (int j = 0; j < 8; j++) tl[r + 32 * i][c8 + j] = ld.s[j];
  }
  __syncthreads();
  int d = t >> 3, m8 = (t & 7) * 8;
#pragma unroll
  for (int i = 0; i < 2; i++) {
    int dd = d + 32 * i;
    U16x8 st;
#pragma unroll
    for (int j = 0; j < 8; j++) st.s[j] = tl[m8 + j][dd];
    *(uint4*)&ob[(long long)(d0 + dd) * SEG + m0 + m8] = st.v;
  }
}

// ---------------------------------------------------------------------------
__global__ void coords_k(const int* __restrict__ g, int nimg,
                         int* __restrict__ rw, int* __restrict__ cl,
                         int* __restrict__ hh, int* __restrict__ ww, int N) {
  int t = blockIdx.x * 256 + threadIdx.x;
  if (t >= N) return;
  int c = 0, local = 0, H = 1, W = 1;
  for (int i = 0; i < nimg; i++) {
    int tpi = g[i * 3] * g[i * 3 + 1] * g[i * 3 + 2];
    if (t >= c && t < c + tpi) { local = t - c; H = g[i * 3 + 1]; W = g[i * 3 + 2]; }
    c += tpi;
  }
  int hw = H * W;
  int sp = local % hw;
  int mw = W >> 1;
  int gr = sp >> 2, intra = sp & 3;
  rw[t] = (gr / mw) * 2 + (intra >> 1);
  cl[t] = (gr % mw) * 2 + (intra & 1);
  hh[t] = H; ww[t] = W;
}

__global__ void peadd_k(float* __restrict__ x, const float* __restrict__ pe,
                        const int* __restrict__ rw, const int* __restrict__ cl,
                        const int* __restrict__ hh, const int* __restrict__ ww) {
  int n = blockIdx.x;
  int d = threadIdx.x * 4;
  int H = hh[n], W = ww[n];
  float rf = (H > 1) ? (float)rw[n] * (float)(GPOS - 1) / (float)(H - 1) : 0.f;
  float cf = (W > 1) ? (float)cl[n] * (float)(GPOS - 1) / (float)(W - 1) : 0.f;
  int r0 = (int)floorf(rf), c0 = (int)floorf(cf);
  int r1 = min(r0 + 1, GPOS - 1), c1 = min(c0 + 1, GPOS - 1);
  float wr = rf - (float)r0, wc = cf - (float)c0;
  float w00 = (1.f - wr) * (1.f - wc), w01 = (1.f - wr) * wc;
  float w10 = wr * (1.f - wc), w11 = wr * wc;
  float4 v00 = *(const float4*)(pe + (long long)(r0 * GPOS + c0) * DMODEL + d);
  float4 v01 = *(const float4*)(pe + (long long)(r0 * GPOS + c1) * DMODEL + d);
  float4 v10 = *(const float4*)(pe + (long long)(r1 * GPOS + c0) * DMODEL + d);
  float4 v11 = *(const float4*)(pe + (long long)(r1 * GPOS + c1) * DMODEL + d);
  float4 xv = *(float4*)(x + (long long)n * DMODEL + d);
  xv.x += w00 * v00.x + w01 * v01.x + w10 * v10.x + w11 * v11.x;
  xv.y += w00 * v00.y + w01 * v01.y + w10 * v10.y + w11 * v11.y;
  xv.z += w00 * v00.z + w01 * v01.z + w10 * v10.z + w11 * v11.z;
  xv.w += w00 * v00.w + w01 * v01.w + w10 * v10.w + w11 * v11.w;
  *(float4*)(x + (long long)n * DMODEL + d) = xv;
}

// LayerNorm fp32 in -> bf16 out (one 320-thread block per row of 1280)
__global__ void ln_k(const float* __restrict__ X, u16* __restrict__ Y,
                     const float* __restrict__ s, const float* __restrict__ b) {
  int row = blockIdx.x;
  int d = threadIdx.x * 4;
  const float* x = X + (long long)row * DMODEL;
  float4 v = *(const float4*)(x + d);
  float sum = v.x + v.y + v.z + v.w;
#pragma unroll
  for (int o = 32; o; o >>= 1) sum += __shfl_xor(sum, o);
  __shared__ float red[8];
  int wv = threadIdx.x >> 6, lnn = threadIdx.x & 63;
  if (lnn == 0) red[wv] = sum;
  __syncthreads();
  float mu = 0.f;
  for (int i = 0; i < 5; i++) mu += red[i];
  mu *= (1.f / DMODEL);
  float dx = v.x - mu, dy = v.y - mu, dz = v.z - mu, dw = v.w - mu;
  float s2 = dx * dx + dy * dy + dz * dz + dw * dw;
#pragma unroll
  for (int o = 32; o; o >>= 1) s2 += __shfl_xor(s2, o);
  __syncthreads();
  if (lnn == 0) red[wv] = s2;
  __syncthreads();
  float var = 0.f;
  for (int i = 0; i < 5; i++) var += red[i];
  var *= (1.f / DMODEL);
  float rs = rsqrtf(var + 1e-6f);
  ushort4 o4;
  o4.x = f2bf(dx * rs * s[d] + b[d]);
  o4.y = f2bf(dy * rs * s[d + 1] + b[d + 1]);
  o4.z = f2bf(dz * rs * s[d + 2] + b[d + 2]);
  o4.w = f2bf(dw * rs * s[d + 3] + b[d + 3]);
  *(ushort4*)(Y + (long long)row * DMODEL + d) = o4;
}

// RoPE from bf16 qkv -> qr/kr bf16 [h][N][96] (zero pad), v -> vp [h][N][128]
__global__ void rope_k(const u16* __restrict__ qkv, const int* __restrict__ rw,
                       const int* __restrict__ cl, u16* __restrict__ qr,
                       u16* __restrict__ kr, u16* __restrict__ vp, int N) {
  int n = blockIdx.x, h = blockIdx.y, t = threadIdx.x;
  const u16* src = qkv + (long long)n * (3 * DMODEL) + h * 80;
  long long ob96 = ((long long)h * N + n) * 96;
  long long ob128 = ((long long)h * N + n) * 128;
  if (t < 40) {
    float pos = (t < 20) ? (float)rw[n] : (float)cl[n];
    float infr = exp2f(-13.287712379549449f * (float)(t % 20) * 0.05f);
    float f = pos * infr;
    float cs = cosf(f), sn = sinf(f);
    float q0 = bf2f(src[t]), q1 = bf2f(src[t + 40]);
    qr[ob96 + t] = f2bf(q0 * cs - q1 * sn);
    qr[ob96 + t + 40] = f2bf(q1 * cs + q0 * sn);
    float k0 = bf2f(src[DMODEL + t]), k1 = bf2f(src[DMODEL + t + 40]);
    kr[ob96 + t] = f2bf(k0 * cs - k1 * sn);
    kr[ob96 + t + 40] = f2bf(k1 * cs + k0 * sn);
    vp[ob128 + t] = src[2 * DMODEL + t];
    vp[ob128 + t + 40] = src[2 * DMODEL + t + 40];
  } else {
    int u = t - 40;
    if (u < 16) { qr[ob96 + 80 + u] = 0; kr[ob96 + 80 + u] = 0; }
    vp[ob128 + 80 + u] = 0;
    vp[ob128 + 104 + u] = 0;
  }
}

// ---------------------------------------------------------------------------
// 128x128-tile path: M%128==0, Nn%128==0, (Kd/nsplit)%32==0.
static void gemm_big(hipStream_t st, int epi, const u16* A, const u16* B,
                     const float* bias, void* C, int M, int Nn, int Kd,
                     int lda, int ldb, int ldc, int nsplit) {
  dim3 g(M / 128, Nn / 128, nsplit), blk(256);
  long long ps = (long long)M * Nn;
  switch (epi) {
    case 0: gemm128<0><<<g, blk, 0, st>>>(A, B, bias, C, Kd, lda, ldb, ldc, nsplit, ps); break;
    case 1: gemm128<1><<<g, blk, 0, st>>>(A, B, bias, C, Kd, lda, ldb, ldc, nsplit, ps); break;
    default: gemm128<3><<<g, blk, 0, st>>>(A, B, bias, C, Kd, lda, ldb, ldc, nsplit, ps); break;
  }
}

extern "C" void kernel_launch(void* const* d_in, const int* in_sizes, int n_in,
                              void* d_out, int out_size, void* d_ws, size_t ws_size,
                              hipStream_t stream) {
  const float* pixels = (const float*)d_in[0];
  const int* grid_thw = (const int*)d_in[1];
  const float* pos_embed = (const float*)d_in[2];
  const float* patch_w = (const float*)d_in[3];
  const float* patch_b = (const float*)d_in[4];
  const float* ln1_s = (const float*)d_in[5];
  const float* ln1_b = (const float*)d_in[6];
  const float* qkv_w = (const float*)d_in[7];
  const float* qkv_b = (const float*)d_in[8];
  const float* proj_w = (const float*)d_in[9];
  const float* proj_b = (const float*)d_in[10];
  const float* ln2_s = (const float*)d_in[11];
  const float* ln2_b = (const float*)d_in[12];
  const float* fc1_w = (const float*)d_in[13];
  const float* fc1_b = (const float*)d_in[14];
  const float* fc2_w = (const float*)d_in[15];
  const float* fc2_b = (const float*)d_in[16];
  const float* mns = (const float*)d_in[17];
  const float* mnb = (const float*)d_in[18];
  const float* mf1w = (const float*)d_in[19];
  const float* mf1b = (const float*)d_in[20];
  const float* mf2w = (const float*)d_in[21];
  const float* mf2b = (const float*)d_in[22];
  float* out = (float*)d_out;

  const int N = in_sizes[0] / 1536;  // 2048
  const int nimg = in_sizes[1] / 3;  // 4
  const int nseg = N / SEG;          // 4
  const int nb = NHEADS * nseg;      // 64

  char* w = (char*)d_ws;
  size_t off = 0;
  auto alloc = [&](size_t bytes) -> void* {
    void* p = w + off;
    off += (bytes + 255) & ~(size_t)255;
    return p;
  };
  int* rw = (int*)alloc((size_t)N * 4);
  int* cl = (int*)alloc((size_t)N * 4);
  int* hh = (int*)alloc((size_t)N * 4);
  int* ww = (int*)alloc((size_t)N * 4);
  float* x = (float*)alloc((size_t)N * DMODEL * 4);
  u16* h = (u16*)alloc((size_t)N * DMODEL * 2);
  u16* pixbf = (u16*)alloc((size_t)N * 1536 * 2);      // mfc2T overlay base
  u16* patchT = (u16*)alloc((size_t)DMODEL * 1536 * 2);
  u16* qkvT = (u16*)alloc((size_t)3 * DMODEL * DMODEL * 2);
  u16* projT = (u16*)alloc((size_t)DMODEL * DMODEL * 2);
  u16* fc1T = (u16*)alloc((size_t)FDIM * DMODEL * 2);
  u16* fc2T = (u16*)alloc((size_t)DMODEL * FDIM * 2);
  u16* qkvb = (u16*)alloc((size_t)N * 3 * DMODEL * 2);  // mfc1T overlay base
  u16* qr = (u16*)alloc((size_t)NHEADS * N * 96 * 2);
  u16* kr = (u16*)alloc((size_t)NHEADS * N * 96 * 2);
  u16* vp = (u16*)alloc((size_t)NHEADS * N * 128 * 2);
  u16* vpT = (u16*)alloc((size_t)NHEADS * N * 128 * 2);
  u16* pad0 = (u16*)alloc((size_t)nb * 2 * SEG * 128 * 2);  // keeps mfc1T overlay in bounds
  u16* o = (u16*)alloc((size_t)N * DMODEL * 2);
  float* bigA = (float*)alloc((size_t)nb * SEG * SEG * 4);  // ffb / mf
  float* bigB = (float*)alloc((size_t)nb * SEG * SEG * 2);  // split-K partials
  (void)ws_size; (void)pad0;
  // overlays (lifetimes disjoint with originals)
  u16* mfc1T = qkvb;         // 52.4 MB over qkvb..pad0 region
  u16* mfc2T = pixbf;        // 21.0 MB over pixbf..projT
  u16* ffb = (u16*)bigA;     // fc1 out, 21 MB at bigA base
  u16* mf = (u16*)bigA;      // merger hidden 5.2 MB at bigA base
  u16* part = (u16*)bigB;    // split-K bf16 partial planes (<= 33.5 MB)

  const float iscale = 0.11180339887498949f;  // 80^-0.5
  const long long mnD = (long long)N * DMODEL;

  coords_k<<<dim3((N + 255) / 256), 256, 0, stream>>>(grid_thw, nimg, rw, cl, hh, ww, N);
  conv_k<<<dim3((int)(((long long)N * 1536 / 4 + 255) / 256)), 256, 0, stream>>>(
      pixels, pixbf, (long long)N * 1536);
  wconv_k<<<dim3(DMODEL / 32, 1536 / 32), 256, 0, stream>>>(patch_w, patchT, 1536, DMODEL);
  // patch embed, split-K=4 (640 blocks)
  gemm_big(stream, 0, pixbf, patchT, nullptr, part, N, DMODEL, 1536, 1536, 1536,
           DMODEL, 4);
  reduce_k<4, 0, 0, 0><<<dim3((int)((mnD / 4 + 255) / 256)), 256, 0, stream>>>(
      part, mnD, DMODEL, patch_b, nullptr, x);
  peadd_k<<<dim3(N), 320, 0, stream>>>(x, pos_embed, rw, cl, hh, ww);
  // ln1 of layer 0 (subsequent LNs fused into split-K reduces)
  ln_k<<<dim3(N), 320, 0, stream>>>(x, h, ln1_s, ln1_b);

  for (int l = 0; l < 4; l++) {
    wconv_k<<<dim3(3 * DMODEL / 32, DMODEL / 32), 256, 0, stream>>>(
        qkv_w + (size_t)l * DMODEL * 3 * DMODEL, qkvT, DMODEL, 3 * DMODEL);
    wconv_k<<<dim3(DMODEL / 32, DMODEL / 32), 256, 0, stream>>>(
        proj_w + (size_t)l * DMODEL * DMODEL, projT, DMODEL, DMODEL);
    wconv_k<<<dim3(FDIM / 32, DMODEL / 32), 256, 0, stream>>>(
        fc1_w + (size_t)l * DMODEL * FDIM, fc1T, DMODEL, FDIM);
    wconv_k<<<dim3(DMODEL / 32, FDIM / 32), 256, 0, stream>>>(
        fc2_w + (size_t)l * FDIM * DMODEL, fc2T, FDIM, DMODEL);

    // qkv direct +bias (480 blocks, NT=40)
    gemm_big(stream, 1, h, qkvT, qkv_b + (size_t)l * 3 * DMODEL, qkvb, N,
             3 * DMODEL, DMODEL, DMODEL, DMODEL, 3 * DMODEL, 1);
    rope_k<<<dim3(N, NHEADS), 64, 0, stream>>>(qkvb, rw, cl, qr, kr, vp, N);
    vtr_k<<<dim3(8, 2, nb), 256, 0, stream>>>(vp, vpT);
    // fused flash attention -> o (256 blocks, 1/CU, XCD-chunked)
    fattn_k<<<dim3(SEG / 128, nb), 256, 0, stream>>>(qr, kr, vpT, o, N, iscale);
    // proj split-K=4 (640 blocks); fused reduce + bias + residual + ln2 -> h
    gemm_big(stream, 0, o, projT, nullptr, part, N, DMODEL, DMODEL, DMODEL,
             DMODEL, DMODEL, 4);
    redln_k<4><<<dim3(N), 320, 0, stream>>>(part, mnD, proj_b + (size_t)l * DMODEL,
                                            x, ln2_s + (size_t)l * DMODEL,
                                            ln2_b + (size_t)l * DMODEL, h);
    // fc1 fused bias+gelu -> bf16 (640 blocks, direct)
    gemm_big(stream, 3, h, fc1T, fc1_b + (size_t)l * FDIM, ffb, N, FDIM, DMODEL,
             DMODEL, DMODEL, FDIM, 1);
    // fc2 split-K=4 (640 blocks); fused reduce + bias + residual + next LN -> h
    gemm_big(stream, 0, ffb, fc2T, nullptr, part, N, DMODEL, FDIM, FDIM, FDIM,
             DMODEL, 4);
    const float* nsl = (l < 3) ? ln1_s + (size_t)(l + 1) * DMODEL : mns;
    const float* nbl = (l < 3) ? ln1_b + (size_t)(l + 1) * DMODEL : mnb;
    redln_k<4><<<dim3(N), 320, 0, stream>>>(part, mnD, fc2_b + (size_t)l * DMODEL,
                                            x, nsl, nbl, h);
  }

  // merger (h already = LN(x; mns,mnb), viewed as [512][5120])
  const int Mm = N / 4;  // 512
  wconv_k<<<dim3(FDIM / 32, FDIM / 32), 256, 0, stream>>>(mf1w, mfc1T, FDIM, FDIM);
  // mfc1 split-K=4 (640 blocks); reduce + bias + gelu -> mf
  gemm_big(stream, 0, h, mfc1T, nullptr, part, Mm, FDIM, FDIM, FDIM, FDIM, FDIM, 4);
  reduce_k<4, 0, 1, 1><<<dim3((int)(((long long)Mm * FDIM / 4 + 255) / 256)), 256, 0, stream>>>(
      part, (long long)Mm * FDIM, FDIM, mf1b, nullptr, mf);
  wconv_k<<<dim3(2048 / 32, FDIM / 32), 256, 0, stream>>>(mf2w, mfc2T, FDIM, 2048);
  // mfc2 split-K=16 (1024 blocks)
  gemm_big(stream, 0, mf, mfc2T, nullptr, part, Mm, 2048, FDIM, FDIM, FDIM, 2048, 16);
  reduce_k<16, 0, 0, 0><<<dim3((int)(((long long)Mm * 2048 / 4 + 255) / 256)), 256, 0, stream>>>(
      part, (long long)Mm * 2048, 2048, mf2b, nullptr, out);
}

// Round 9
// 1314.419 us; speedup vs baseline: 1.1545x; 1.0366x over previous
//
#include <hip/hip_runtime.h>
#include <math.h>

#define DMODEL 1280
#define NHEADS 16
#define FDIM   5120
#define GPOS   48
#define SEG    512

typedef __attribute__((ext_vector_type(8))) short bf16x8;
typedef __attribute__((ext_vector_type(4))) float f32x4;
typedef unsigned short u16;

__device__ __forceinline__ u16 f2bf(float f) {
  unsigned int u = __float_as_uint(f);
  u = (u + 0x7FFFu + ((u >> 16) & 1u)) >> 16;  // RNE
  return (u16)u;
}
__device__ __forceinline__ float bf2f(u16 u) {
  return __uint_as_float((unsigned int)u << 16);
}
__device__ __forceinline__ float gelu_tanh(float x) {
  float u = 0.7978845608028654f * (x + 0.044715f * x * x * x);
  float t = __expf(2.f * u);
  float th = 1.f - 2.f / (t + 1.f);
  return 0.5f * x * (1.f + th);
}

typedef const __attribute__((address_space(1))) unsigned int* gas_t;
typedef __attribute__((address_space(3))) unsigned int* las_t;
__device__ __forceinline__ void async16(const void* g, void* l) {
  __builtin_amdgcn_global_load_lds((gas_t)g, (las_t)l, 16, 0, 0);
}

// Bijective XCD chunk remap (T1, m204 form).
__device__ __forceinline__ int xcd_remap(int b, int nwg) {
  int q = nwg >> 3, r = nwg & 7, x = b & 7, d = b >> 3;
  return (x < r ? x * (q + 1) : r * (q + 1) + (x - r) * q) + d;
}

// ---------------------------------------------------------------------------
// gemm128 (R8-verified): 128x128 tile, BK=32, 4 waves, 32 KiB dbuf LDS,
// 3 blocks/CU, R2 subtile swizzle, T1 remap, 2 phases/tile, depth-1
// prefetch, per-element accumulation order fixed (k0,k32,...).
// A:[M][K] bf16, B:[N][K] bf16, C = A.B^T.
// EPI 0: bf16 partial planes (split-K). EPI 1: +bias bf16. EPI 3: +bias+gelu.
// ---------------------------------------------------------------------------
#define STG1(mat, PW, ldx, rb, kk, pp)                                      \
  async16((PW) + (long long)(rb) * 16 * (ldx) + (kk),                       \
          &L[pp][mat][(rb) * 512])

#define BARX() asm volatile("s_barrier" ::: "memory")
#define LGKM0() asm volatile("s_waitcnt lgkmcnt(0)" ::: "memory")

template <int EPI>
__global__ __launch_bounds__(256, 3) void gemm128(
    const u16* __restrict__ A, const u16* __restrict__ B,
    const float* __restrict__ bias, void* __restrict__ Cv,
    int Kd, int lda, int ldb, int ldc, int nsplit, long long pstride) {
  __shared__ __align__(16) u16 L[2][2][4096];  // [buf][A|B][8rb x 512]
  const int sp = blockIdx.z;
  const int Ks = Kd / nsplit;
  const int NT = Ks >> 5;
  const u16* Ab = A + (long long)sp * Ks;
  const u16* Bb = B + (long long)sp * Ks;
  const int gx = gridDim.x;
  const int lg = xcd_remap(blockIdx.x + gx * blockIdx.y, gx * gridDim.y);
  const int m0 = (lg % gx) * 128, n0 = (lg / gx) * 128;
  const int t = threadIdx.x, ln = t & 63, w = t >> 6;
  const int wr = w >> 1, wc = w & 1;
  const int m16 = ln & 15, q = ln >> 4;
  const int r16 = ln >> 2;
  const int csw = (ln & 3) ^ ((ln >> 5) << 1);               // R2 source swz
  const int rbase = m16 * 32 + (q ^ ((m16 >> 3) << 1)) * 8;  // R2 read swz

  const u16* Aw = Ab + (long long)(m0 + r16) * lda + csw * 8;
  const u16* Bw = Bb + (long long)(n0 + r16) * ldb + csw * 8;
  const int w4 = w + 4;

  f32x4 acc[4][4];
#pragma unroll
  for (int i = 0; i < 4; i++)
#pragma unroll
    for (int j = 0; j < 4; j++)
#pragma unroll
      for (int r = 0; r < 4; r++) acc[i][j][r] = 0.f;

  // prologue: tile0 (4 loads/wave) + tile1 (4); vmcnt(4) -> tile0 landed.
  STG1(0, Aw, lda, w, 0, 0);  STG1(0, Aw, lda, w4, 0, 0);
  STG1(1, Bw, ldb, w, 0, 0);  STG1(1, Bw, ldb, w4, 0, 0);
  if (NT > 1) {
    STG1(0, Aw, lda, w, 32, 1);  STG1(0, Aw, lda, w4, 32, 1);
    STG1(1, Bw, ldb, w, 32, 1);  STG1(1, Bw, ldb, w4, 32, 1);
    asm volatile("s_waitcnt vmcnt(4)" ::: "memory");
  } else {
    asm volatile("s_waitcnt vmcnt(0)" ::: "memory");
  }
  BARX();

  for (int tt = 0; tt < NT; ++tt) {
    const int p = tt & 1;
    const u16* Abuf = &L[p][0][0];
    const u16* Bbuf = &L[p][1][0];
    bf16x8 aR[4], bR[4];

    // ph1: ds all aR (4) + bR[0..1] (2); stage A(t+1) -> buf p^1
#pragma unroll
    for (int i = 0; i < 4; ++i)
      aR[i] = *(const bf16x8*)(Abuf + (wr * 4 + i) * 512 + rbase);
    bR[0] = *(const bf16x8*)(Bbuf + (wc * 4 + 0) * 512 + rbase);
    bR[1] = *(const bf16x8*)(Bbuf + (wc * 4 + 1) * 512 + rbase);
    if (tt + 1 < NT) {
      STG1(0, Aw, lda, w, (tt + 1) * 32, p ^ 1);
      STG1(0, Aw, lda, w4, (tt + 1) * 32, p ^ 1);
    }
    BARX();
    LGKM0();
    __builtin_amdgcn_s_setprio(1);
#pragma unroll
    for (int i = 0; i < 4; ++i) {
      acc[i][0] = __builtin_amdgcn_mfma_f32_16x16x32_bf16(aR[i], bR[0], acc[i][0], 0, 0, 0);
      acc[i][1] = __builtin_amdgcn_mfma_f32_16x16x32_bf16(aR[i], bR[1], acc[i][1], 0, 0, 0);
    }
    __builtin_amdgcn_s_setprio(0);
    BARX();

    // ph2: ds bR[2..3] (2); stage B(t+1) -> buf p^1; tile-end drain
    bR[2] = *(const bf16x8*)(Bbuf + (wc * 4 + 2) * 512 + rbase);
    bR[3] = *(const bf16x8*)(Bbuf + (wc * 4 + 3) * 512 + rbase);
    if (tt + 1 < NT) {
      STG1(1, Bw, ldb, w, (tt + 1) * 32, p ^ 1);
      STG1(1, Bw, ldb, w4, (tt + 1) * 32, p ^ 1);
    }
    BARX();
    LGKM0();
    __builtin_amdgcn_s_setprio(1);
#pragma unroll
    for (int i = 0; i < 4; ++i) {
      acc[i][2] = __builtin_amdgcn_mfma_f32_16x16x32_bf16(aR[i], bR[2], acc[i][2], 0, 0, 0);
      acc[i][3] = __builtin_amdgcn_mfma_f32_16x16x32_bf16(aR[i], bR[3], acc[i][3], 0, 0, 0);
    }
    __builtin_amdgcn_s_setprio(0);
    if (tt + 1 < NT) asm volatile("s_waitcnt vmcnt(0)" ::: "memory");
    BARX();
  }

#pragma unroll
  for (int fr = 0; fr < 4; fr++) {
#pragma unroll
    for (int r = 0; r < 4; r++) {
      int row = m0 + wr * 64 + fr * 16 + q * 4 + r;
      if (EPI == 0) {
        u16* Cp = (u16*)Cv + (long long)sp * pstride + (long long)row * ldc;
#pragma unroll
        for (int fc = 0; fc < 4; fc++)
          Cp[n0 + wc * 64 + fc * 16 + m16] = f2bf(acc[fr][fc][r]);
      } else if (EPI == 1) {
        u16* Cb = (u16*)Cv + (long long)row * ldc;
#pragma unroll
        for (int fc = 0; fc < 4; fc++) {
          int col = n0 + wc * 64 + fc * 16 + m16;
          Cb[col] = f2bf(acc[fr][fc][r] + bias[col]);
        }
      } else {  // EPI == 3
        u16* Cb = (u16*)Cv + (long long)row * ldc;
#pragma unroll
        for (int fc = 0; fc < 4; fc++) {
          int col = n0 + wc * 64 + fc * 16 + m16;
          Cb[col] = f2bf(gelu_tanh(acc[fr][fc][r] + bias[col]));
        }
      }
    }
  }
}

// ---------------------------------------------------------------------------
// Fused flash attention, 8-wave re-partition: 512 threads, each wave owns
// 16 q-rows (was 4 waves x 32 rows = 1 wave/SIMD, zero TLP). 2 waves/SIMD
// lets one wave's serial softmax/exp/P-store hide under another's MFMA.
// Per-q-row math, P-panel XOR layout, staging addresses and accumulation
// order identical to the R6-verified form -> bit-identical results.
// LDS: K/V dbuf 90 KB + 8 x 4 KB P panels = 122.8 KB (1 block/CU).
// Grid: (SEG/128, NHEADS*nseg), T1-chunked.
// ---------------------------------------------------------------------------
__global__ __launch_bounds__(512) void fattn_k(
    const u16* __restrict__ qr, const u16* __restrict__ kr,
    const u16* __restrict__ vpT, u16* __restrict__ o, int N, float iscale) {
  __shared__ __align__(16) u16 Ks[2][24][512];   // [buf][f*3+kg][16kv x 32hd]
  __shared__ __align__(16) u16 Vs[2][20][512];   // [buf][df*4+kvg][16d x 32kv]
  __shared__ __align__(16) u16 Ps[8][16 * 128];  // per-wave P panel (16 rows)
  const int nseg = N >> 9;
  const int gx = gridDim.x;
  const int lg = xcd_remap(blockIdx.x + gx * blockIdx.y, gx * gridDim.y);
  const int strip = lg % gx, hb = lg / gx;
  const int h = hb / nseg, seg = hb - h * nseg;
  const int t = threadIdx.x, ln = t & 63, w = t >> 6;  // w in [0,8)
  const int m16 = ln & 15, qh = ln >> 4;
  const int r4 = ln >> 2, gsw = (ln & 3) ^ ((ln >> 5) << 1);
  const int rbase = m16 * 32 + ((qh ^ ((m16 >> 3) << 1)) << 3);
  const long long hN = (long long)h * N;
  const int segbase = seg * SEG;
  const int q0 = segbase + strip * 128 + w * 16;  // 8 waves x 16 rows

  bf16x8 qf[3];
#pragma unroll
  for (int ks = 0; ks < 3; ks++)
    qf[ks] = *(const bf16x8*)&qr[(hN + q0 + m16) * 96 + ks * 32 + qh * 8];

  f32x4 ao[5];
#pragma unroll
  for (int df = 0; df < 5; df++)
#pragma unroll
    for (int r = 0; r < 4; r++) ao[df][r] = 0.f;
  float m_[4], l_[4];
#pragma unroll
  for (int r = 0; r < 4; r++) { m_[r] = -1e30f; l_[r] = 0.f; }

  auto stage = [&](int c, int pb) {
#pragma unroll
    for (int i = 0; i < 3; i++) {  // 24 K subtiles over 8 waves
      int sK = w * 3 + i, f = sK / 3, kg = sK - f * 3;
      async16(&kr[(hN + segbase + c * 128 + f * 16 + r4) * 96 + kg * 32 + gsw * 8],
              &Ks[pb][sK][0]);
    }
#pragma unroll
    for (int i = 0; i < 2; i++) {  // 16 of 20 V subtiles
      int sV = w * 2 + i, df = sV >> 2, kvg = sV & 3;
      async16(&vpT[((long long)hb * 128 + df * 16 + r4) * SEG + c * 128 + kvg * 32 + gsw * 8],
              &Vs[pb][sV][0]);
    }
    if (w < 4) {  // remaining 4 V subtiles
      int sV = 16 + w, df = sV >> 2, kvg = sV & 3;
      async16(&vpT[((long long)hb * 128 + df * 16 + r4) * SEG + c * 128 + kvg * 32 + gsw * 8],
              &Vs[pb][sV][0]);
    }
  };

  stage(0, 0);
  u16* Pmy = &Ps[w][0];
  for (int c = 0; c < 4; c++) {
    const int pb = c & 1;
    __syncthreads();  // implicit vmcnt(0)+lgkmcnt(0): buf[pb] staged by all waves
    if (c < 3) stage(c + 1, pb ^ 1);

    // QK^T: s[f] rows q=qh*4+r, cols kv=f*16+m16
    f32x4 s[8];
#pragma unroll
    for (int f = 0; f < 8; f++)
#pragma unroll
      for (int r = 0; r < 4; r++) s[f][r] = 0.f;
#pragma unroll
    for (int ks = 0; ks < 3; ks++) {
#pragma unroll
      for (int f = 0; f < 8; f++) {
        bf16x8 kf = *(const bf16x8*)&Ks[pb][f * 3 + ks][rbase];
        s[f] = __builtin_amdgcn_mfma_f32_16x16x32_bf16(qf[ks], kf, s[f], 0, 0, 0);
      }
    }

    // online softmax per row
#pragma unroll
    for (int r = 0; r < 4; r++) {
      float mx = s[0][r];
#pragma unroll
      for (int f = 1; f < 8; f++) mx = fmaxf(mx, s[f][r]);
      mx *= iscale;
#pragma unroll
      for (int o2 = 1; o2 <= 8; o2 <<= 1) mx = fmaxf(mx, __shfl_xor(mx, o2));
      float mn = fmaxf(m_[r], mx);
      float corr = __expf(m_[r] - mn);
      m_[r] = mn;
      float rs = 0.f;
#pragma unroll
      for (int f = 0; f < 8; f++) {
        float p = __expf(s[f][r] * iscale - mn);
        s[f][r] = p;
        rs += p;
      }
#pragma unroll
      for (int o2 = 1; o2 <= 8; o2 <<= 1) rs += __shfl_xor(rs, o2);
      l_[r] = l_[r] * corr + rs;
#pragma unroll
      for (int df = 0; df < 5; df++) ao[df][r] *= corr;
    }

    // P -> LDS (per-wave private): addr(q,kv)=q*128 + ((kv>>3)^(q&7))*8 + (kv&7)
#pragma unroll
    for (int r = 0; r < 4; r++) {
      int qq = qh * 4 + r;  // 0..15
      int base = qq * 128 + (m16 & 7);
      int ql = qq & 7;
#pragma unroll
      for (int f = 0; f < 8; f++) {
        int gr = (f * 2 + (m16 >> 3)) ^ ql;
        Pmy[base + gr * 8] = f2bf(s[f][r]);
      }
    }

    // PV: O[q][d] += P[q][kv] V^T[d][kv]
#pragma unroll
    for (int ks = 0; ks < 4; ks++) {
      bf16x8 pf = *(const bf16x8*)&Pmy[m16 * 128 +
                                       (((ks * 4 + qh) ^ (m16 & 7)) << 3)];
#pragma unroll
      for (int df = 0; df < 5; df++) {
        bf16x8 vf = *(const bf16x8*)&Vs[pb][df * 4 + ks][rbase];
        ao[df] = __builtin_amdgcn_mfma_f32_16x16x32_bf16(pf, vf, ao[df], 0, 0, 0);
      }
    }
  }

#pragma unroll
  for (int r = 0; r < 4; r++) {
    float rl = 1.f / l_[r];
    long long rowb = (long long)(q0 + qh * 4 + r) * DMODEL + h * 80;
#pragma unroll
    for (int df = 0; df < 5; df++)
      o[rowb + df * 16 + m16] = f2bf(ao[df][r] * rl);
  }
}

// ---------------------------------------------------------------------------
// Split-K reduce + epilogue (bf16 partials): out = [gelu](sum + bias) [+ res]
// ---------------------------------------------------------------------------
template <int S, int RES, int GELU, int OUTBF>
__global__ void reduce_k(const u16* __restrict__ Pp, long long mn, int Nn,
                         const float* __restrict__ bias,
                         const float* __restrict__ res, void* __restrict__ out) {
  long long i = ((long long)blockIdx.x * 256 + threadIdx.x) * 4;
  if (i >= mn) return;
  float vx = 0.f, vy = 0.f, vz = 0.f, vw = 0.f;
#pragma unroll
  for (int s = 0; s < S; s++) {
    ushort4 u4 = *(const ushort4*)(Pp + (long long)s * mn + i);
    vx += bf2f(u4.x); vy += bf2f(u4.y); vz += bf2f(u4.z); vw += bf2f(u4.w);
  }
  int col = (int)(i % Nn);
  vx += bias[col]; vy += bias[col + 1]; vz += bias[col + 2]; vw += bias[col + 3];
  if (GELU) {
    vx = gelu_tanh(vx); vy = gelu_tanh(vy);
    vz = gelu_tanh(vz); vw = gelu_tanh(vw);
  }
  if (RES) {
    float4 r4 = *(const float4*)(res + i);
    vx += r4.x; vy += r4.y; vz += r4.z; vw += r4.w;
  }
  if (OUTBF) {
    ushort4 o; o.x = f2bf(vx); o.y = f2bf(vy); o.z = f2bf(vz); o.w = f2bf(vw);
    *(ushort4*)((u16*)out + i) = o;
  } else {
    float4 o; o.x = vx; o.y = vy; o.z = vz; o.w = vw;
    *(float4*)((float*)out + i) = o;
  }
}

// ---------------------------------------------------------------------------
// Fused split-K reduce + residual + LayerNorm: one 320-thread block per row.
// ---------------------------------------------------------------------------
template <int S>
__global__ void redln_k(const u16* __restrict__ Pp, long long mn,
                        const float* __restrict__ bias,
                        float* __restrict__ x,
                        const float* __restrict__ s, const float* __restrict__ b,
                        u16* __restrict__ h) {
  int row = blockIdx.x;
  int d = threadIdx.x * 4;
  long long base = (long long)row * DMODEL + d;
  float vx = 0.f, vy = 0.f, vz = 0.f, vw = 0.f;
#pragma unroll
  for (int si = 0; si < S; si++) {
    ushort4 u4 = *(const ushort4*)(Pp + (long long)si * mn + base);
    vx += bf2f(u4.x); vy += bf2f(u4.y); vz += bf2f(u4.z); vw += bf2f(u4.w);
  }
  vx += bias[d]; vy += bias[d + 1]; vz += bias[d + 2]; vw += bias[d + 3];
  float4 r4 = *(const float4*)(x + base);
  vx += r4.x; vy += r4.y; vz += r4.z; vw += r4.w;
  float4 xv; xv.x = vx; xv.y = vy; xv.z = vz; xv.w = vw;
  *(float4*)(x + base) = xv;
  float sum = vx + vy + vz + vw;
#pragma unroll
  for (int o = 32; o; o >>= 1) sum += __shfl_xor(sum, o);
  __shared__ float red[8];
  int wv = threadIdx.x >> 6, lnn = threadIdx.x & 63;
  if (lnn == 0) red[wv] = sum;
  __syncthreads();
  float mu = 0.f;
  for (int i = 0; i < 5; i++) mu += red[i];
  mu *= (1.f / DMODEL);
  float dx = vx - mu, dy = vy - mu, dz = vz - mu, dw = vw - mu;
  float s2 = dx * dx + dy * dy + dz * dz + dw * dw;
#pragma unroll
  for (int o = 32; o; o >>= 1) s2 += __shfl_xor(s2, o);
  __syncthreads();
  if (lnn == 0) red[wv] = s2;
  __syncthreads();
  float var = 0.f;
  for (int i = 0; i < 5; i++) var += red[i];
  var *= (1.f / DMODEL);
  float rs = rsqrtf(var + 1e-6f);
  ushort4 o4;
  o4.x = f2bf(dx * rs * s[d] + b[d]);
  o4.y = f2bf(dy * rs * s[d + 1] + b[d + 1]);
  o4.z = f2bf(dz * rs * s[d + 2] + b[d + 2]);
  o4.w = f2bf(dw * rs * s[d + 3] + b[d + 3]);
  *(ushort4*)(h + base) = o4;
}

// ---------------------------------------------------------------------------
// Weight convert+transpose: in fp32 [K][N] -> out bf16 [N][K]. 32x32 tiles.
// ---------------------------------------------------------------------------
__global__ void wconv_k(const float* __restrict__ in, u16* __restrict__ out,
                        int K, int N) {
  __shared__ float tl[32][33];
  int n0 = blockIdx.x * 32, k0 = blockIdx.y * 32;
  int t = threadIdx.x;
  int r = t >> 5, c = t & 31;
#pragma unroll
  for (int i = 0; i < 4; i++)
    tl[r + 8 * i][c] = in[(long long)(k0 + r + 8 * i) * N + n0 + c];
  __syncthreads();
  int n = t >> 4, kp = (t & 15) * 2;
#pragma unroll
  for (int i = 0; i < 2; i++) {
    ushort2 o;
    o.x = f2bf(tl[kp][n + 16 * i]);
    o.y = f2bf(tl[kp + 1][n + 16 * i]);
    *(ushort2*)&out[(long long)(n0 + n + 16 * i) * K + k0 + kp] = o;
  }
}

// fp32 -> bf16 flat copy
__global__ void conv_k(const float* __restrict__ in, u16* __restrict__ out,
                       long long n) {
  long long i = ((long long)blockIdx.x * 256 + threadIdx.x) * 4;
  if (i >= n) return;
  float4 v = *(const float4*)(in + i);
  ushort4 o; o.x = f2bf(v.x); o.y = f2bf(v.y); o.z = f2bf(v.z); o.w = f2bf(v.w);
  *(ushort4*)&out[i] = o;
}

// V transpose per batch: in bf16 [b][512][128] -> out bf16 [b][128][512]
union U16x8 { uint4 v; u16 s[8]; };
__global__ void vtr_k(const u16* __restrict__ in, u16* __restrict__ out) {
  __shared__ u16 tl[64][65];
  int b = blockIdx.z;
  int m0 = blockIdx.x * 64;
  int d0 = blockIdx.y * 64;
  const u16* ib = in + (long long)b * SEG * 128;
  u16* ob = out + (long long)b * 128 * SEG;
  int t = threadIdx.x;
  int r = t >> 3, c8 = (t & 7) * 8;
#pragma unroll
  for (int i = 0; i < 2; i++) {
    U16x8 ld;
    ld.v = *(const uint4*)&ib[(long long)(m0 + r + 32 * i) * 128 + d0 + c8];
#pragma unroll
    for (int j = 0; j < 8; j++) tl[r + 32 * i][c8 + j] = ld.s[j];
  }
  __syncthreads();
  int d = t >> 3, m8 = (t & 7) * 8;
#pragma unroll
  for (int i = 0; i < 2; i++) {
    int dd = d + 32 * i;
    U16x8 st;
#pragma unroll
    for (int j = 0; j < 8; j++) st.s[j] = tl[m8 + j][dd];
    *(uint4*)&ob[(long long)(d0 + dd) * SEG + m0 + m8] = st.v;
  }
}

// ---------------------------------------------------------------------------
__global__ void coords_k(const int* __restrict__ g, int nimg,
                         int* __restrict__ rw, int* __restrict__ cl,
                         int* __restrict__ hh, int* __restrict__ ww, int N) {
  int t = blockIdx.x * 256 + threadIdx.x;
  if (t >= N) return;
  int c = 0, local = 0, H = 1, W = 1;
  for (int i = 0; i < nimg; i++) {
    int tpi = g[i * 3] * g[i * 3 + 1] * g[i * 3 + 2];
    if (t >= c && t < c + tpi) { local = t - c; H = g[i * 3 + 1]; W = g[i * 3 + 2]; }
    c += tpi;
  }
  int hw = H * W;
  int sp = local % hw;
  int mw = W >> 1;
  int gr = sp >> 2, intra = sp & 3;
  rw[t] = (gr / mw) * 2 + (intra >> 1);
  cl[t] = (gr % mw) * 2 + (intra & 1);
  hh[t] = H; ww[t] = W;
}

__global__ void peadd_k(float* __restrict__ x, const float* __restrict__ pe,
                        const int* __restrict__ rw, const int* __restrict__ cl,
                        const int* __restrict__ hh, const int* __restrict__ ww) {
  int n = blockIdx.x;
  int d = threadIdx.x * 4;
  int H = hh[n], W = ww[n];
  float rf = (H > 1) ? (float)rw[n] * (float)(GPOS - 1) / (float)(H - 1) : 0.f;
  float cf = (W > 1) ? (float)cl[n] * (float)(GPOS - 1) / (float)(W - 1) : 0.f;
  int r0 = (int)floorf(rf), c0 = (int)floorf(cf);
  int r1 = min(r0 + 1, GPOS - 1), c1 = min(c0 + 1, GPOS - 1);
  float wr = rf - (float)r0, wc = cf - (float)c0;
  float w00 = (1.f - wr) * (1.f - wc), w01 = (1.f - wr) * wc;
  float w10 = wr * (1.f - wc), w11 = wr * wc;
  float4 v00 = *(const float4*)(pe + (long long)(r0 * GPOS + c0) * DMODEL + d);
  float4 v01 = *(const float4*)(pe + (long long)(r0 * GPOS + c1) * DMODEL + d);
  float4 v10 = *(const float4*)(pe + (long long)(r1 * GPOS + c0) * DMODEL + d);
  float4 v11 = *(const float4*)(pe + (long long)(r1 * GPOS + c1) * DMODEL + d);
  float4 xv = *(float4*)(x + (long long)n * DMODEL + d);
  xv.x += w00 * v00.x + w01 * v01.x + w10 * v10.x + w11 * v11.x;
  xv.y += w00 * v00.y + w01 * v01.y + w10 * v10.y + w11 * v11.y;
  xv.z += w00 * v00.z + w01 * v01.z + w10 * v10.z + w11 * v11.z;
  xv.w += w00 * v00.w + w01 * v01.w + w10 * v10.w + w11 * v11.w;
  *(float4*)(x + (long long)n * DMODEL + d) = xv;
}

// LayerNorm fp32 in -> bf16 out (one 320-thread block per row of 1280)
__global__ void ln_k(const float* __restrict__ X, u16* __restrict__ Y,
                     const float* __restrict__ s, const float* __restrict__ b) {
  int row = blockIdx.x;
  int d = threadIdx.x * 4;
  const float* x = X + (long long)row * DMODEL;
  float4 v = *(const float4*)(x + d);
  float sum = v.x + v.y + v.z + v.w;
#pragma unroll
  for (int o = 32; o; o >>= 1) sum += __shfl_xor(sum, o);
  __shared__ float red[8];
  int wv = threadIdx.x >> 6, lnn = threadIdx.x & 63;
  if (lnn == 0) red[wv] = sum;
  __syncthreads();
  float mu = 0.f;
  for (int i = 0; i < 5; i++) mu += red[i];
  mu *= (1.f / DMODEL);
  float dx = v.x - mu, dy = v.y - mu, dz = v.z - mu, dw = v.w - mu;
  float s2 = dx * dx + dy * dy + dz * dz + dw * dw;
#pragma unroll
  for (int o = 32; o; o >>= 1) s2 += __shfl_xor(s2, o);
  __syncthreads();
  if (lnn == 0) red[wv] = s2;
  __syncthreads();
  float var = 0.f;
  for (int i = 0; i < 5; i++) var += red[i];
  var *= (1.f / DMODEL);
  float rs = rsqrtf(var + 1e-6f);
  ushort4 o4;
  o4.x = f2bf(dx * rs * s[d] + b[d]);
  o4.y = f2bf(dy * rs * s[d + 1] + b[d + 1]);
  o4.z = f2bf(dz * rs * s[d + 2] + b[d + 2]);
  o4.w = f2bf(dw * rs * s[d + 3] + b[d + 3]);
  *(ushort4*)(Y + (long long)row * DMODEL + d) = o4;
}

// RoPE from bf16 qkv -> qr/kr bf16 [h][N][96] (zero pad), v -> vp [h][N][128]
// 256-thread blocks, 4 tokens per block (same per-token code as before).
__global__ void rope_k(const u16* __restrict__ qkv, const int* __restrict__ rw,
                       const int* __restrict__ cl, u16* __restrict__ qr,
                       u16* __restrict__ kr, u16* __restrict__ vp, int N) {
  int n = blockIdx.x * 4 + (threadIdx.x >> 6), h = blockIdx.y;
  int t = threadIdx.x & 63;
  const u16* src = qkv + (long long)n * (3 * DMODEL) + h * 80;
  long long ob96 = ((long long)h * N + n) * 96;
  long long ob128 = ((long long)h * N + n) * 128;
  if (t < 40) {
    float pos = (t < 20) ? (float)rw[n] : (float)cl[n];
    float infr = exp2f(-13.287712379549449f * (float)(t % 20) * 0.05f);
    float f = pos * infr;
    float cs = cosf(f), sn = sinf(f);
    float q0 = bf2f(src[t]), q1 = bf2f(src[t + 40]);
    qr[ob96 + t] = f2bf(q0 * cs - q1 * sn);
    qr[ob96 + t + 40] = f2bf(q1 * cs + q0 * sn);
    float k0 = bf2f(src[DMODEL + t]), k1 = bf2f(src[DMODEL + t + 40]);
    kr[ob96 + t] = f2bf(k0 * cs - k1 * sn);
    kr[ob96 + t + 40] = f2bf(k1 * cs + k0 * sn);
    vp[ob128 + t] = src[2 * DMODEL + t];
    vp[ob128 + t + 40] = src[2 * DMODEL + t + 40];
  } else {
    int u = t - 40;
    if (u < 16) { qr[ob96 + 80 + u] = 0; kr[ob96 + 80 + u] = 0; }
    vp[ob128 + 80 + u] = 0;
    vp[ob128 + 104 + u] = 0;
  }
}

// ---------------------------------------------------------------------------
// 128x128-tile path: M%128==0, Nn%128==0, (Kd/nsplit)%32==0.
static void gemm_big(hipStream_t st, int epi, const u16* A, const u16* B,
                     const float* bias, void* C, int M, int Nn, int Kd,
                     int lda, int ldb, int ldc, int nsplit) {
  dim3 g(M / 128, Nn / 128, nsplit), blk(256);
  long long ps = (long long)M * Nn;
  switch (epi) {
    case 0: gemm128<0><<<g, blk, 0, st>>>(A, B, bias, C, Kd, lda, ldb, ldc, nsplit, ps); break;
    case 1: gemm128<1><<<g, blk, 0, st>>>(A, B, bias, C, Kd, lda, ldb, ldc, nsplit, ps); break;
    default: gemm128<3><<<g, blk, 0, st>>>(A, B, bias, C, Kd, lda, ldb, ldc, nsplit, ps); break;
  }
}

extern "C" void kernel_launch(void* const* d_in, const int* in_sizes, int n_in,
                              void* d_out, int out_size, void* d_ws, size_t ws_size,
                              hipStream_t stream) {
  const float* pixels = (const float*)d_in[0];
  const int* grid_thw = (const int*)d_in[1];
  const float* pos_embed = (const float*)d_in[2];
  const float* patch_w = (const float*)d_in[3];
  const float* patch_b = (const float*)d_in[4];
  const float* ln1_s = (const float*)d_in[5];
  const float* ln1_b = (const float*)d_in[6];
  const float* qkv_w = (const float*)d_in[7];
  const float* qkv_b = (const float*)d_in[8];
  const float* proj_w = (const float*)d_in[9];
  const float* proj_b = (const float*)d_in[10];
  const float* ln2_s = (const float*)d_in[11];
  const float* ln2_b = (const float*)d_in[12];
  const float* fc1_w = (const float*)d_in[13];
  const float* fc1_b = (const float*)d_in[14];
  const float* fc2_w = (const float*)d_in[15];
  const float* fc2_b = (const float*)d_in[16];
  const float* mns = (const float*)d_in[17];
  const float* mnb = (const float*)d_in[18];
  const float* mf1w = (const float*)d_in[19];
  const float* mf1b = (const float*)d_in[20];
  const float* mf2w = (const float*)d_in[21];
  const float* mf2b = (const float*)d_in[22];
  float* out = (float*)d_out;

  const int N = in_sizes[0] / 1536;  // 2048
  const int nimg = in_sizes[1] / 3;  // 4
  const int nseg = N / SEG;          // 4
  const int nb = NHEADS * nseg;      // 64

  char* w = (char*)d_ws;
  size_t off = 0;
  auto alloc = [&](size_t bytes) -> void* {
    void* p = w + off;
    off += (bytes + 255) & ~(size_t)255;
    return p;
  };
  int* rw = (int*)alloc((size_t)N * 4);
  int* cl = (int*)alloc((size_t)N * 4);
  int* hh = (int*)alloc((size_t)N * 4);
  int* ww = (int*)alloc((size_t)N * 4);
  float* x = (float*)alloc((size_t)N * DMODEL * 4);
  u16* h = (u16*)alloc((size_t)N * DMODEL * 2);
  u16* pixbf = (u16*)alloc((size_t)N * 1536 * 2);      // mfc2T overlay base
  u16* patchT = (u16*)alloc((size_t)DMODEL * 1536 * 2);
  u16* qkvT = (u16*)alloc((size_t)3 * DMODEL * DMODEL * 2);
  u16* projT = (u16*)alloc((size_t)DMODEL * DMODEL * 2);
  u16* fc1T = (u16*)alloc((size_t)FDIM * DMODEL * 2);
  u16* fc2T = (u16*)alloc((size_t)DMODEL * FDIM * 2);
  u16* qkvb = (u16*)alloc((size_t)N * 3 * DMODEL * 2);  // mfc1T overlay base
  u16* qr = (u16*)alloc((size_t)NHEADS * N * 96 * 2);
  u16* kr = (u16*)alloc((size_t)NHEADS * N * 96 * 2);
  u16* vp = (u16*)alloc((size_t)NHEADS * N * 128 * 2);
  u16* vpT = (u16*)alloc((size_t)NHEADS * N * 128 * 2);
  u16* pad0 = (u16*)alloc((size_t)nb * 2 * SEG * 128 * 2);  // keeps mfc1T overlay in bounds
  u16* o = (u16*)alloc((size_t)N * DMODEL * 2);
  float* bigA = (float*)alloc((size_t)nb * SEG * SEG * 4);  // ffb / mf
  float* bigB = (float*)alloc((size_t)nb * SEG * SEG * 2);  // split-K partials
  (void)ws_size; (void)pad0;
  // overlays (lifetimes disjoint with originals)
  u16* mfc1T = qkvb;         // 52.4 MB over qkvb..pad0 region
  u16* mfc2T = pixbf;        // 21.0 MB over pixbf..projT
  u16* ffb = (u16*)bigA;     // fc1 out, 21 MB at bigA base
  u16* mf = (u16*)bigA;      // merger hidden 5.2 MB at bigA base
  u16* part = (u16*)bigB;    // split-K bf16 partial planes (<= 33.5 MB)

  const float iscale = 0.11180339887498949f;  // 80^-0.5
  const long long mnD = (long long)N * DMODEL;

  coords_k<<<dim3((N + 255) / 256), 256, 0, stream>>>(grid_thw, nimg, rw, cl, hh, ww, N);
  conv_k<<<dim3((int)(((long long)N * 1536 / 4 + 255) / 256)), 256, 0, stream>>>(
      pixels, pixbf, (long long)N * 1536);
  wconv_k<<<dim3(DMODEL / 32, 1536 / 32), 256, 0, stream>>>(patch_w, patchT, 1536, DMODEL);
  // patch embed, split-K=4 (640 blocks)
  gemm_big(stream, 0, pixbf, patchT, nullptr, part, N, DMODEL, 1536, 1536, 1536,
           DMODEL, 4);
  reduce_k<4, 0, 0, 0><<<dim3((int)((mnD / 4 + 255) / 256)), 256, 0, stream>>>(
      part, mnD, DMODEL, patch_b, nullptr, x);
  peadd_k<<<dim3(N), 320, 0, stream>>>(x, pos_embed, rw, cl, hh, ww);
  // ln1 of layer 0 (subsequent LNs fused into split-K reduces)
  ln_k<<<dim3(N), 320, 0, stream>>>(x, h, ln1_s, ln1_b);

  for (int l = 0; l < 4; l++) {
    wconv_k<<<dim3(3 * DMODEL / 32, DMODEL / 32), 256, 0, stream>>>(
        qkv_w + (size_t)l * DMODEL * 3 * DMODEL, qkvT, DMODEL, 3 * DMODEL);
    wconv_k<<<dim3(DMODEL / 32, DMODEL / 32), 256, 0, stream>>>(
        proj_w + (size_t)l * DMODEL * DMODEL, projT, DMODEL, DMODEL);
    wconv_k<<<dim3(FDIM / 32, DMODEL / 32), 256, 0, stream>>>(
        fc1_w + (size_t)l * DMODEL * FDIM, fc1T, DMODEL, FDIM);
    wconv_k<<<dim3(DMODEL / 32, FDIM / 32), 256, 0, stream>>>(
        fc2_w + (size_t)l * FDIM * DMODEL, fc2T, FDIM, DMODEL);

    // qkv direct +bias (480 blocks, NT=40)
    gemm_big(stream, 1, h, qkvT, qkv_b + (size_t)l * 3 * DMODEL, qkvb, N,
             3 * DMODEL, DMODEL, DMODEL, DMODEL, 3 * DMODEL, 1);
    rope_k<<<dim3(N / 4, NHEADS), 256, 0, stream>>>(qkvb, rw, cl, qr, kr, vp, N);
    vtr_k<<<dim3(8, 2, nb), 256, 0, stream>>>(vp, vpT);
    // fused flash attention -> o (256 blocks x 512 thr, 2 waves/SIMD)
    fattn_k<<<dim3(SEG / 128, nb), 512, 0, stream>>>(qr, kr, vpT, o, N, iscale);
    // proj split-K=4 (640 blocks); fused reduce + bias + residual + ln2 -> h
    gemm_big(stream, 0, o, projT, nullptr, part, N, DMODEL, DMODEL, DMODEL,
             DMODEL, DMODEL, 4);
    redln_k<4><<<dim3(N), 320, 0, stream>>>(part, mnD, proj_b + (size_t)l * DMODEL,
                                            x, ln2_s + (size_t)l * DMODEL,
                                            ln2_b + (size_t)l * DMODEL, h);
    // fc1 fused bias+gelu -> bf16 (640 blocks, direct)
    gemm_big(stream, 3, h, fc1T, fc1_b + (size_t)l * FDIM, ffb, N, FDIM, DMODEL,
             DMODEL, DMODEL, FDIM, 1);
    // fc2 split-K=4 (640 blocks); fused reduce + bias + residual + next LN -> h
    gemm_big(stream, 0, ffb, fc2T, nullptr, part, N, DMODEL, FDIM, FDIM, FDIM,
             DMODEL, 4);
    const float* nsl = (l < 3) ? ln1_s + (size_t)(l + 1) * DMODEL : mns;
    const float* nbl = (l < 3) ? ln1_b + (size_t)(l + 1) * DMODEL : mnb;
    redln_k<4><<<dim3(N), 320, 0, stream>>>(part, mnD, fc2_b + (size_t)l * DMODEL,
                                            x, nsl, nbl, h);
  }

  // merger (h already = LN(x; mns,mnb), viewed as [512][5120])
  const int Mm = N / 4;  // 512
  wconv_k<<<dim3(FDIM / 32, FDIM / 32), 256, 0, stream>>>(mf1w, mfc1T, FDIM, FDIM);
  // mfc1 split-K=4 (640 blocks); reduce + bias + gelu -> mf
  gemm_big(stream, 0, h, mfc1T, nullptr, part, Mm, FDIM, FDIM, FDIM, FDIM, FDIM, 4);
  reduce_k<4, 0, 1, 1><<<dim3((int)(((long long)Mm * FDIM / 4 + 255) / 256)), 256, 0, stream>>>(
      part, (long long)Mm * FDIM, FDIM, mf1b, nullptr, mf);
  wconv_k<<<dim3(2048 / 32, FDIM / 32), 256, 0, stream>>>(mf2w, mfc2T, FDIM, 2048);
  // mfc2 split-K=16 (1024 blocks)
  gemm_big(stream, 0, mf, mfc2T, nullptr, part, Mm, 2048, FDIM, FDIM, FDIM, 2048, 16);
  reduce_k<16, 0, 0, 0><<<dim3((int)(((long long)Mm * 2048 / 4 + 255) / 256)), 256, 0, stream>>>(
      part, (long long)Mm * 2048, 2048, mf2b, nullptr, out);
}

// Round 10
// 1310.519 us; speedup vs baseline: 1.1580x; 1.0030x over previous
//
#include <hip/hip_runtime.h>
#include <math.h>

#define DMODEL 1280
#define NHEADS 16
#define FDIM   5120
#define GPOS   48
#define SEG    512

typedef __attribute__((ext_vector_type(8))) short bf16x8;
typedef __attribute__((ext_vector_type(4))) float f32x4;
typedef unsigned short u16;

__device__ __forceinline__ u16 f2bf(float f) {
  unsigned int u = __float_as_uint(f);
  u = (u + 0x7FFFu + ((u >> 16) & 1u)) >> 16;  // RNE
  return (u16)u;
}
__device__ __forceinline__ float bf2f(u16 u) {
  return __uint_as_float((unsigned int)u << 16);
}
__device__ __forceinline__ float gelu_tanh(float x) {
  float u = 0.7978845608028654f * (x + 0.044715f * x * x * x);
  float t = __expf(2.f * u);
  float th = 1.f - 2.f / (t + 1.f);
  return 0.5f * x * (1.f + th);
}

typedef const __attribute__((address_space(1))) unsigned int* gas_t;
typedef __attribute__((address_space(3))) unsigned int* las_t;
__device__ __forceinline__ void async16(const void* g, void* l) {
  __builtin_amdgcn_global_load_lds((gas_t)g, (las_t)l, 16, 0, 0);
}

// Bijective XCD chunk remap (T1, m204 form).
__device__ __forceinline__ int xcd_remap(int b, int nwg) {
  int q = nwg >> 3, r = nwg & 7, x = b & 7, d = b >> 3;
  return (x < r ? x * (q + 1) : r * (q + 1) + (x - r) * q) + d;
}

// ---------------------------------------------------------------------------
// gemm128 (R8-verified): 128x128 tile, BK=32, 4 waves, 32 KiB dbuf LDS,
// 3 blocks/CU, R2 subtile swizzle, T1 remap, 2 phases/tile, depth-1
// prefetch, per-element accumulation order fixed (k0,k32,...).
// A:[M][K] bf16, B:[N][K] bf16, C = A.B^T.
// EPI 0: bf16 partial planes (split-K). EPI 1: +bias bf16. EPI 3: +bias+gelu.
// ---------------------------------------------------------------------------
#define STG1(mat, PW, ldx, rb, kk, pp)                                      \
  async16((PW) + (long long)(rb) * 16 * (ldx) + (kk),                       \
          &L[pp][mat][(rb) * 512])

#define BARX() asm volatile("s_barrier" ::: "memory")
#define LGKM0() asm volatile("s_waitcnt lgkmcnt(0)" ::: "memory")

template <int EPI>
__global__ __launch_bounds__(256, 3) void gemm128(
    const u16* __restrict__ A, const u16* __restrict__ B,
    const float* __restrict__ bias, void* __restrict__ Cv,
    int Kd, int lda, int ldb, int ldc, int nsplit, long long pstride) {
  __shared__ __align__(16) u16 L[2][2][4096];  // [buf][A|B][8rb x 512]
  const int sp = blockIdx.z;
  const int Ks = Kd / nsplit;
  const int NT = Ks >> 5;
  const u16* Ab = A + (long long)sp * Ks;
  const u16* Bb = B + (long long)sp * Ks;
  const int gx = gridDim.x;
  const int lg = xcd_remap(blockIdx.x + gx * blockIdx.y, gx * gridDim.y);
  const int m0 = (lg % gx) * 128, n0 = (lg / gx) * 128;
  const int t = threadIdx.x, ln = t & 63, w = t >> 6;
  const int wr = w >> 1, wc = w & 1;
  const int m16 = ln & 15, q = ln >> 4;
  const int r16 = ln >> 2;
  const int csw = (ln & 3) ^ ((ln >> 5) << 1);               // R2 source swz
  const int rbase = m16 * 32 + (q ^ ((m16 >> 3) << 1)) * 8;  // R2 read swz

  const u16* Aw = Ab + (long long)(m0 + r16) * lda + csw * 8;
  const u16* Bw = Bb + (long long)(n0 + r16) * ldb + csw * 8;
  const int w4 = w + 4;

  f32x4 acc[4][4];
#pragma unroll
  for (int i = 0; i < 4; i++)
#pragma unroll
    for (int j = 0; j < 4; j++)
#pragma unroll
      for (int r = 0; r < 4; r++) acc[i][j][r] = 0.f;

  // prologue: tile0 (4 loads/wave) + tile1 (4); vmcnt(4) -> tile0 landed.
  STG1(0, Aw, lda, w, 0, 0);  STG1(0, Aw, lda, w4, 0, 0);
  STG1(1, Bw, ldb, w, 0, 0);  STG1(1, Bw, ldb, w4, 0, 0);
  if (NT > 1) {
    STG1(0, Aw, lda, w, 32, 1);  STG1(0, Aw, lda, w4, 32, 1);
    STG1(1, Bw, ldb, w, 32, 1);  STG1(1, Bw, ldb, w4, 32, 1);
    asm volatile("s_waitcnt vmcnt(4)" ::: "memory");
  } else {
    asm volatile("s_waitcnt vmcnt(0)" ::: "memory");
  }
  BARX();

  for (int tt = 0; tt < NT; ++tt) {
    const int p = tt & 1;
    const u16* Abuf = &L[p][0][0];
    const u16* Bbuf = &L[p][1][0];
    bf16x8 aR[4], bR[4];

    // ph1: ds all aR (4) + bR[0..1] (2); stage A(t+1) -> buf p^1
#pragma unroll
    for (int i = 0; i < 4; ++i)
      aR[i] = *(const bf16x8*)(Abuf + (wr * 4 + i) * 512 + rbase);
    bR[0] = *(const bf16x8*)(Bbuf + (wc * 4 + 0) * 512 + rbase);
    bR[1] = *(const bf16x8*)(Bbuf + (wc * 4 + 1) * 512 + rbase);
    if (tt + 1 < NT) {
      STG1(0, Aw, lda, w, (tt + 1) * 32, p ^ 1);
      STG1(0, Aw, lda, w4, (tt + 1) * 32, p ^ 1);
    }
    BARX();
    LGKM0();
    __builtin_amdgcn_s_setprio(1);
#pragma unroll
    for (int i = 0; i < 4; ++i) {
      acc[i][0] = __builtin_amdgcn_mfma_f32_16x16x32_bf16(aR[i], bR[0], acc[i][0], 0, 0, 0);
      acc[i][1] = __builtin_amdgcn_mfma_f32_16x16x32_bf16(aR[i], bR[1], acc[i][1], 0, 0, 0);
    }
    __builtin_amdgcn_s_setprio(0);
    BARX();

    // ph2: ds bR[2..3] (2); stage B(t+1) -> buf p^1; tile-end drain
    bR[2] = *(const bf16x8*)(Bbuf + (wc * 4 + 2) * 512 + rbase);
    bR[3] = *(const bf16x8*)(Bbuf + (wc * 4 + 3) * 512 + rbase);
    if (tt + 1 < NT) {
      STG1(1, Bw, ldb, w, (tt + 1) * 32, p ^ 1);
      STG1(1, Bw, ldb, w4, (tt + 1) * 32, p ^ 1);
    }
    BARX();
    LGKM0();
    __builtin_amdgcn_s_setprio(1);
#pragma unroll
    for (int i = 0; i < 4; ++i) {
      acc[i][2] = __builtin_amdgcn_mfma_f32_16x16x32_bf16(aR[i], bR[2], acc[i][2], 0, 0, 0);
      acc[i][3] = __builtin_amdgcn_mfma_f32_16x16x32_bf16(aR[i], bR[3], acc[i][3], 0, 0, 0);
    }
    __builtin_amdgcn_s_setprio(0);
    if (tt + 1 < NT) asm volatile("s_waitcnt vmcnt(0)" ::: "memory");
    BARX();
  }

#pragma unroll
  for (int fr = 0; fr < 4; fr++) {
#pragma unroll
    for (int r = 0; r < 4; r++) {
      int row = m0 + wr * 64 + fr * 16 + q * 4 + r;
      if (EPI == 0) {
        u16* Cp = (u16*)Cv + (long long)sp * pstride + (long long)row * ldc;
#pragma unroll
        for (int fc = 0; fc < 4; fc++)
          Cp[n0 + wc * 64 + fc * 16 + m16] = f2bf(acc[fr][fc][r]);
      } else if (EPI == 1) {
        u16* Cb = (u16*)Cv + (long long)row * ldc;
#pragma unroll
        for (int fc = 0; fc < 4; fc++) {
          int col = n0 + wc * 64 + fc * 16 + m16;
          Cb[col] = f2bf(acc[fr][fc][r] + bias[col]);
        }
      } else {  // EPI == 3
        u16* Cb = (u16*)Cv + (long long)row * ldc;
#pragma unroll
        for (int fc = 0; fc < 4; fc++) {
          int col = n0 + wc * 64 + fc * 16 + m16;
          Cb[col] = f2bf(gelu_tanh(acc[fr][fc][r] + bias[col]));
        }
      }
    }
  }
}

// ---------------------------------------------------------------------------
// Fused flash attention (R9-verified 8-wave form, T1-chunked).
// Grid: (SEG/128, NHEADS*nseg), 512 threads.
// ---------------------------------------------------------------------------
__global__ __launch_bounds__(512) void fattn_k(
    const u16* __restrict__ qr, const u16* __restrict__ kr,
    const u16* __restrict__ vpT, u16* __restrict__ o, int N, float iscale) {
  __shared__ __align__(16) u16 Ks[2][24][512];   // [buf][f*3+kg][16kv x 32hd]
  __shared__ __align__(16) u16 Vs[2][20][512];   // [buf][df*4+kvg][16d x 32kv]
  __shared__ __align__(16) u16 Ps[8][16 * 128];  // per-wave P panel (16 rows)
  const int nseg = N >> 9;
  const int gx = gridDim.x;
  const int lg = xcd_remap(blockIdx.x + gx * blockIdx.y, gx * gridDim.y);
  const int strip = lg % gx, hb = lg / gx;
  const int h = hb / nseg, seg = hb - h * nseg;
  const int t = threadIdx.x, ln = t & 63, w = t >> 6;  // w in [0,8)
  const int m16 = ln & 15, qh = ln >> 4;
  const int r4 = ln >> 2, gsw = (ln & 3) ^ ((ln >> 5) << 1);
  const int rbase = m16 * 32 + ((qh ^ ((m16 >> 3) << 1)) << 3);
  const long long hN = (long long)h * N;
  const int segbase = seg * SEG;
  const int q0 = segbase + strip * 128 + w * 16;  // 8 waves x 16 rows

  bf16x8 qf[3];
#pragma unroll
  for (int ks = 0; ks < 3; ks++)
    qf[ks] = *(const bf16x8*)&qr[(hN + q0 + m16) * 96 + ks * 32 + qh * 8];

  f32x4 ao[5];
#pragma unroll
  for (int df = 0; df < 5; df++)
#pragma unroll
    for (int r = 0; r < 4; r++) ao[df][r] = 0.f;
  float m_[4], l_[4];
#pragma unroll
  for (int r = 0; r < 4; r++) { m_[r] = -1e30f; l_[r] = 0.f; }

  auto stage = [&](int c, int pb) {
#pragma unroll
    for (int i = 0; i < 3; i++) {  // 24 K subtiles over 8 waves
      int sK = w * 3 + i, f = sK / 3, kg = sK - f * 3;
      async16(&kr[(hN + segbase + c * 128 + f * 16 + r4) * 96 + kg * 32 + gsw * 8],
              &Ks[pb][sK][0]);
    }
#pragma unroll
    for (int i = 0; i < 2; i++) {  // 16 of 20 V subtiles
      int sV = w * 2 + i, df = sV >> 2, kvg = sV & 3;
      async16(&vpT[((long long)hb * 128 + df * 16 + r4) * SEG + c * 128 + kvg * 32 + gsw * 8],
              &Vs[pb][sV][0]);
    }
    if (w < 4) {  // remaining 4 V subtiles
      int sV = 16 + w, df = sV >> 2, kvg = sV & 3;
      async16(&vpT[((long long)hb * 128 + df * 16 + r4) * SEG + c * 128 + kvg * 32 + gsw * 8],
              &Vs[pb][sV][0]);
    }
  };

  stage(0, 0);
  u16* Pmy = &Ps[w][0];
  for (int c = 0; c < 4; c++) {
    const int pb = c & 1;
    __syncthreads();  // implicit vmcnt(0)+lgkmcnt(0): buf[pb] staged by all waves
    if (c < 3) stage(c + 1, pb ^ 1);

    // QK^T: s[f] rows q=qh*4+r, cols kv=f*16+m16
    f32x4 s[8];
#pragma unroll
    for (int f = 0; f < 8; f++)
#pragma unroll
      for (int r = 0; r < 4; r++) s[f][r] = 0.f;
#pragma unroll
    for (int ks = 0; ks < 3; ks++) {
#pragma unroll
      for (int f = 0; f < 8; f++) {
        bf16x8 kf = *(const bf16x8*)&Ks[pb][f * 3 + ks][rbase];
        s[f] = __builtin_amdgcn_mfma_f32_16x16x32_bf16(qf[ks], kf, s[f], 0, 0, 0);
      }
    }

    // online softmax per row
#pragma unroll
    for (int r = 0; r < 4; r++) {
      float mx = s[0][r];
#pragma unroll
      for (int f = 1; f < 8; f++) mx = fmaxf(mx, s[f][r]);
      mx *= iscale;
#pragma unroll
      for (int o2 = 1; o2 <= 8; o2 <<= 1) mx = fmaxf(mx, __shfl_xor(mx, o2));
      float mn = fmaxf(m_[r], mx);
      float corr = __expf(m_[r] - mn);
      m_[r] = mn;
      float rs = 0.f;
#pragma unroll
      for (int f = 0; f < 8; f++) {
        float p = __expf(s[f][r] * iscale - mn);
        s[f][r] = p;
        rs += p;
      }
#pragma unroll
      for (int o2 = 1; o2 <= 8; o2 <<= 1) rs += __shfl_xor(rs, o2);
      l_[r] = l_[r] * corr + rs;
#pragma unroll
      for (int df = 0; df < 5; df++) ao[df][r] *= corr;
    }

    // P -> LDS (per-wave private): addr(q,kv)=q*128 + ((kv>>3)^(q&7))*8 + (kv&7)
#pragma unroll
    for (int r = 0; r < 4; r++) {
      int qq = qh * 4 + r;  // 0..15
      int base = qq * 128 + (m16 & 7);
      int ql = qq & 7;
#pragma unroll
      for (int f = 0; f < 8; f++) {
        int gr = (f * 2 + (m16 >> 3)) ^ ql;
        Pmy[base + gr * 8] = f2bf(s[f][r]);
      }
    }

    // PV: O[q][d] += P[q][kv] V^T[d][kv]
#pragma unroll
    for (int ks = 0; ks < 4; ks++) {
      bf16x8 pf = *(const bf16x8*)&Pmy[m16 * 128 +
                                       (((ks * 4 + qh) ^ (m16 & 7)) << 3)];
#pragma unroll
      for (int df = 0; df < 5; df++) {
        bf16x8 vf = *(const bf16x8*)&Vs[pb][df * 4 + ks][rbase];
        ao[df] = __builtin_amdgcn_mfma_f32_16x16x32_bf16(pf, vf, ao[df], 0, 0, 0);
      }
    }
  }

#pragma unroll
  for (int r = 0; r < 4; r++) {
    float rl = 1.f / l_[r];
    long long rowb = (long long)(q0 + qh * 4 + r) * DMODEL + h * 80;
#pragma unroll
    for (int df = 0; df < 5; df++)
      o[rowb + df * 16 + m16] = f2bf(ao[df][r] * rl);
  }
}

// ---------------------------------------------------------------------------
// Split-K reduce + epilogue (bf16 partials): out = [gelu](sum + bias) [+ res]
// ---------------------------------------------------------------------------
template <int S, int RES, int GELU, int OUTBF>
__global__ void reduce_k(const u16* __restrict__ Pp, long long mn, int Nn,
                         const float* __restrict__ bias,
                         const float* __restrict__ res, void* __restrict__ out) {
  long long i = ((long long)blockIdx.x * 256 + threadIdx.x) * 4;
  if (i >= mn) return;
  float vx = 0.f, vy = 0.f, vz = 0.f, vw = 0.f;
#pragma unroll
  for (int s = 0; s < S; s++) {
    ushort4 u4 = *(const ushort4*)(Pp + (long long)s * mn + i);
    vx += bf2f(u4.x); vy += bf2f(u4.y); vz += bf2f(u4.z); vw += bf2f(u4.w);
  }
  int col = (int)(i % Nn);
  vx += bias[col]; vy += bias[col + 1]; vz += bias[col + 2]; vw += bias[col + 3];
  if (GELU) {
    vx = gelu_tanh(vx); vy = gelu_tanh(vy);
    vz = gelu_tanh(vz); vw = gelu_tanh(vw);
  }
  if (RES) {
    float4 r4 = *(const float4*)(res + i);
    vx += r4.x; vy += r4.y; vz += r4.z; vw += r4.w;
  }
  if (OUTBF) {
    ushort4 o; o.x = f2bf(vx); o.y = f2bf(vy); o.z = f2bf(vz); o.w = f2bf(vw);
    *(ushort4*)((u16*)out + i) = o;
  } else {
    float4 o; o.x = vx; o.y = vy; o.z = vz; o.w = vw;
    *(float4*)((float*)out + i) = o;
  }
}

// ---------------------------------------------------------------------------
// Fused split-K reduce + residual + LayerNorm: one 320-thread block per row.
// ---------------------------------------------------------------------------
template <int S>
__global__ void redln_k(const u16* __restrict__ Pp, long long mn,
                        const float* __restrict__ bias,
                        float* __restrict__ x,
                        const float* __restrict__ s, const float* __restrict__ b,
                        u16* __restrict__ h) {
  int row = blockIdx.x;
  int d = threadIdx.x * 4;
  long long base = (long long)row * DMODEL + d;
  float vx = 0.f, vy = 0.f, vz = 0.f, vw = 0.f;
#pragma unroll
  for (int si = 0; si < S; si++) {
    ushort4 u4 = *(const ushort4*)(Pp + (long long)si * mn + base);
    vx += bf2f(u4.x); vy += bf2f(u4.y); vz += bf2f(u4.z); vw += bf2f(u4.w);
  }
  vx += bias[d]; vy += bias[d + 1]; vz += bias[d + 2]; vw += bias[d + 3];
  float4 r4 = *(const float4*)(x + base);
  vx += r4.x; vy += r4.y; vz += r4.z; vw += r4.w;
  float4 xv; xv.x = vx; xv.y = vy; xv.z = vz; xv.w = vw;
  *(float4*)(x + base) = xv;
  float sum = vx + vy + vz + vw;
#pragma unroll
  for (int o = 32; o; o >>= 1) sum += __shfl_xor(sum, o);
  __shared__ float red[8];
  int wv = threadIdx.x >> 6, lnn = threadIdx.x & 63;
  if (lnn == 0) red[wv] = sum;
  __syncthreads();
  float mu = 0.f;
  for (int i = 0; i < 5; i++) mu += red[i];
  mu *= (1.f / DMODEL);
  float dx = vx - mu, dy = vy - mu, dz = vz - mu, dw = vw - mu;
  float s2 = dx * dx + dy * dy + dz * dz + dw * dw;
#pragma unroll
  for (int o = 32; o; o >>= 1) s2 += __shfl_xor(s2, o);
  __syncthreads();
  if (lnn == 0) red[wv] = s2;
  __syncthreads();
  float var = 0.f;
  for (int i = 0; i < 5; i++) var += red[i];
  var *= (1.f / DMODEL);
  float rs = rsqrtf(var + 1e-6f);
  ushort4 o4;
  o4.x = f2bf(dx * rs * s[d] + b[d]);
  o4.y = f2bf(dy * rs * s[d + 1] + b[d + 1]);
  o4.z = f2bf(dz * rs * s[d + 2] + b[d + 2]);
  o4.w = f2bf(dw * rs * s[d + 3] + b[d + 3]);
  *(ushort4*)(h + base) = o4;
}

// ---------------------------------------------------------------------------
// Weight convert+transpose v2: in fp32 [K][N] -> out bf16 [N][K].
// Tile 64k x 32n, 256 threads. Writes are 16B/lane ushort8 (8 lanes cover a
// 128B contiguous k-run of one output row) vs v1's 4B scattered ushort2 —
// the write path was ~4B/lane scatter and dominated. Per-element math
// identical (f2bf of the same element) -> bit-identical output.
// Grid: (N/32, K/64).
// ---------------------------------------------------------------------------
union U16x8 { uint4 v; u16 s[8]; };
__global__ void wconv_k(const float* __restrict__ in, u16* __restrict__ out,
                        int K, int N) {
  __shared__ float tl[64][33];
  int n0 = blockIdx.x * 32, k0 = blockIdx.y * 64;
  int t = threadIdx.x;
  int rr = t >> 5, c = t & 31;
#pragma unroll
  for (int i = 0; i < 8; i++)
    tl[rr + 8 * i][c] = in[(long long)(k0 + rr + 8 * i) * N + n0 + c];
  __syncthreads();
  int n = t >> 3, kq = (t & 7) * 8;
  U16x8 o;
#pragma unroll
  for (int j = 0; j < 8; j++) o.s[j] = f2bf(tl[kq + j][n]);
  *(uint4*)&out[(long long)(n0 + n) * K + k0 + kq] = o.v;
}

// fp32 -> bf16 flat copy
__global__ void conv_k(const float* __restrict__ in, u16* __restrict__ out,
                       long long n) {
  long long i = ((long long)blockIdx.x * 256 + threadIdx.x) * 4;
  if (i >= n) return;
  float4 v = *(const float4*)(in + i);
  ushort4 o; o.x = f2bf(v.x); o.y = f2bf(v.y); o.z = f2bf(v.z); o.w = f2bf(v.w);
  *(ushort4*)&out[i] = o;
}

// V transpose per batch: in bf16 [b][512][128] -> out bf16 [b][128][512]
__global__ void vtr_k(const u16* __restrict__ in, u16* __restrict__ out) {
  __shared__ u16 tl[64][65];
  int b = blockIdx.z;
  int m0 = blockIdx.x * 64;
  int d0 = blockIdx.y * 64;
  const u16* ib = in + (long long)b * SEG * 128;
  u16* ob = out + (long long)b * 128 * SEG;
  int t = threadIdx.x;
  int r = t >> 3, c8 = (t & 7) * 8;
#pragma unroll
  for (int i = 0; i < 2; i++) {
    U16x8 ld;
    ld.v = *(const uint4*)&ib[(long long)(m0 + r + 32 * i) * 128 + d0 + c8];
#pragma unroll
    for (int j = 0; j < 8; j++) tl[r + 32 * i][c8 + j] = ld.s[j];
  }
  __syncthreads();
  int d = t >> 3, m8 = (t & 7) * 8;
#pragma unroll
  for (int i = 0; i < 2; i++) {
    int dd = d + 32 * i;
    U16x8 st;
#pragma unroll
    for (int j = 0; j < 8; j++) st.s[j] = tl[m8 + j][dd];
    *(uint4*)&ob[(long long)(d0 + dd) * SEG + m0 + m8] = st.v;
  }
}

// ---------------------------------------------------------------------------
__global__ void coords_k(const int* __restrict__ g, int nimg,
                         int* __restrict__ rw, int* __restrict__ cl,
                         int* __restrict__ hh, int* __restrict__ ww, int N) {
  int t = blockIdx.x * 256 + threadIdx.x;
  if (t >= N) return;
  int c = 0, local = 0, H = 1, W = 1;
  for (int i = 0; i < nimg; i++) {
    int tpi = g[i * 3] * g[i * 3 + 1] * g[i * 3 + 2];
    if (t >= c && t < c + tpi) { local = t - c; H = g[i * 3 + 1]; W = g[i * 3 + 2]; }
    c += tpi;
  }
  int hw = H * W;
  int sp = local % hw;
  int mw = W >> 1;
  int gr = sp >> 2, intra = sp & 3;
  rw[t] = (gr / mw) * 2 + (intra >> 1);
  cl[t] = (gr % mw) * 2 + (intra & 1);
  hh[t] = H; ww[t] = W;
}

__global__ void peadd_k(float* __restrict__ x, const float* __restrict__ pe,
                        const int* __restrict__ rw, const int* __restrict__ cl,
                        const int* __restrict__ hh, const int* __restrict__ ww) {
  int n = blockIdx.x;
  int d = threadIdx.x * 4;
  int H = hh[n], W = ww[n];
  float rf = (H > 1) ? (float)rw[n] * (float)(GPOS - 1) / (float)(H - 1) : 0.f;
  float cf = (W > 1) ? (float)cl[n] * (float)(GPOS - 1) / (float)(W - 1) : 0.f;
  int r0 = (int)floorf(rf), c0 = (int)floorf(cf);
  int r1 = min(r0 + 1, GPOS - 1), c1 = min(c0 + 1, GPOS - 1);
  float wr = rf - (float)r0, wc = cf - (float)c0;
  float w00 = (1.f - wr) * (1.f - wc), w01 = (1.f - wr) * wc;
  float w10 = wr * (1.f - wc), w11 = wr * wc;
  float4 v00 = *(const float4*)(pe + (long long)(r0 * GPOS + c0) * DMODEL + d);
  float4 v01 = *(const float4*)(pe + (long long)(r0 * GPOS + c1) * DMODEL + d);
  float4 v10 = *(const float4*)(pe + (long long)(r1 * GPOS + c0) * DMODEL + d);
  float4 v11 = *(const float4*)(pe + (long long)(r1 * GPOS + c1) * DMODEL + d);
  float4 xv = *(float4*)(x + (long long)n * DMODEL + d);
  xv.x += w00 * v00.x + w01 * v01.x + w10 * v10.x + w11 * v11.x;
  xv.y += w00 * v00.y + w01 * v01.y + w10 * v10.y + w11 * v11.y;
  xv.z += w00 * v00.z + w01 * v01.z + w10 * v10.z + w11 * v11.z;
  xv.w += w00 * v00.w + w01 * v01.w + w10 * v10.w + w11 * v11.w;
  *(float4*)(x + (long long)n * DMODEL + d) = xv;
}

// LayerNorm fp32 in -> bf16 out (one 320-thread block per row of 1280)
__global__ void ln_k(const float* __restrict__ X, u16* __restrict__ Y,
                     const float* __restrict__ s, const float* __restrict__ b) {
  int row = blockIdx.x;
  int d = threadIdx.x * 4;
  const float* x = X + (long long)row * DMODEL;
  float4 v = *(const float4*)(x + d);
  float sum = v.x + v.y + v.z + v.w;
#pragma unroll
  for (int o = 32; o; o >>= 1) sum += __shfl_xor(sum, o);
  __shared__ float red[8];
  int wv = threadIdx.x >> 6, lnn = threadIdx.x & 63;
  if (lnn == 0) red[wv] = sum;
  __syncthreads();
  float mu = 0.f;
  for (int i = 0; i < 5; i++) mu += red[i];
  mu *= (1.f / DMODEL);
  float dx = v.x - mu, dy = v.y - mu, dz = v.z - mu, dw = v.w - mu;
  float s2 = dx * dx + dy * dy + dz * dz + dw * dw;
#pragma unroll
  for (int o = 32; o; o >>= 1) s2 += __shfl_xor(s2, o);
  __syncthreads();
  if (lnn == 0) red[wv] = s2;
  __syncthreads();
  float var = 0.f;
  for (int i = 0; i < 5; i++) var += red[i];
  var *= (1.f / DMODEL);
  float rs = rsqrtf(var + 1e-6f);
  ushort4 o4;
  o4.x = f2bf(dx * rs * s[d] + b[d]);
  o4.y = f2bf(dy * rs * s[d + 1] + b[d + 1]);
  o4.z = f2bf(dz * rs * s[d + 2] + b[d + 2]);
  o4.w = f2bf(dw * rs * s[d + 3] + b[d + 3]);
  *(ushort4*)(Y + (long long)row * DMODEL + d) = o4;
}

// RoPE from bf16 qkv -> qr/kr bf16 [h][N][96] (zero pad), v -> vp [h][N][128]
// 256-thread blocks, 4 tokens per block.
__global__ void rope_k(const u16* __restrict__ qkv, const int* __restrict__ rw,
                       const int* __restrict__ cl, u16* __restrict__ qr,
                       u16* __restrict__ kr, u16* __restrict__ vp, int N) {
  int n = blockIdx.x * 4 + (threadIdx.x >> 6), h = blockIdx.y;
  int t = threadIdx.x & 63;
  const u16* src = qkv + (long long)n * (3 * DMODEL) + h * 80;
  long long ob96 = ((long long)h * N + n) * 96;
  long long ob128 = ((long long)h * N + n) * 128;
  if (t < 40) {
    float pos = (t < 20) ? (float)rw[n] : (float)cl[n];
    float infr = exp2f(-13.287712379549449f * (float)(t % 20) * 0.05f);
    float f = pos * infr;
    float cs = cosf(f), sn = sinf(f);
    float q0 = bf2f(src[t]), q1 = bf2f(src[t + 40]);
    qr[ob96 + t] = f2bf(q0 * cs - q1 * sn);
    qr[ob96 + t + 40] = f2bf(q1 * cs + q0 * sn);
    float k0 = bf2f(src[DMODEL + t]), k1 = bf2f(src[DMODEL + t + 40]);
    kr[ob96 + t] = f2bf(k0 * cs - k1 * sn);
    kr[ob96 + t + 40] = f2bf(k1 * cs + k0 * sn);
    vp[ob128 + t] = src[2 * DMODEL + t];
    vp[ob128 + t + 40] = src[2 * DMODEL + t + 40];
  } else {
    int u = t - 40;
    if (u < 16) { qr[ob96 + 80 + u] = 0; kr[ob96 + 80 + u] = 0; }
    vp[ob128 + 80 + u] = 0;
    vp[ob128 + 104 + u] = 0;
  }
}

// ---------------------------------------------------------------------------
// 128x128-tile path: M%128==0, Nn%128==0, (Kd/nsplit)%32==0.
static void gemm_big(hipStream_t st, int epi, const u16* A, const u16* B,
                     const float* bias, void* C, int M, int Nn, int Kd,
                     int lda, int ldb, int ldc, int nsplit) {
  dim3 g(M / 128, Nn / 128, nsplit), blk(256);
  long long ps = (long long)M * Nn;
  switch (epi) {
    case 0: gemm128<0><<<g, blk, 0, st>>>(A, B, bias, C, Kd, lda, ldb, ldc, nsplit, ps); break;
    case 1: gemm128<1><<<g, blk, 0, st>>>(A, B, bias, C, Kd, lda, ldb, ldc, nsplit, ps); break;
    default: gemm128<3><<<g, blk, 0, st>>>(A, B, bias, C, Kd, lda, ldb, ldc, nsplit, ps); break;
  }
}

extern "C" void kernel_launch(void* const* d_in, const int* in_sizes, int n_in,
                              void* d_out, int out_size, void* d_ws, size_t ws_size,
                              hipStream_t stream) {
  const float* pixels = (const float*)d_in[0];
  const int* grid_thw = (const int*)d_in[1];
  const float* pos_embed = (const float*)d_in[2];
  const float* patch_w = (const float*)d_in[3];
  const float* patch_b = (const float*)d_in[4];
  const float* ln1_s = (const float*)d_in[5];
  const float* ln1_b = (const float*)d_in[6];
  const float* qkv_w = (const float*)d_in[7];
  const float* qkv_b = (const float*)d_in[8];
  const float* proj_w = (const float*)d_in[9];
  const float* proj_b = (const float*)d_in[10];
  const float* ln2_s = (const float*)d_in[11];
  const float* ln2_b = (const float*)d_in[12];
  const float* fc1_w = (const float*)d_in[13];
  const float* fc1_b = (const float*)d_in[14];
  const float* fc2_w = (const float*)d_in[15];
  const float* fc2_b = (const float*)d_in[16];
  const float* mns = (const float*)d_in[17];
  const float* mnb = (const float*)d_in[18];
  const float* mf1w = (const float*)d_in[19];
  const float* mf1b = (const float*)d_in[20];
  const float* mf2w = (const float*)d_in[21];
  const float* mf2b = (const float*)d_in[22];
  float* out = (float*)d_out;

  const int N = in_sizes[0] / 1536;  // 2048
  const int nimg = in_sizes[1] / 3;  // 4
  const int nseg = N / SEG;          // 4
  const int nb = NHEADS * nseg;      // 64

  char* w = (char*)d_ws;
  size_t off = 0;
  auto alloc = [&](size_t bytes) -> void* {
    void* p = w + off;
    off += (bytes + 255) & ~(size_t)255;
    return p;
  };
  int* rw = (int*)alloc((size_t)N * 4);
  int* cl = (int*)alloc((size_t)N * 4);
  int* hh = (int*)alloc((size_t)N * 4);
  int* ww = (int*)alloc((size_t)N * 4);
  float* x = (float*)alloc((size_t)N * DMODEL * 4);
  u16* h = (u16*)alloc((size_t)N * DMODEL * 2);
  u16* pixbf = (u16*)alloc((size_t)N * 1536 * 2);      // mfc2T overlay base
  u16* patchT = (u16*)alloc((size_t)DMODEL * 1536 * 2);
  u16* qkvT = (u16*)alloc((size_t)3 * DMODEL * DMODEL * 2);
  u16* projT = (u16*)alloc((size_t)DMODEL * DMODEL * 2);
  u16* fc1T = (u16*)alloc((size_t)FDIM * DMODEL * 2);
  u16* fc2T = (u16*)alloc((size_t)DMODEL * FDIM * 2);
  u16* qkvb = (u16*)alloc((size_t)N * 3 * DMODEL * 2);  // mfc1T overlay base
  u16* qr = (u16*)alloc((size_t)NHEADS * N * 96 * 2);
  u16* kr = (u16*)alloc((size_t)NHEADS * N * 96 * 2);
  u16* vp = (u16*)alloc((size_t)NHEADS * N * 128 * 2);
  u16* vpT = (u16*)alloc((size_t)NHEADS * N * 128 * 2);
  u16* pad0 = (u16*)alloc((size_t)nb * 2 * SEG * 128 * 2);  // keeps mfc1T overlay in bounds
  u16* o = (u16*)alloc((size_t)N * DMODEL * 2);
  float* bigA = (float*)alloc((size_t)nb * SEG * SEG * 4);  // ffb / mf
  float* bigB = (float*)alloc((size_t)nb * SEG * SEG * 2);  // split-K partials
  (void)ws_size; (void)pad0;
  // overlays (lifetimes disjoint with originals)
  u16* mfc1T = qkvb;         // 52.4 MB over qkvb..pad0 region
  u16* mfc2T = pixbf;        // 21.0 MB over pixbf..projT
  u16* ffb = (u16*)bigA;     // fc1 out, 21 MB at bigA base
  u16* mf = (u16*)bigA;      // merger hidden 5.2 MB at bigA base
  u16* part = (u16*)bigB;    // split-K bf16 partial planes (<= 33.5 MB)

  const float iscale = 0.11180339887498949f;  // 80^-0.5
  const long long mnD = (long long)N * DMODEL;

  coords_k<<<dim3((N + 255) / 256), 256, 0, stream>>>(grid_thw, nimg, rw, cl, hh, ww, N);
  conv_k<<<dim3((int)(((long long)N * 1536 / 4 + 255) / 256)), 256, 0, stream>>>(
      pixels, pixbf, (long long)N * 1536);
  wconv_k<<<dim3(DMODEL / 32, 1536 / 64), 256, 0, stream>>>(patch_w, patchT, 1536, DMODEL);
  // patch embed, split-K=4 (640 blocks)
  gemm_big(stream, 0, pixbf, patchT, nullptr, part, N, DMODEL, 1536, 1536, 1536,
           DMODEL, 4);
  reduce_k<4, 0, 0, 0><<<dim3((int)((mnD / 4 + 255) / 256)), 256, 0, stream>>>(
      part, mnD, DMODEL, patch_b, nullptr, x);
  peadd_k<<<dim3(N), 320, 0, stream>>>(x, pos_embed, rw, cl, hh, ww);
  // ln1 of layer 0 (subsequent LNs fused into split-K reduces)
  ln_k<<<dim3(N), 320, 0, stream>>>(x, h, ln1_s, ln1_b);

  for (int l = 0; l < 4; l++) {
    wconv_k<<<dim3(3 * DMODEL / 32, DMODEL / 64), 256, 0, stream>>>(
        qkv_w + (size_t)l * DMODEL * 3 * DMODEL, qkvT, DMODEL, 3 * DMODEL);
    wconv_k<<<dim3(DMODEL / 32, DMODEL / 64), 256, 0, stream>>>(
        proj_w + (size_t)l * DMODEL * DMODEL, projT, DMODEL, DMODEL);
    wconv_k<<<dim3(FDIM / 32, DMODEL / 64), 256, 0, stream>>>(
        fc1_w + (size_t)l * DMODEL * FDIM, fc1T, DMODEL, FDIM);
    wconv_k<<<dim3(DMODEL / 32, FDIM / 64), 256, 0, stream>>>(
        fc2_w + (size_t)l * FDIM * DMODEL, fc2T, FDIM, DMODEL);

    // qkv direct +bias (480 blocks, NT=40)
    gemm_big(stream, 1, h, qkvT, qkv_b + (size_t)l * 3 * DMODEL, qkvb, N,
             3 * DMODEL, DMODEL, DMODEL, DMODEL, 3 * DMODEL, 1);
    rope_k<<<dim3(N / 4, NHEADS), 256, 0, stream>>>(qkvb, rw, cl, qr, kr, vp, N);
    vtr_k<<<dim3(8, 2, nb), 256, 0, stream>>>(vp, vpT);
    // fused flash attention -> o (256 blocks x 512 thr, 2 waves/SIMD)
    fattn_k<<<dim3(SEG / 128, nb), 512, 0, stream>>>(qr, kr, vpT, o, N, iscale);
    // proj split-K=4 (640 blocks); fused reduce + bias + residual + ln2 -> h
    gemm_big(stream, 0, o, projT, nullptr, part, N, DMODEL, DMODEL, DMODEL,
             DMODEL, DMODEL, 4);
    redln_k<4><<<dim3(N), 320, 0, stream>>>(part, mnD, proj_b + (size_t)l * DMODEL,
                                            x, ln2_s + (size_t)l * DMODEL,
                                            ln2_b + (size_t)l * DMODEL, h);
    // fc1 fused bias+gelu -> bf16 (640 blocks, direct)
    gemm_big(stream, 3, h, fc1T, fc1_b + (size_t)l * FDIM, ffb, N, FDIM, DMODEL,
             DMODEL, DMODEL, FDIM, 1);
    // fc2 split-K=4 (640 blocks); fused reduce + bias + residual + next LN -> h
    gemm_big(stream, 0, ffb, fc2T, nullptr, part, N, DMODEL, FDIM, FDIM, FDIM,
             DMODEL, 4);
    const float* nsl = (l < 3) ? ln1_s + (size_t)(l + 1) * DMODEL : mns;
    const float* nbl = (l < 3) ? ln1_b + (size_t)(l + 1) * DMODEL : mnb;
    redln_k<4><<<dim3(N), 320, 0, stream>>>(part, mnD, fc2_b + (size_t)l * DMODEL,
                                            x, nsl, nbl, h);
  }

  // merger (h already = LN(x; mns,mnb), viewed as [512][5120])
  const int Mm = N / 4;  // 512
  wconv_k<<<dim3(FDIM / 32, FDIM / 64), 256, 0, stream>>>(mf1w, mfc1T, FDIM, FDIM);
  // mfc1 split-K=4 (640 blocks); reduce + bias + gelu -> mf
  gemm_big(stream, 0, h, mfc1T, nullptr, part, Mm, FDIM, FDIM, FDIM, FDIM, FDIM, 4);
  reduce_k<4, 0, 1, 1><<<dim3((int)(((long long)Mm * FDIM / 4 + 255) / 256)), 256, 0, stream>>>(
      part, (long long)Mm * FDIM, FDIM, mf1b, nullptr, mf);
  wconv_k<<<dim3(2048 / 32, FDIM / 64), 256, 0, stream>>>(mf2w, mfc2T, FDIM, 2048);
  // mfc2 split-K=16 (1024 blocks)
  gemm_big(stream, 0, mf, mfc2T, nullptr, part, Mm, 2048, FDIM, FDIM, FDIM, 2048, 16);
  reduce_k<16, 0, 0, 0><<<dim3((int)(((long long)Mm * 2048 / 4 + 255) / 256)), 256, 0, stream>>>(
      part, (long long)Mm * 2048, 2048, mf2b, nullptr, out);
}

// Round 11
// 1306.896 us; speedup vs baseline: 1.1612x; 1.0028x over previous
//
#include <hip/hip_runtime.h>
#include <math.h>

#define DMODEL 1280
#define NHEADS 16
#define FDIM   5120
#define GPOS   48
#define SEG    512

typedef __attribute__((ext_vector_type(8))) short bf16x8;
typedef __attribute__((ext_vector_type(4))) float f32x4;
typedef unsigned short u16;

__device__ __forceinline__ u16 f2bf(float f) {
  unsigned int u = __float_as_uint(f);
  u = (u + 0x7FFFu + ((u >> 16) & 1u)) >> 16;  // RNE
  return (u16)u;
}
__device__ __forceinline__ float bf2f(u16 u) {
  return __uint_as_float((unsigned int)u << 16);
}
__device__ __forceinline__ float gelu_tanh(float x) {
  float u = 0.7978845608028654f * (x + 0.044715f * x * x * x);
  float t = __expf(2.f * u);
  float th = 1.f - 2.f / (t + 1.f);
  return 0.5f * x * (1.f + th);
}

typedef const __attribute__((address_space(1))) unsigned int* gas_t;
typedef __attribute__((address_space(3))) unsigned int* las_t;
__device__ __forceinline__ void async16(const void* g, void* l) {
  __builtin_amdgcn_global_load_lds((gas_t)g, (las_t)l, 16, 0, 0);
}

// Bijective XCD chunk remap (T1, m204 form).
__device__ __forceinline__ int xcd_remap(int b, int nwg) {
  int q = nwg >> 3, r = nwg & 7, x = b & 7, d = b >> 3;
  return (x < r ? x * (q + 1) : r * (q + 1) + (x - r) * q) + d;
}

// ---------------------------------------------------------------------------
// gemm128 (R8-verified): 128x128 tile, BK=32, 4 waves, 32 KiB dbuf LDS,
// 3 blocks/CU, R2 subtile swizzle, T1 remap, 2 phases/tile, depth-1
// prefetch, per-element accumulation order fixed (k0,k32,...).
// A:[M][K] bf16, B:[N][K] bf16, C = A.B^T.
// EPI 0: bf16 partial planes (split-K). EPI 1: +bias bf16. EPI 3: +bias+gelu.
// ---------------------------------------------------------------------------
#define STG1(mat, PW, ldx, rb, kk, pp)                                      \
  async16((PW) + (long long)(rb) * 16 * (ldx) + (kk),                       \
          &L[pp][mat][(rb) * 512])

#define BARX() asm volatile("s_barrier" ::: "memory")
#define LGKM0() asm volatile("s_waitcnt lgkmcnt(0)" ::: "memory")

template <int EPI>
__global__ __launch_bounds__(256, 3) void gemm128(
    const u16* __restrict__ A, const u16* __restrict__ B,
    const float* __restrict__ bias, void* __restrict__ Cv,
    int Kd, int lda, int ldb, int ldc, int nsplit, long long pstride) {
  __shared__ __align__(16) u16 L[2][2][4096];  // [buf][A|B][8rb x 512]
  const int sp = blockIdx.z;
  const int Ks = Kd / nsplit;
  const int NT = Ks >> 5;
  const u16* Ab = A + (long long)sp * Ks;
  const u16* Bb = B + (long long)sp * Ks;
  const int gx = gridDim.x;
  const int lg = xcd_remap(blockIdx.x + gx * blockIdx.y, gx * gridDim.y);
  const int m0 = (lg % gx) * 128, n0 = (lg / gx) * 128;
  const int t = threadIdx.x, ln = t & 63, w = t >> 6;
  const int wr = w >> 1, wc = w & 1;
  const int m16 = ln & 15, q = ln >> 4;
  const int r16 = ln >> 2;
  const int csw = (ln & 3) ^ ((ln >> 5) << 1);               // R2 source swz
  const int rbase = m16 * 32 + (q ^ ((m16 >> 3) << 1)) * 8;  // R2 read swz

  const u16* Aw = Ab + (long long)(m0 + r16) * lda + csw * 8;
  const u16* Bw = Bb + (long long)(n0 + r16) * ldb + csw * 8;
  const int w4 = w + 4;

  f32x4 acc[4][4];
#pragma unroll
  for (int i = 0; i < 4; i++)
#pragma unroll
    for (int j = 0; j < 4; j++)
#pragma unroll
      for (int r = 0; r < 4; r++) acc[i][j][r] = 0.f;

  // prologue: tile0 (4 loads/wave) + tile1 (4); vmcnt(4) -> tile0 landed.
  STG1(0, Aw, lda, w, 0, 0);  STG1(0, Aw, lda, w4, 0, 0);
  STG1(1, Bw, ldb, w, 0, 0);  STG1(1, Bw, ldb, w4, 0, 0);
  if (NT > 1) {
    STG1(0, Aw, lda, w, 32, 1);  STG1(0, Aw, lda, w4, 32, 1);
    STG1(1, Bw, ldb, w, 32, 1);  STG1(1, Bw, ldb, w4, 32, 1);
    asm volatile("s_waitcnt vmcnt(4)" ::: "memory");
  } else {
    asm volatile("s_waitcnt vmcnt(0)" ::: "memory");
  }
  BARX();

  for (int tt = 0; tt < NT; ++tt) {
    const int p = tt & 1;
    const u16* Abuf = &L[p][0][0];
    const u16* Bbuf = &L[p][1][0];
    bf16x8 aR[4], bR[4];

    // ph1: ds all aR (4) + bR[0..1] (2); stage A(t+1) -> buf p^1
#pragma unroll
    for (int i = 0; i < 4; ++i)
      aR[i] = *(const bf16x8*)(Abuf + (wr * 4 + i) * 512 + rbase);
    bR[0] = *(const bf16x8*)(Bbuf + (wc * 4 + 0) * 512 + rbase);
    bR[1] = *(const bf16x8*)(Bbuf + (wc * 4 + 1) * 512 + rbase);
    if (tt + 1 < NT) {
      STG1(0, Aw, lda, w, (tt + 1) * 32, p ^ 1);
      STG1(0, Aw, lda, w4, (tt + 1) * 32, p ^ 1);
    }
    BARX();
    LGKM0();
    __builtin_amdgcn_s_setprio(1);
#pragma unroll
    for (int i = 0; i < 4; ++i) {
      acc[i][0] = __builtin_amdgcn_mfma_f32_16x16x32_bf16(aR[i], bR[0], acc[i][0], 0, 0, 0);
      acc[i][1] = __builtin_amdgcn_mfma_f32_16x16x32_bf16(aR[i], bR[1], acc[i][1], 0, 0, 0);
    }
    __builtin_amdgcn_s_setprio(0);
    BARX();

    // ph2: ds bR[2..3] (2); stage B(t+1) -> buf p^1; tile-end drain
    bR[2] = *(const bf16x8*)(Bbuf + (wc * 4 + 2) * 512 + rbase);
    bR[3] = *(const bf16x8*)(Bbuf + (wc * 4 + 3) * 512 + rbase);
    if (tt + 1 < NT) {
      STG1(1, Bw, ldb, w, (tt + 1) * 32, p ^ 1);
      STG1(1, Bw, ldb, w4, (tt + 1) * 32, p ^ 1);
    }
    BARX();
    LGKM0();
    __builtin_amdgcn_s_setprio(1);
#pragma unroll
    for (int i = 0; i < 4; ++i) {
      acc[i][2] = __builtin_amdgcn_mfma_f32_16x16x32_bf16(aR[i], bR[2], acc[i][2], 0, 0, 0);
      acc[i][3] = __builtin_amdgcn_mfma_f32_16x16x32_bf16(aR[i], bR[3], acc[i][3], 0, 0, 0);
    }
    __builtin_amdgcn_s_setprio(0);
    if (tt + 1 < NT) asm volatile("s_waitcnt vmcnt(0)" ::: "memory");
    BARX();
  }

#pragma unroll
  for (int fr = 0; fr < 4; fr++) {
#pragma unroll
    for (int r = 0; r < 4; r++) {
      int row = m0 + wr * 64 + fr * 16 + q * 4 + r;
      if (EPI == 0) {
        u16* Cp = (u16*)Cv + (long long)sp * pstride + (long long)row * ldc;
#pragma unroll
        for (int fc = 0; fc < 4; fc++)
          Cp[n0 + wc * 64 + fc * 16 + m16] = f2bf(acc[fr][fc][r]);
      } else if (EPI == 1) {
        u16* Cb = (u16*)Cv + (long long)row * ldc;
#pragma unroll
        for (int fc = 0; fc < 4; fc++) {
          int col = n0 + wc * 64 + fc * 16 + m16;
          Cb[col] = f2bf(acc[fr][fc][r] + bias[col]);
        }
      } else {  // EPI == 3
        u16* Cb = (u16*)Cv + (long long)row * ldc;
#pragma unroll
        for (int fc = 0; fc < 4; fc++) {
          int col = n0 + wc * 64 + fc * 16 + m16;
          Cb[col] = f2bf(gelu_tanh(acc[fr][fc][r] + bias[col]));
        }
      }
    }
  }
}

// ---------------------------------------------------------------------------
// Fused flash attention v3: 64-row q-strips -> grid (8, nb) = 512 blocks,
// 4 waves x 16 q-rows, single-buffered K/V (stage -> barrier -> compute;
// the lost intra-block double-buffer is replaced by inter-block overlap:
// LDS = 44KB KV + 16KB P = 60KB -> 2 blocks/CU co-resident, the R7-proven
// mechanism; fattn was the last 1-block/CU kernel). Per-q-row arithmetic,
// P-panel XOR layout, stage partition (R2-era w*6/w*5 split) unchanged ->
// bit-identical results. T1-chunked: 8 strips of one (head,seg) contiguous.
// ---------------------------------------------------------------------------
__global__ __launch_bounds__(256) void fattn_k(
    const u16* __restrict__ qr, const u16* __restrict__ kr,
    const u16* __restrict__ vpT, u16* __restrict__ o, int N, float iscale) {
  __shared__ __align__(16) u16 Ks[24][512];      // [f*3+kg][16kv x 32hd]
  __shared__ __align__(16) u16 Vs[20][512];      // [df*4+kvg][16d x 32kv]
  __shared__ __align__(16) u16 Ps[4][16 * 128];  // per-wave P panel (16 rows)
  const int nseg = N >> 9;
  const int gx = gridDim.x;  // 8
  const int lg = xcd_remap(blockIdx.x + gx * blockIdx.y, gx * gridDim.y);
  const int strip = lg % gx, hb = lg / gx;
  const int h = hb / nseg, seg = hb - h * nseg;
  const int t = threadIdx.x, ln = t & 63, w = t >> 6;  // w in [0,4)
  const int m16 = ln & 15, qh = ln >> 4;
  const int r4 = ln >> 2, gsw = (ln & 3) ^ ((ln >> 5) << 1);
  const int rbase = m16 * 32 + ((qh ^ ((m16 >> 3) << 1)) << 3);
  const long long hN = (long long)h * N;
  const int segbase = seg * SEG;
  const int q0 = segbase + strip * 64 + w * 16;  // 8 strips x 4 waves x 16

  bf16x8 qf[3];
#pragma unroll
  for (int ks = 0; ks < 3; ks++)
    qf[ks] = *(const bf16x8*)&qr[(hN + q0 + m16) * 96 + ks * 32 + qh * 8];

  f32x4 ao[5];
#pragma unroll
  for (int df = 0; df < 5; df++)
#pragma unroll
    for (int r = 0; r < 4; r++) ao[df][r] = 0.f;
  float m_[4], l_[4];
#pragma unroll
  for (int r = 0; r < 4; r++) { m_[r] = -1e30f; l_[r] = 0.f; }

  auto stage = [&](int c) {
#pragma unroll
    for (int i = 0; i < 6; i++) {  // 24 K subtiles over 4 waves
      int sK = w * 6 + i, f = sK / 3, kg = sK - f * 3;
      async16(&kr[(hN + segbase + c * 128 + f * 16 + r4) * 96 + kg * 32 + gsw * 8],
              &Ks[sK][0]);
    }
#pragma unroll
    for (int i = 0; i < 5; i++) {  // 20 V subtiles over 4 waves
      int sV = w * 5 + i, df = sV >> 2, kvg = sV & 3;
      async16(&vpT[((long long)hb * 128 + df * 16 + r4) * SEG + c * 128 + kvg * 32 + gsw * 8],
              &Vs[sV][0]);
    }
  };

  u16* Pmy = &Ps[w][0];
  for (int c = 0; c < 4; c++) {
    if (c) __syncthreads();  // all reads of chunk c-1 done before overwrite
    stage(c);
    __syncthreads();         // chunk c staged (barrier drains vmcnt)

    // QK^T: s[f] rows q=qh*4+r, cols kv=f*16+m16
    f32x4 s[8];
#pragma unroll
    for (int f = 0; f < 8; f++)
#pragma unroll
      for (int r = 0; r < 4; r++) s[f][r] = 0.f;
#pragma unroll
    for (int ks = 0; ks < 3; ks++) {
#pragma unroll
      for (int f = 0; f < 8; f++) {
        bf16x8 kf = *(const bf16x8*)&Ks[f * 3 + ks][rbase];
        s[f] = __builtin_amdgcn_mfma_f32_16x16x32_bf16(qf[ks], kf, s[f], 0, 0, 0);
      }
    }

    // online softmax per row
#pragma unroll
    for (int r = 0; r < 4; r++) {
      float mx = s[0][r];
#pragma unroll
      for (int f = 1; f < 8; f++) mx = fmaxf(mx, s[f][r]);
      mx *= iscale;
#pragma unroll
      for (int o2 = 1; o2 <= 8; o2 <<= 1) mx = fmaxf(mx, __shfl_xor(mx, o2));
      float mn = fmaxf(m_[r], mx);
      float corr = __expf(m_[r] - mn);
      m_[r] = mn;
      float rs = 0.f;
#pragma unroll
      for (int f = 0; f < 8; f++) {
        float p = __expf(s[f][r] * iscale - mn);
        s[f][r] = p;
        rs += p;
      }
#pragma unroll
      for (int o2 = 1; o2 <= 8; o2 <<= 1) rs += __shfl_xor(rs, o2);
      l_[r] = l_[r] * corr + rs;
#pragma unroll
      for (int df = 0; df < 5; df++) ao[df][r] *= corr;
    }

    // P -> LDS (per-wave private): addr(q,kv)=q*128 + ((kv>>3)^(q&7))*8 + (kv&7)
#pragma unroll
    for (int r = 0; r < 4; r++) {
      int qq = qh * 4 + r;  // 0..15
      int base = qq * 128 + (m16 & 7);
      int ql = qq & 7;
#pragma unroll
      for (int f = 0; f < 8; f++) {
        int gr = (f * 2 + (m16 >> 3)) ^ ql;
        Pmy[base + gr * 8] = f2bf(s[f][r]);
      }
    }

    // PV: O[q][d] += P[q][kv] V^T[d][kv]
#pragma unroll
    for (int ks = 0; ks < 4; ks++) {
      bf16x8 pf = *(const bf16x8*)&Pmy[m16 * 128 +
                                       (((ks * 4 + qh) ^ (m16 & 7)) << 3)];
#pragma unroll
      for (int df = 0; df < 5; df++) {
        bf16x8 vf = *(const bf16x8*)&Vs[df * 4 + ks][rbase];
        ao[df] = __builtin_amdgcn_mfma_f32_16x16x32_bf16(pf, vf, ao[df], 0, 0, 0);
      }
    }
  }

#pragma unroll
  for (int r = 0; r < 4; r++) {
    float rl = 1.f / l_[r];
    long long rowb = (long long)(q0 + qh * 4 + r) * DMODEL + h * 80;
#pragma unroll
    for (int df = 0; df < 5; df++)
      o[rowb + df * 16 + m16] = f2bf(ao[df][r] * rl);
  }
}

// ---------------------------------------------------------------------------
// Split-K reduce + epilogue (bf16 partials): out = [gelu](sum + bias) [+ res]
// ---------------------------------------------------------------------------
template <int S, int RES, int GELU, int OUTBF>
__global__ void reduce_k(const u16* __restrict__ Pp, long long mn, int Nn,
                         const float* __restrict__ bias,
                         const float* __restrict__ res, void* __restrict__ out) {
  long long i = ((long long)blockIdx.x * 256 + threadIdx.x) * 4;
  if (i >= mn) return;
  float vx = 0.f, vy = 0.f, vz = 0.f, vw = 0.f;
#pragma unroll
  for (int s = 0; s < S; s++) {
    ushort4 u4 = *(const ushort4*)(Pp + (long long)s * mn + i);
    vx += bf2f(u4.x); vy += bf2f(u4.y); vz += bf2f(u4.z); vw += bf2f(u4.w);
  }
  int col = (int)(i % Nn);
  vx += bias[col]; vy += bias[col + 1]; vz += bias[col + 2]; vw += bias[col + 3];
  if (GELU) {
    vx = gelu_tanh(vx); vy = gelu_tanh(vy);
    vz = gelu_tanh(vz); vw = gelu_tanh(vw);
  }
  if (RES) {
    float4 r4 = *(const float4*)(res + i);
    vx += r4.x; vy += r4.y; vz += r4.z; vw += r4.w;
  }
  if (OUTBF) {
    ushort4 o; o.x = f2bf(vx); o.y = f2bf(vy); o.z = f2bf(vz); o.w = f2bf(vw);
    *(ushort4*)((u16*)out + i) = o;
  } else {
    float4 o; o.x = vx; o.y = vy; o.z = vz; o.w = vw;
    *(float4*)((float*)out + i) = o;
  }
}

// ---------------------------------------------------------------------------
// Fused split-K reduce + residual + LayerNorm: one 320-thread block per row.
// ---------------------------------------------------------------------------
template <int S>
__global__ void redln_k(const u16* __restrict__ Pp, long long mn,
                        const float* __restrict__ bias,
                        float* __restrict__ x,
                        const float* __restrict__ s, const float* __restrict__ b,
                        u16* __restrict__ h) {
  int row = blockIdx.x;
  int d = threadIdx.x * 4;
  long long base = (long long)row * DMODEL + d;
  float vx = 0.f, vy = 0.f, vz = 0.f, vw = 0.f;
#pragma unroll
  for (int si = 0; si < S; si++) {
    ushort4 u4 = *(const ushort4*)(Pp + (long long)si * mn + base);
    vx += bf2f(u4.x); vy += bf2f(u4.y); vz += bf2f(u4.z); vw += bf2f(u4.w);
  }
  vx += bias[d]; vy += bias[d + 1]; vz += bias[d + 2]; vw += bias[d + 3];
  float4 r4 = *(const float4*)(x + base);
  vx += r4.x; vy += r4.y; vz += r4.z; vw += r4.w;
  float4 xv; xv.x = vx; xv.y = vy; xv.z = vz; xv.w = vw;
  *(float4*)(x + base) = xv;
  float sum = vx + vy + vz + vw;
#pragma unroll
  for (int o = 32; o; o >>= 1) sum += __shfl_xor(sum, o);
  __shared__ float red[8];
  int wv = threadIdx.x >> 6, lnn = threadIdx.x & 63;
  if (lnn == 0) red[wv] = sum;
  __syncthreads();
  float mu = 0.f;
  for (int i = 0; i < 5; i++) mu += red[i];
  mu *= (1.f / DMODEL);
  float dx = vx - mu, dy = vy - mu, dz = vz - mu, dw = vw - mu;
  float s2 = dx * dx + dy * dy + dz * dz + dw * dw;
#pragma unroll
  for (int o = 32; o; o >>= 1) s2 += __shfl_xor(s2, o);
  __syncthreads();
  if (lnn == 0) red[wv] = s2;
  __syncthreads();
  float var = 0.f;
  for (int i = 0; i < 5; i++) var += red[i];
  var *= (1.f / DMODEL);
  float rs = rsqrtf(var + 1e-6f);
  ushort4 o4;
  o4.x = f2bf(dx * rs * s[d] + b[d]);
  o4.y = f2bf(dy * rs * s[d + 1] + b[d + 1]);
  o4.z = f2bf(dz * rs * s[d + 2] + b[d + 2]);
  o4.w = f2bf(dw * rs * s[d + 3] + b[d + 3]);
  *(ushort4*)(h + base) = o4;
}

// ---------------------------------------------------------------------------
// Fused patch epilogue: split-K reduce + bias + pos-embed + store x + ln1 -> h
// (replaces reduce_k<4,0,0,0> + peadd_k + ln_k; identical op order.)
// ---------------------------------------------------------------------------
__global__ void redpeln_k(const u16* __restrict__ Pp, long long mn,
                          const float* __restrict__ bias,
                          const float* __restrict__ pe,
                          const int* __restrict__ rw, const int* __restrict__ cl,
                          const int* __restrict__ hh, const int* __restrict__ ww,
                          float* __restrict__ x,
                          const float* __restrict__ s, const float* __restrict__ b,
                          u16* __restrict__ h) {
  int n = blockIdx.x;
  int d = threadIdx.x * 4;
  long long base = (long long)n * DMODEL + d;
  float vx = 0.f, vy = 0.f, vz = 0.f, vw = 0.f;
#pragma unroll
  for (int si = 0; si < 4; si++) {
    ushort4 u4 = *(const ushort4*)(Pp + (long long)si * mn + base);
    vx += bf2f(u4.x); vy += bf2f(u4.y); vz += bf2f(u4.z); vw += bf2f(u4.w);
  }
  vx += bias[d]; vy += bias[d + 1]; vz += bias[d + 2]; vw += bias[d + 3];
  // pos-embed bilinear add (same math as peadd_k)
  int H = hh[n], W = ww[n];
  float rf = (H > 1) ? (float)rw[n] * (float)(GPOS - 1) / (float)(H - 1) : 0.f;
  float cf = (W > 1) ? (float)cl[n] * (float)(GPOS - 1) / (float)(W - 1) : 0.f;
  int r0 = (int)floorf(rf), c0 = (int)floorf(cf);
  int r1 = min(r0 + 1, GPOS - 1), c1 = min(c0 + 1, GPOS - 1);
  float wr = rf - (float)r0, wc = cf - (float)c0;
  float w00 = (1.f - wr) * (1.f - wc), w01 = (1.f - wr) * wc;
  float w10 = wr * (1.f - wc), w11 = wr * wc;
  float4 v00 = *(const float4*)(pe + (long long)(r0 * GPOS + c0) * DMODEL + d);
  float4 v01 = *(const float4*)(pe + (long long)(r0 * GPOS + c1) * DMODEL + d);
  float4 v10 = *(const float4*)(pe + (long long)(r1 * GPOS + c0) * DMODEL + d);
  float4 v11 = *(const float4*)(pe + (long long)(r1 * GPOS + c1) * DMODEL + d);
  vx += w00 * v00.x + w01 * v01.x + w10 * v10.x + w11 * v11.x;
  vy += w00 * v00.y + w01 * v01.y + w10 * v10.y + w11 * v11.y;
  vz += w00 * v00.z + w01 * v01.z + w10 * v10.z + w11 * v11.z;
  vw += w00 * v00.w + w01 * v01.w + w10 * v10.w + w11 * v11.w;
  float4 xv; xv.x = vx; xv.y = vy; xv.z = vz; xv.w = vw;
  *(float4*)(x + base) = xv;
  // LayerNorm (ln1 of layer 0)
  float sum = vx + vy + vz + vw;
#pragma unroll
  for (int o = 32; o; o >>= 1) sum += __shfl_xor(sum, o);
  __shared__ float red[8];
  int wv = threadIdx.x >> 6, lnn = threadIdx.x & 63;
  if (lnn == 0) red[wv] = sum;
  __syncthreads();
  float mu = 0.f;
  for (int i = 0; i < 5; i++) mu += red[i];
  mu *= (1.f / DMODEL);
  float dx = vx - mu, dy = vy - mu, dz = vz - mu, dw = vw - mu;
  float s2 = dx * dx + dy * dy + dz * dz + dw * dw;
#pragma unroll
  for (int o = 32; o; o >>= 1) s2 += __shfl_xor(s2, o);
  __syncthreads();
  if (lnn == 0) red[wv] = s2;
  __syncthreads();
  float var = 0.f;
  for (int i = 0; i < 5; i++) var += red[i];
  var *= (1.f / DMODEL);
  float rs = rsqrtf(var + 1e-6f);
  ushort4 o4;
  o4.x = f2bf(dx * rs * s[d] + b[d]);
  o4.y = f2bf(dy * rs * s[d + 1] + b[d + 1]);
  o4.z = f2bf(dz * rs * s[d + 2] + b[d + 2]);
  o4.w = f2bf(dw * rs * s[d + 3] + b[d + 3]);
  *(ushort4*)(h + base) = o4;
}

// ---------------------------------------------------------------------------
// Weight convert+transpose v2: in fp32 [K][N] -> out bf16 [N][K].
// Tile 64k x 32n, 256 threads; 16B ushort8 writes. Grid: (N/32, K/64).
// ---------------------------------------------------------------------------
union U16x8 { uint4 v; u16 s[8]; };
__global__ void wconv_k(const float* __restrict__ in, u16* __restrict__ out,
                        int K, int N) {
  __shared__ float tl[64][33];
  int n0 = blockIdx.x * 32, k0 = blockIdx.y * 64;
  int t = threadIdx.x;
  int rr = t >> 5, c = t & 31;
#pragma unroll
  for (int i = 0; i < 8; i++)
    tl[rr + 8 * i][c] = in[(long long)(k0 + rr + 8 * i) * N + n0 + c];
  __syncthreads();
  int n = t >> 3, kq = (t & 7) * 8;
  U16x8 o;
#pragma unroll
  for (int j = 0; j < 8; j++) o.s[j] = f2bf(tl[kq + j][n]);
  *(uint4*)&out[(long long)(n0 + n) * K + k0 + kq] = o.v;
}

// fp32 -> bf16 flat copy
__global__ void conv_k(const float* __restrict__ in, u16* __restrict__ out,
                       long long n) {
  long long i = ((long long)blockIdx.x * 256 + threadIdx.x) * 4;
  if (i >= n) return;
  float4 v = *(const float4*)(in + i);
  ushort4 o; o.x = f2bf(v.x); o.y = f2bf(v.y); o.z = f2bf(v.z); o.w = f2bf(v.w);
  *(ushort4*)&out[i] = o;
}

// V transpose per batch: in bf16 [b][512][128] -> out bf16 [b][128][512]
__global__ void vtr_k(const u16* __restrict__ in, u16* __restrict__ out) {
  __shared__ u16 tl[64][65];
  int b = blockIdx.z;
  int m0 = blockIdx.x * 64;
  int d0 = blockIdx.y * 64;
  const u16* ib = in + (long long)b * SEG * 128;
  u16* ob = out + (long long)b * 128 * SEG;
  int t = threadIdx.x;
  int r = t >> 3, c8 = (t & 7) * 8;
#pragma unroll
  for (int i = 0; i < 2; i++) {
    U16x8 ld;
    ld.v = *(const uint4*)&ib[(long long)(m0 + r + 32 * i) * 128 + d0 + c8];
#pragma unroll
    for (int j = 0; j < 8; j++) tl[r + 32 * i][c8 + j] = ld.s[j];
  }
  __syncthreads();
  int d = t >> 3, m8 = (t & 7) * 8;
#pragma unroll
  for (int i = 0; i < 2; i++) {
    int dd = d + 32 * i;
    U16x8 st;
#pragma unroll
    for (int j = 0; j < 8; j++) st.s[j] = tl[m8 + j][dd];
    *(uint4*)&ob[(long long)(d0 + dd) * SEG + m0 + m8] = st.v;
  }
}

// ---------------------------------------------------------------------------
__global__ void coords_k(const int* __restrict__ g, int nimg,
                         int* __restrict__ rw, int* __restrict__ cl,
                         int* __restrict__ hh, int* __restrict__ ww, int N) {
  int t = blockIdx.x * 256 + threadIdx.x;
  if (t >= N) return;
  int c = 0, local = 0, H = 1, W = 1;
  for (int i = 0; i < nimg; i++) {
    int tpi = g[i * 3] * g[i * 3 + 1] * g[i * 3 + 2];
    if (t >= c && t < c + tpi) { local = t - c; H = g[i * 3 + 1]; W = g[i * 3 + 2]; }
    c += tpi;
  }
  int hw = H * W;
  int sp = local % hw;
  int mw = W >> 1;
  int gr = sp >> 2, intra = sp & 3;
  rw[t] = (gr / mw) * 2 + (intra >> 1);
  cl[t] = (gr % mw) * 2 + (intra & 1);
  hh[t] = H; ww[t] = W;
}

// RoPE from bf16 qkv -> qr/kr bf16 [h][N][96] (zero pad), v -> vp [h][N][128]
// 256-thread blocks, 4 tokens per block.
__global__ void rope_k(const u16* __restrict__ qkv, const int* __restrict__ rw,
                       const int* __restrict__ cl, u16* __restrict__ qr,
                       u16* __restrict__ kr, u16* __restrict__ vp, int N) {
  int n = blockIdx.x * 4 + (threadIdx.x >> 6), h = blockIdx.y;
  int t = threadIdx.x & 63;
  const u16* src = qkv + (long long)n * (3 * DMODEL) + h * 80;
  long long ob96 = ((long long)h * N + n) * 96;
  long long ob128 = ((long long)h * N + n) * 128;
  if (t < 40) {
    float pos = (t < 20) ? (float)rw[n] : (float)cl[n];
    float infr = exp2f(-13.287712379549449f * (float)(t % 20) * 0.05f);
    float f = pos * infr;
    float cs = cosf(f), sn = sinf(f);
    float q0 = bf2f(src[t]), q1 = bf2f(src[t + 40]);
    qr[ob96 + t] = f2bf(q0 * cs - q1 * sn);
    qr[ob96 + t + 40] = f2bf(q1 * cs + q0 * sn);
    float k0 = bf2f(src[DMODEL + t]), k1 = bf2f(src[DMODEL + t + 40]);
    kr[ob96 + t] = f2bf(k0 * cs - k1 * sn);
    kr[ob96 + t + 40] = f2bf(k1 * cs + k0 * sn);
    vp[ob128 + t] = src[2 * DMODEL + t];
    vp[ob128 + t + 40] = src[2 * DMODEL + t + 40];
  } else {
    int u = t - 40;
    if (u < 16) { qr[ob96 + 80 + u] = 0; kr[ob96 + 80 + u] = 0; }
    vp[ob128 + 80 + u] = 0;
    vp[ob128 + 104 + u] = 0;
  }
}

// ---------------------------------------------------------------------------
// 128x128-tile path: M%128==0, Nn%128==0, (Kd/nsplit)%32==0.
static void gemm_big(hipStream_t st, int epi, const u16* A, const u16* B,
                     const float* bias, void* C, int M, int Nn, int Kd,
                     int lda, int ldb, int ldc, int nsplit) {
  dim3 g(M / 128, Nn / 128, nsplit), blk(256);
  long long ps = (long long)M * Nn;
  switch (epi) {
    case 0: gemm128<0><<<g, blk, 0, st>>>(A, B, bias, C, Kd, lda, ldb, ldc, nsplit, ps); break;
    case 1: gemm128<1><<<g, blk, 0, st>>>(A, B, bias, C, Kd, lda, ldb, ldc, nsplit, ps); break;
    default: gemm128<3><<<g, blk, 0, st>>>(A, B, bias, C, Kd, lda, ldb, ldc, nsplit, ps); break;
  }
}

extern "C" void kernel_launch(void* const* d_in, const int* in_sizes, int n_in,
                              void* d_out, int out_size, void* d_ws, size_t ws_size,
                              hipStream_t stream) {
  const float* pixels = (const float*)d_in[0];
  const int* grid_thw = (const int*)d_in[1];
  const float* pos_embed = (const float*)d_in[2];
  const float* patch_w = (const float*)d_in[3];
  const float* patch_b = (const float*)d_in[4];
  const float* ln1_s = (const float*)d_in[5];
  const float* ln1_b = (const float*)d_in[6];
  const float* qkv_w = (const float*)d_in[7];
  const float* qkv_b = (const float*)d_in[8];
  const float* proj_w = (const float*)d_in[9];
  const float* proj_b = (const float*)d_in[10];
  const float* ln2_s = (const float*)d_in[11];
  const float* ln2_b = (const float*)d_in[12];
  const float* fc1_w = (const float*)d_in[13];
  const float* fc1_b = (const float*)d_in[14];
  const float* fc2_w = (const float*)d_in[15];
  const float* fc2_b = (const float*)d_in[16];
  const float* mns = (const float*)d_in[17];
  const float* mnb = (const float*)d_in[18];
  const float* mf1w = (const float*)d_in[19];
  const float* mf1b = (const float*)d_in[20];
  const float* mf2w = (const float*)d_in[21];
  const float* mf2b = (const float*)d_in[22];
  float* out = (float*)d_out;

  const int N = in_sizes[0] / 1536;  // 2048
  const int nimg = in_sizes[1] / 3;  // 4
  const int nseg = N / SEG;          // 4
  const int nb = NHEADS * nseg;      // 64

  char* w = (char*)d_ws;
  size_t off = 0;
  auto alloc = [&](size_t bytes) -> void* {
    void* p = w + off;
    off += (bytes + 255) & ~(size_t)255;
    return p;
  };
  int* rw = (int*)alloc((size_t)N * 4);
  int* cl = (int*)alloc((size_t)N * 4);
  int* hh = (int*)alloc((size_t)N * 4);
  int* ww = (int*)alloc((size_t)N * 4);
  float* x = (float*)alloc((size_t)N * DMODEL * 4);
  u16* h = (u16*)alloc((size_t)N * DMODEL * 2);
  u16* pixbf = (u16*)alloc((size_t)N * 1536 * 2);      // mfc2T overlay base
  u16* patchT = (u16*)alloc((size_t)DMODEL * 1536 * 2);
  u16* qkvT = (u16*)alloc((size_t)3 * DMODEL * DMODEL * 2);
  u16* projT = (u16*)alloc((size_t)DMODEL * DMODEL * 2);
  u16* fc1T = (u16*)alloc((size_t)FDIM * DMODEL * 2);
  u16* fc2T = (u16*)alloc((size_t)DMODEL * FDIM * 2);
  u16* qkvb = (u16*)alloc((size_t)N * 3 * DMODEL * 2);  // mfc1T overlay base
  u16* qr = (u16*)alloc((size_t)NHEADS * N * 96 * 2);
  u16* kr = (u16*)alloc((size_t)NHEADS * N * 96 * 2);
  u16* vp = (u16*)alloc((size_t)NHEADS * N * 128 * 2);
  u16* vpT = (u16*)alloc((size_t)NHEADS * N * 128 * 2);
  u16* pad0 = (u16*)alloc((size_t)nb * 2 * SEG * 128 * 2);  // keeps mfc1T overlay in bounds
  u16* o = (u16*)alloc((size_t)N * DMODEL * 2);
  float* bigA = (float*)alloc((size_t)nb * SEG * SEG * 4);  // ffb / mf
  float* bigB = (float*)alloc((size_t)nb * SEG * SEG * 2);  // split-K partials
  (void)ws_size; (void)pad0;
  // overlays (lifetimes disjoint with originals)
  u16* mfc1T = qkvb;         // 52.4 MB over qkvb..pad0 region
  u16* mfc2T = pixbf;        // 21.0 MB over pixbf..projT
  u16* ffb = (u16*)bigA;     // fc1 out, 21 MB at bigA base
  u16* mf = (u16*)bigA;      // merger hidden 5.2 MB at bigA base
  u16* part = (u16*)bigB;    // split-K bf16 partial planes (<= 33.5 MB)

  const float iscale = 0.11180339887498949f;  // 80^-0.5
  const long long mnD = (long long)N * DMODEL;

  coords_k<<<dim3((N + 255) / 256), 256, 0, stream>>>(grid_thw, nimg, rw, cl, hh, ww, N);
  conv_k<<<dim3((int)(((long long)N * 1536 / 4 + 255) / 256)), 256, 0, stream>>>(
      pixels, pixbf, (long long)N * 1536);
  wconv_k<<<dim3(DMODEL / 32, 1536 / 64), 256, 0, stream>>>(patch_w, patchT, 1536, DMODEL);
  // patch embed, split-K=4 (640 blocks)
  gemm_big(stream, 0, pixbf, patchT, nullptr, part, N, DMODEL, 1536, 1536, 1536,
           DMODEL, 4);
  // fused: reduce + bias + pos-embed + x + ln1(layer0) -> h
  redpeln_k<<<dim3(N), 320, 0, stream>>>(part, mnD, patch_b, pos_embed,
                                         rw, cl, hh, ww, x, ln1_s, ln1_b, h);

  for (int l = 0; l < 4; l++) {
    wconv_k<<<dim3(3 * DMODEL / 32, DMODEL / 64), 256, 0, stream>>>(
        qkv_w + (size_t)l * DMODEL * 3 * DMODEL, qkvT, DMODEL, 3 * DMODEL);
    wconv_k<<<dim3(DMODEL / 32, DMODEL / 64), 256, 0, stream>>>(
        proj_w + (size_t)l * DMODEL * DMODEL, projT, DMODEL, DMODEL);
    wconv_k<<<dim3(FDIM / 32, DMODEL / 64), 256, 0, stream>>>(
        fc1_w + (size_t)l * DMODEL * FDIM, fc1T, DMODEL, FDIM);
    wconv_k<<<dim3(DMODEL / 32, FDIM / 64), 256, 0, stream>>>(
        fc2_w + (size_t)l * FDIM * DMODEL, fc2T, FDIM, DMODEL);

    // qkv direct +bias (480 blocks, NT=40)
    gemm_big(stream, 1, h, qkvT, qkv_b + (size_t)l * 3 * DMODEL, qkvb, N,
             3 * DMODEL, DMODEL, DMODEL, DMODEL, 3 * DMODEL, 1);
    rope_k<<<dim3(N / 4, NHEADS), 256, 0, stream>>>(qkvb, rw, cl, qr, kr, vp, N);
    vtr_k<<<dim3(8, 2, nb), 256, 0, stream>>>(vp, vpT);
    // fused flash attention -> o (512 blocks x 256 thr, 2 blocks/CU)
    fattn_k<<<dim3(8, nb), 256, 0, stream>>>(qr, kr, vpT, o, N, iscale);
    // proj split-K=4 (640 blocks); fused reduce + bias + residual + ln2 -> h
    gemm_big(stream, 0, o, projT, nullptr, part, N, DMODEL, DMODEL, DMODEL,
             DMODEL, DMODEL, 4);
    redln_k<4><<<dim3(N), 320, 0, stream>>>(part, mnD, proj_b + (size_t)l * DMODEL,
                                            x, ln2_s + (size_t)l * DMODEL,
                                            ln2_b + (size_t)l * DMODEL, h);
    // fc1 fused bias+gelu -> bf16 (640 blocks, direct)
    gemm_big(stream, 3, h, fc1T, fc1_b + (size_t)l * FDIM, ffb, N, FDIM, DMODEL,
             DMODEL, DMODEL, FDIM, 1);
    // fc2 split-K=4 (640 blocks); fused reduce + bias + residual + next LN -> h
    gemm_big(stream, 0, ffb, fc2T, nullptr, part, N, DMODEL, FDIM, FDIM, FDIM,
             DMODEL, 4);
    const float* nsl = (l < 3) ? ln1_s + (size_t)(l + 1) * DMODEL : mns;
    const float* nbl = (l < 3) ? ln1_b + (size_t)(l + 1) * DMODEL : mnb;
    redln_k<4><<<dim3(N), 320, 0, stream>>>(part, mnD, fc2_b + (size_t)l * DMODEL,
                                            x, nsl, nbl, h);
  }

  // merger (h already = LN(x; mns,mnb), viewed as [512][5120])
  const int Mm = N / 4;  // 512
  wconv_k<<<dim3(FDIM / 32, FDIM / 64), 256, 0, stream>>>(mf1w, mfc1T, FDIM, FDIM);
  // mfc1 split-K=4 (640 blocks); reduce + bias + gelu -> mf
  gemm_big(stream, 0, h, mfc1T, nullptr, part, Mm, FDIM, FDIM, FDIM, FDIM, FDIM, 4);
  reduce_k<4, 0, 1, 1><<<dim3((int)(((long long)Mm * FDIM / 4 + 255) / 256)), 256, 0, stream>>>(
      part, (long long)Mm * FDIM, FDIM, mf1b, nullptr, mf);
  wconv_k<<<dim3(2048 / 32, FDIM / 64), 256, 0, stream>>>(mf2w, mfc2T, FDIM, 2048);
  // mfc2 split-K=16 (1024 blocks)
  gemm_big(stream, 0, mf, mfc2T, nullptr, part, Mm, 2048, FDIM, FDIM, FDIM, 2048, 16);
  reduce_k<16, 0, 0, 0><<<dim3((int)(((long long)Mm * 2048 / 4 + 255) / 256)), 256, 0, stream>>>(
      part, (long long)Mm * 2048, 2048, mf2b, nullptr, out);
}